// Round 1
// baseline (1259.300 us; speedup 1.0000x reference)
//
#include <hip/hip_runtime.h>

#define HW 65536
#define NSP 1024
#define CIN 200
#define DH 128
#define NE 524288
#define NCLS 16
#define BN_EPS 1e-5f
#define LSLOPE 0.01f

// ---------------- seg extraction from one-hot Q ----------------
__global__ void k_seg(const float* __restrict__ Q, int* __restrict__ seg) {
  int gid = blockIdx.x * blockDim.x + threadIdx.x;
  const int n4 = HW * NSP / 4;
  const float4* Q4 = (const float4*)Q;
  for (int i = gid; i < n4; i += gridDim.x * blockDim.x) {
    float4 q = Q4[i];
    int base = i * 4;
    if (q.x > 0.5f) seg[(base    ) >> 10] = (base    ) & (NSP - 1);
    if (q.y > 0.5f) seg[(base + 1) >> 10] = (base + 1) & (NSP - 1);
    if (q.z > 0.5f) seg[(base + 2) >> 10] = (base + 2) & (NSP - 1);
    if (q.w > 0.5f) seg[(base + 3) >> 10] = (base + 3) & (NSP - 1);
  }
}

// ---------------- degree count ----------------
__global__ void k_deg(const int* __restrict__ dst, int* __restrict__ cntd) {
  int e = blockIdx.x * blockDim.x + threadIdx.x;
  if (e < NE) atomicAdd(&cntd[dst[e]], 1);
}

// ---------------- prefix scan (3 stages) ----------------
__global__ void k_scan_a(const int* __restrict__ cntd, int* __restrict__ off,
                         int* __restrict__ bsum) {
  __shared__ int s[256];
  int t = threadIdx.x, b = blockIdx.x;
  int i = b * 256 + t;
  int v = cntd[i];
  s[t] = v; __syncthreads();
  for (int o = 1; o < 256; o <<= 1) {
    int x = (t >= o) ? s[t - o] : 0;
    __syncthreads();
    s[t] += x;
    __syncthreads();
  }
  off[i] = s[t] - v;
  if (t == 255) bsum[b] = s[t];
}
__global__ void k_scan_b(const int* __restrict__ bsum, int* __restrict__ bo) {
  __shared__ int s[256];
  int t = threadIdx.x;
  int v = bsum[t];
  s[t] = v; __syncthreads();
  for (int o = 1; o < 256; o <<= 1) {
    int x = (t >= o) ? s[t - o] : 0;
    __syncthreads();
    s[t] += x;
    __syncthreads();
  }
  bo[t] = s[t] - v;
}
__global__ void k_scan_c(int* __restrict__ off, const int* __restrict__ bo) {
  int i = blockIdx.x * blockDim.x + threadIdx.x;
  off[i] += bo[i >> 8];
  if (i == 0) off[HW] = NE;
}

// ---------------- CSR scatter ----------------
__global__ void k_scatter(const int* __restrict__ src, const int* __restrict__ dst,
                          int* __restrict__ cursor, int* __restrict__ esrc) {
  int e = blockIdx.x * blockDim.x + threadIdx.x;
  if (e < NE) {
    int d = dst[e];
    int pos = atomicAdd(&cursor[d], 1);
    esrc[pos] = src[e];
  }
}

// ---------------- generic row-GEMM: out[M,128] = A[M,K]@B[K,128] (+bias)(leaky) --
// block 256 = (d:128, rg:2); 8 rows/block; B staged in 32KB LDS chunks
__global__ __launch_bounds__(256) void k_rowgemm(
    const float* __restrict__ A, const float* __restrict__ B,
    const float* __restrict__ bias, float* __restrict__ out,
    int K, int leaky) {
  __shared__ float Bs[64 * 128];
  int t = threadIdx.x;
  int d = t & 127, rg = t >> 7;
  int row0 = blockIdx.x * 8 + rg * 4;
  float acc0 = 0.f, acc1 = 0.f, acc2 = 0.f, acc3 = 0.f;
  const float* a = A + (size_t)row0 * K;
  for (int j0 = 0; j0 < K; j0 += 64) {
    int kc = min(64, K - j0);
    __syncthreads();
    for (int idx = t; idx < kc * 128; idx += 256) Bs[idx] = B[j0 * 128 + idx];
    __syncthreads();
    #pragma unroll 4
    for (int j = 0; j < kc; ++j) {
      float bv = Bs[j * 128 + d];
      int jj = j0 + j;
      acc0 = fmaf(a[jj],           bv, acc0);
      acc1 = fmaf(a[(size_t)K + jj],   bv, acc1);
      acc2 = fmaf(a[(size_t)2*K + jj], bv, acc2);
      acc3 = fmaf(a[(size_t)3*K + jj], bv, acc3);
    }
  }
  float bb = bias ? bias[d] : 0.f;
  float v[4] = {acc0 + bb, acc1 + bb, acc2 + bb, acc3 + bb};
  #pragma unroll
  for (int r = 0; r < 4; ++r) {
    float x = v[r];
    if (leaky) x = (x >= 0.f) ? x : LSLOPE * x;
    out[(size_t)(row0 + r) * 128 + d] = x;
  }
}

// ---------------- column stats over [M,128] ----------------
__global__ void k_colstats(const float* __restrict__ in, float* __restrict__ sums,
                           float* __restrict__ sumsq, int M) {
  __shared__ float ls[256], lq[256];
  int t = threadIdx.x, b = blockIdx.x;
  int c = t & 127, half = t >> 7;
  int rpb = M / gridDim.x;
  float s = 0.f, q = 0.f;
  for (int r = b * rpb + half; r < (b + 1) * rpb; r += 2) {
    float v = in[(size_t)r * 128 + c];
    s += v; q += v * v;
  }
  ls[t] = s; lq[t] = q; __syncthreads();
  if (t < 128) {
    s = ls[t] + ls[t + 128];
    q = lq[t] + lq[t + 128];
    atomicAdd(&sums[t], s);
    atomicAdd(&sumsq[t], q);
  }
}

__global__ void k_finstats(const float* __restrict__ sums, const float* __restrict__ sumsq,
                           float cnt, float* __restrict__ mean, float* __restrict__ rs) {
  int t = threadIdx.x;
  float m = sums[t] / cnt;
  float var = sumsq[t] / cnt - m * m;
  mean[t] = m;
  rs[t] = rsqrtf(var + BN_EPS);
}

// ---------------- superpixel pooling (atomic mean) ----------------
__global__ void k_pool(const float* __restrict__ y, const int* __restrict__ seg,
                       float* __restrict__ spsum, float* __restrict__ spcnt) {
  int gid = blockIdx.x * blockDim.x + threadIdx.x;
  const int n2 = HW * 64;
  for (int i2 = gid; i2 < n2; i2 += gridDim.x * blockDim.x) {
    int row = i2 >> 6, dp = i2 & 63, d0 = dp * 2;
    float2 v = *(const float2*)(y + (size_t)row * 128 + d0);
    int s = seg[row];
    atomicAdd(&spsum[s * 128 + d0], v.x);
    atomicAdd(&spsum[s * 128 + d0 + 1], v.y);
    if (dp == 0) atomicAdd(&spcnt[s], 1.0f);
  }
}

__global__ void k_spfin(const float* __restrict__ spsum, const float* __restrict__ spcnt,
                        const float* __restrict__ mean, const float* __restrict__ rs,
                        float* __restrict__ sp) {
  int gid = blockIdx.x * blockDim.x + threadIdx.x;  // over NSP*128
  int s = gid >> 7, d = gid & 127;
  float v = spsum[gid] / spcnt[s];
  sp[gid] = (v - mean[d]) * rs[d];
}

// ---------------- fused (optional affine) + row l2norm + column stats ----------
__global__ void k_l2stats(const float* __restrict__ in, float* __restrict__ out,
                          float* __restrict__ sums, float* __restrict__ sumsq,
                          int M, const float* __restrict__ mean,
                          const float* __restrict__ rs) {
  __shared__ float lsum[128], lssq[128];
  int t = threadIdx.x;
  if (t < 128) { lsum[t] = 0.f; lssq[t] = 0.f; }
  __syncthreads();
  int wid = t >> 6, lane = t & 63, d0 = lane * 2;
  float m0 = 0.f, m1 = 0.f, r0 = 1.f, r1 = 1.f;
  if (mean) { m0 = mean[d0]; m1 = mean[d0 + 1]; r0 = rs[d0]; r1 = rs[d0 + 1]; }
  float cs0 = 0.f, cs1 = 0.f, cq0 = 0.f, cq1 = 0.f;
  for (int row = blockIdx.x * 4 + wid; row < M; row += gridDim.x * 4) {
    float2 v = *(const float2*)(in + (size_t)row * 128 + d0);
    v.x = (v.x - m0) * r0;
    v.y = (v.y - m1) * r1;
    float ss = v.x * v.x + v.y * v.y;
    #pragma unroll
    for (int o = 1; o < 64; o <<= 1) ss += __shfl_xor(ss, o);
    float sc = 1.0f / fmaxf(sqrtf(ss), 1e-12f);
    v.x *= sc; v.y *= sc;
    *(float2*)(out + (size_t)row * 128 + d0) = v;
    cs0 += v.x; cs1 += v.y; cq0 += v.x * v.x; cq1 += v.y * v.y;
  }
  atomicAdd(&lsum[d0], cs0); atomicAdd(&lsum[d0 + 1], cs1);
  atomicAdd(&lssq[d0], cq0); atomicAdd(&lssq[d0 + 1], cq1);
  __syncthreads();
  if (t < 128) { atomicAdd(&sums[t], lsum[t]); atomicAdd(&sumsq[t], lssq[t]); }
}

// ---------------- fold BN into W: Wp = rs*W, bp = base - sum(m*rs*W) ------------
__global__ void k_prepw(const float* __restrict__ sums, const float* __restrict__ sumsq,
                        float cnt, const float* __restrict__ W,
                        const float* __restrict__ base,
                        float* __restrict__ Wp, float* __restrict__ bp) {
  int k = threadIdx.x;  // 128
  float acc = 0.f;
  for (int j = 0; j < 128; ++j) {
    float m = sums[j] / cnt;
    float rsv = rsqrtf(sumsq[j] / cnt - m * m + BN_EPS);
    float w = W[j * 128 + k];
    Wp[j * 128 + k] = rsv * w;
    acc += m * rsv * w;
  }
  bp[k] = (base ? base[k] : 0.f) - acc;
}

// ---------------- CSR edge aggregation (gcn_conv) + bias + leaky ----------------
__global__ __launch_bounds__(256) void k_agg(
    const float* __restrict__ xw, const int* __restrict__ esrc,
    const int* __restrict__ off, const int* __restrict__ cntd,
    const float* __restrict__ bias, float* __restrict__ out) {
  int t = threadIdx.x;
  int wid = t >> 6, lane = t & 63, d0 = lane * 2;
  int i = blockIdx.x * 4 + wid;
  float degf = (float)cntd[i] + 1.0f;
  float dinv_i = rsqrtf(degf);
  float2 xwi = *(const float2*)(xw + (size_t)i * 128 + d0);
  float ax = xwi.x / degf, ay = xwi.y / degf;
  int s0 = off[i], s1 = off[i + 1];
  for (int k = s0; k < s1; ++k) {
    int s = esrc[k];
    float w = dinv_i * rsqrtf((float)cntd[s] + 1.0f);
    float2 v = *(const float2*)(xw + (size_t)s * 128 + d0);
    ax = fmaf(w, v.x, ax);
    ay = fmaf(w, v.y, ay);
  }
  ax += bias[d0]; ay += bias[d0 + 1];
  ax = (ax >= 0.f) ? ax : LSLOPE * ax;
  ay = (ay >= 0.f) ? ay : LSLOPE * ay;
  *(float2*)(out + (size_t)i * 128 + d0) = make_float2(ax, ay);
}

// ---------------- final: (m2 + H1[seg]) @ out_W + out_b -> softmax --------------
__global__ __launch_bounds__(256) void k_final(
    const float* __restrict__ m2, const float* __restrict__ H1,
    const int* __restrict__ seg, const float* __restrict__ Wout,
    const float* __restrict__ bout, float* __restrict__ out) {
  __shared__ float rb[16][132];
  __shared__ float WL[128 * 16];
  int t = threadIdx.x;
  int row0 = blockIdx.x * 16;
  for (int idx = t; idx < 128 * NCLS; idx += 256) WL[idx] = Wout[idx];
  for (int idx = t; idx < 16 * 128; idx += 256) {
    int r = idx >> 7, d = idx & 127;
    int row = row0 + r;
    rb[r][d] = m2[(size_t)row * 128 + d] + H1[(size_t)seg[row] * 128 + d];
  }
  __syncthreads();
  int c = t & 15, r = t >> 4;
  float acc = bout[c];
  #pragma unroll 8
  for (int d = 0; d < 128; ++d) acc = fmaf(rb[r][d], WL[d * 16 + c], acc);
  float mx = acc;
  #pragma unroll
  for (int o = 1; o < 16; o <<= 1) mx = fmaxf(mx, __shfl_xor(mx, o));
  float e = expf(acc - mx);
  float s = e;
  #pragma unroll
  for (int o = 1; o < 16; o <<= 1) s += __shfl_xor(s, o);
  out[(size_t)(row0 + r) * NCLS + c] = e / s;
}

// =================================================================================
extern "C" void kernel_launch(void* const* d_in, const int* in_sizes, int n_in,
                              void* d_out, int out_size, void* d_ws, size_t ws_size,
                              hipStream_t stream) {
  const float* x        = (const float*)d_in[0];
  const float* Q        = (const float*)d_in[1];
  const float* A_norm   = (const float*)d_in[2];
  const int*   ei       = (const int*)d_in[3];
  const float* prelin_W = (const float*)d_in[4];
  const float* prelin_b = (const float*)d_in[5];
  const float* gcn1_W   = (const float*)d_in[6];
  const float* gcn1_b   = (const float*)d_in[7];
  const float* gcn2_W   = (const float*)d_in[8];
  const float* gcn2_b   = (const float*)d_in[9];
  const float* mpnn1_W  = (const float*)d_in[10];
  const float* mpnn1_b  = (const float*)d_in[11];
  const float* mpnn2_W  = (const float*)d_in[12];
  const float* mpnn2_b  = (const float*)d_in[13];
  const float* out_W    = (const float*)d_in[14];
  const float* out_b    = (const float*)d_in[15];
  float* outp = (float*)d_out;
  const int* e_src = ei;
  const int* e_dst = ei + NE;

  char* ws = (char*)d_ws;
  size_t o = 0;
  auto alloc = [&](size_t bytes) { size_t r = o; o = (o + bytes + 255) & ~255ULL; return r; };
  size_t bufA_o  = alloc((size_t)HW * 128 * 4);
  size_t bufB_o  = alloc((size_t)HW * 128 * 4);
  size_t cntd_o  = alloc((size_t)HW * 4);         // |- zero group
  size_t spsum_o = alloc((size_t)NSP * 128 * 4);  // |
  size_t spcnt_o = alloc((size_t)NSP * 4);        // |
  size_t seg_o   = alloc((size_t)HW * 4);
  size_t off_o   = alloc((size_t)(HW + 1) * 4);
  size_t cur_o   = alloc((size_t)HW * 4);
  size_t esrc_o  = alloc((size_t)NE * 4);
  size_t bsum_o  = alloc(256 * 4);
  size_t bo_o    = alloc(256 * 4);
  size_t spA_o   = alloc((size_t)NSP * 128 * 4);
  size_t spB_o   = alloc((size_t)NSP * 128 * 4);
  size_t spC_o   = alloc((size_t)NSP * 128 * 4);
  size_t Wp_o    = alloc(128 * 128 * 4);
  size_t bp_o    = alloc(128 * 4);
  size_t meanA_o = alloc(128 * 4);
  size_t rsA_o   = alloc(128 * 4);
  size_t sums_o  = alloc(128 * 4);   // |- stat zero group (contiguous)
  size_t sumsq_o = alloc(128 * 4);   // |
  if (o > ws_size) return;  // workspace too small; fail visibly

  float* bufA  = (float*)(ws + bufA_o);
  float* bufB  = (float*)(ws + bufB_o);
  int*   cntd  = (int*)(ws + cntd_o);
  float* spsum = (float*)(ws + spsum_o);
  float* spcnt = (float*)(ws + spcnt_o);
  int*   seg   = (int*)(ws + seg_o);
  int*   offp  = (int*)(ws + off_o);
  int*   cur   = (int*)(ws + cur_o);
  int*   esrc  = (int*)(ws + esrc_o);
  int*   bsum  = (int*)(ws + bsum_o);
  int*   bo    = (int*)(ws + bo_o);
  float* spA   = (float*)(ws + spA_o);
  float* spB   = (float*)(ws + spB_o);
  float* spC   = (float*)(ws + spC_o);
  float* Wp    = (float*)(ws + Wp_o);
  float* bp    = (float*)(ws + bp_o);
  float* meanA = (float*)(ws + meanA_o);
  float* rsA   = (float*)(ws + rsA_o);
  float* sums  = (float*)(ws + sums_o);
  float* sumsq = (float*)(ws + sumsq_o);

  #define ZERO_STATS() hipMemsetAsync(sums, 0, (sumsq_o - sums_o) + 128 * 4, stream)

  // zero cntd+spsum+spcnt (contiguous block) and stats
  hipMemsetAsync(cntd, 0, (spcnt_o - cntd_o) + (size_t)NSP * 4, stream);
  ZERO_STATS();

  // seg + CSR build
  hipLaunchKernelGGL(k_seg, dim3(4096), dim3(256), 0, stream, Q, seg);
  hipLaunchKernelGGL(k_deg, dim3(NE / 256), dim3(256), 0, stream, e_dst, cntd);
  hipLaunchKernelGGL(k_scan_a, dim3(256), dim3(256), 0, stream, cntd, offp, bsum);
  hipLaunchKernelGGL(k_scan_b, dim3(1), dim3(256), 0, stream, bsum, bo);
  hipLaunchKernelGGL(k_scan_c, dim3(256), dim3(256), 0, stream, offp, bo);
  hipMemcpyAsync(cur, offp, (size_t)HW * 4, hipMemcpyDeviceToDevice, stream);
  hipLaunchKernelGGL(k_scatter, dim3(NE / 256), dim3(256), 0, stream, e_src, e_dst, cur, esrc);

  // prelin GEMM: y = x @ prelin_W + prelin_b  -> bufA
  hipLaunchKernelGGL(k_rowgemm, dim3(HW / 8), dim3(256), 0, stream,
                     x, prelin_W, prelin_b, bufA, CIN, 0);
  // BN stats of y
  hipLaunchKernelGGL(k_colstats, dim3(256), dim3(256), 0, stream, bufA, sums, sumsq, HW);
  hipLaunchKernelGGL(k_finstats, dim3(1), dim3(128), 0, stream, sums, sumsq, (float)HW, meanA, rsA);
  // pool raw y; BN applied after mean (affine commutes with mean)
  hipLaunchKernelGGL(k_pool, dim3(4096), dim3(256), 0, stream, bufA, seg, spsum, spcnt);
  hipLaunchKernelGGL(k_spfin, dim3(NSP * 128 / 256), dim3(256), 0, stream,
                     spsum, spcnt, meanA, rsA, spA);

  // GCN layer 1 (superpixels)
  ZERO_STATS();
  hipLaunchKernelGGL(k_l2stats, dim3(256), dim3(256), 0, stream,
                     spA, spB, sums, sumsq, NSP, (const float*)nullptr, (const float*)nullptr);
  hipLaunchKernelGGL(k_prepw, dim3(1), dim3(128), 0, stream, sums, sumsq, (float)NSP,
                     gcn1_W, gcn1_b, Wp, bp);
  hipLaunchKernelGGL(k_rowgemm, dim3(NSP / 8), dim3(256), 0, stream, spB, Wp, bp, spC, 128, 0);
  hipLaunchKernelGGL(k_rowgemm, dim3(NSP / 8), dim3(256), 0, stream,
                     A_norm, spC, (const float*)nullptr, spA, NSP, 1);
  // GCN layer 2
  ZERO_STATS();
  hipLaunchKernelGGL(k_l2stats, dim3(256), dim3(256), 0, stream,
                     spA, spB, sums, sumsq, NSP, (const float*)nullptr, (const float*)nullptr);
  hipLaunchKernelGGL(k_prepw, dim3(1), dim3(128), 0, stream, sums, sumsq, (float)NSP,
                     gcn2_W, gcn2_b, Wp, bp);
  hipLaunchKernelGGL(k_rowgemm, dim3(NSP / 8), dim3(256), 0, stream, spB, Wp, bp, spC, 128, 0);
  hipLaunchKernelGGL(k_rowgemm, dim3(NSP / 8), dim3(256), 0, stream,
                     A_norm, spC, (const float*)nullptr, spA, NSP, 1);  // H1 -> spA

  // MPNN layer 1 (pixels): h = BN(y) applied inside l2stats via affine
  ZERO_STATS();
  hipLaunchKernelGGL(k_l2stats, dim3(512), dim3(256), 0, stream,
                     bufA, bufB, sums, sumsq, HW, meanA, rsA);
  hipLaunchKernelGGL(k_prepw, dim3(1), dim3(128), 0, stream, sums, sumsq, (float)HW,
                     mpnn1_W, (const float*)nullptr, Wp, bp);
  hipLaunchKernelGGL(k_rowgemm, dim3(HW / 8), dim3(256), 0, stream, bufB, Wp, bp, bufA, 128, 0);
  hipLaunchKernelGGL(k_agg, dim3(HW / 4), dim3(256), 0, stream,
                     bufA, esrc, offp, cntd, mpnn1_b, bufB);  // m1 -> bufB

  // MPNN layer 2
  ZERO_STATS();
  hipLaunchKernelGGL(k_l2stats, dim3(512), dim3(256), 0, stream,
                     bufB, bufA, sums, sumsq, HW, (const float*)nullptr, (const float*)nullptr);
  hipLaunchKernelGGL(k_prepw, dim3(1), dim3(128), 0, stream, sums, sumsq, (float)HW,
                     mpnn2_W, (const float*)nullptr, Wp, bp);
  hipLaunchKernelGGL(k_rowgemm, dim3(HW / 8), dim3(256), 0, stream, bufA, Wp, bp, bufB, 128, 0);
  hipLaunchKernelGGL(k_agg, dim3(HW / 4), dim3(256), 0, stream,
                     bufB, esrc, offp, cntd, mpnn2_b, bufA);  // m2 -> bufA

  // final fused head
  hipLaunchKernelGGL(k_final, dim3(HW / 16), dim3(256), 0, stream,
                     bufA, spA, seg, out_W, out_b, outp);
  #undef ZERO_STATS
}

// Round 2
// 910.063 us; speedup vs baseline: 1.3838x; 1.3838x over previous
//
#include <hip/hip_runtime.h>

#define HW 65536
#define NSP 1024
#define CIN 200
#define DH 128
#define NE 524288
#define NCLS 16
#define BN_EPS 1e-5f
#define LSLOPE 0.01f

// ---------------- seg extraction from one-hot Q ----------------
__global__ void k_seg(const float* __restrict__ Q, int* __restrict__ seg) {
  int gid = blockIdx.x * blockDim.x + threadIdx.x;
  const int n4 = HW * NSP / 4;
  const float4* Q4 = (const float4*)Q;
  for (int i = gid; i < n4; i += gridDim.x * blockDim.x) {
    float4 q = Q4[i];
    int base = i * 4;
    if (q.x > 0.5f) seg[(base    ) >> 10] = (base    ) & (NSP - 1);
    if (q.y > 0.5f) seg[(base + 1) >> 10] = (base + 1) & (NSP - 1);
    if (q.z > 0.5f) seg[(base + 2) >> 10] = (base + 2) & (NSP - 1);
    if (q.w > 0.5f) seg[(base + 3) >> 10] = (base + 3) & (NSP - 1);
  }
}

// ---------------- degree count ----------------
__global__ void k_deg(const int* __restrict__ dst, int* __restrict__ cntd) {
  int e = blockIdx.x * blockDim.x + threadIdx.x;
  if (e < NE) atomicAdd(&cntd[dst[e]], 1);
}

// ---------------- prefix scan (3 stages) ----------------
__global__ void k_scan_a(const int* __restrict__ cntd, int* __restrict__ off,
                         int* __restrict__ bsum) {
  __shared__ int s[256];
  int t = threadIdx.x, b = blockIdx.x;
  int i = b * 256 + t;
  int v = cntd[i];
  s[t] = v; __syncthreads();
  for (int o = 1; o < 256; o <<= 1) {
    int x = (t >= o) ? s[t - o] : 0;
    __syncthreads();
    s[t] += x;
    __syncthreads();
  }
  off[i] = s[t] - v;
  if (t == 255) bsum[b] = s[t];
}
__global__ void k_scan_b(const int* __restrict__ bsum, int* __restrict__ bo) {
  __shared__ int s[256];
  int t = threadIdx.x;
  int v = bsum[t];
  s[t] = v; __syncthreads();
  for (int o = 1; o < 256; o <<= 1) {
    int x = (t >= o) ? s[t - o] : 0;
    __syncthreads();
    s[t] += x;
    __syncthreads();
  }
  bo[t] = s[t] - v;
}
// finalize offsets, init cursor, precompute dinv = rsqrt(deg+1)
__global__ void k_scan_c(int* __restrict__ off, const int* __restrict__ bo,
                         int* __restrict__ cur, const int* __restrict__ cntd,
                         float* __restrict__ dinv) {
  int i = blockIdx.x * blockDim.x + threadIdx.x;
  int v = off[i] + bo[i >> 8];
  off[i] = v;
  cur[i] = v;
  dinv[i] = rsqrtf((float)cntd[i] + 1.0f);
  if (i == 0) off[HW] = NE;
}

// ---------------- CSR scatter ----------------
__global__ void k_scatter(const int* __restrict__ src, const int* __restrict__ dst,
                          int* __restrict__ cursor, int* __restrict__ esrc) {
  int e = blockIdx.x * blockDim.x + threadIdx.x;
  if (e < NE) {
    int d = dst[e];
    int pos = atomicAdd(&cursor[d], 1);
    esrc[pos] = src[e];
  }
}

// ---------------- register-tiled GEMM: C[M,128] = A[M,K] @ B[K,128] -------------
// block 256 threads -> 64 rows x 128 cols; each thread 8 rows x 4 cols.
// Optional bias, leaky, and fused column-stats (sums/sumsq) of the output.
__global__ __launch_bounds__(256) void k_gemm(
    const float* __restrict__ A, const float* __restrict__ B,
    const float* __restrict__ bias, float* __restrict__ C,
    int K, int leaky, float* __restrict__ sums, float* __restrict__ sumsq) {
  __shared__ float As[32][68];   // [k][row], padded
  __shared__ float Bs[32][128];  // [k][col]
  __shared__ float lsum[128], lssq[128];
  int t = threadIdx.x;
  int c0 = (t & 31) * 4;
  int r0 = (t >> 5) * 8;
  int row0 = blockIdx.x * 64;
  int lr = t >> 2, lkb = (t & 3) * 8;   // A-load assignment
  float acc[8][4] = {};

  for (int k0 = 0; k0 < K; k0 += 32) {
    int kc = min(32, K - k0);
    __syncthreads();
    // B chunk (contiguous rows) -> Bs
    for (int idx = t * 4; idx < kc * 128; idx += 1024) {
      *(float4*)&Bs[idx >> 7][idx & 127] = *(const float4*)&B[(size_t)k0 * 128 + idx];
    }
    // A chunk transposed -> As[k][r]
    if (lkb < kc) {
      const float* ap = A + (size_t)(row0 + lr) * K + k0 + lkb;
      int nj = kc - lkb; if (nj > 8) nj = 8;
      if (nj == 8) {
        float4 v0 = *(const float4*)ap;
        float4 v1 = *(const float4*)(ap + 4);
        As[lkb + 0][lr] = v0.x; As[lkb + 1][lr] = v0.y;
        As[lkb + 2][lr] = v0.z; As[lkb + 3][lr] = v0.w;
        As[lkb + 4][lr] = v1.x; As[lkb + 5][lr] = v1.y;
        As[lkb + 6][lr] = v1.z; As[lkb + 7][lr] = v1.w;
      } else {
        for (int j = 0; j < nj; ++j) As[lkb + j][lr] = ap[j];
      }
    }
    __syncthreads();
    #pragma unroll 2
    for (int k = 0; k < kc; ++k) {
      float4 b4 = *(float4*)&Bs[k][c0];
      float4 a0 = *(float4*)&As[k][r0];
      float4 a1 = *(float4*)&As[k][r0 + 4];
      float av[8] = {a0.x, a0.y, a0.z, a0.w, a1.x, a1.y, a1.z, a1.w};
      float bv[4] = {b4.x, b4.y, b4.z, b4.w};
      #pragma unroll
      for (int r = 0; r < 8; ++r)
        #pragma unroll
        for (int c = 0; c < 4; ++c)
          acc[r][c] = fmaf(av[r], bv[c], acc[r][c]);
    }
  }

  float bb[4] = {0.f, 0.f, 0.f, 0.f};
  if (bias) {
    bb[0] = bias[c0]; bb[1] = bias[c0 + 1]; bb[2] = bias[c0 + 2]; bb[3] = bias[c0 + 3];
  }
  float colsum[4] = {}, colsq[4] = {};
  #pragma unroll
  for (int r = 0; r < 8; ++r) {
    float4 o;
    float v[4];
    #pragma unroll
    for (int c = 0; c < 4; ++c) {
      float x = acc[r][c] + bb[c];
      if (leaky) x = (x >= 0.f) ? x : LSLOPE * x;
      v[c] = x;
      colsum[c] += x; colsq[c] += x * x;
    }
    o.x = v[0]; o.y = v[1]; o.z = v[2]; o.w = v[3];
    *(float4*)&C[(size_t)(row0 + r0 + r) * 128 + c0] = o;
  }
  if (sums) {
    __syncthreads();
    if (t < 128) { lsum[t] = 0.f; lssq[t] = 0.f; }
    __syncthreads();
    #pragma unroll
    for (int c = 0; c < 4; ++c) {
      atomicAdd(&lsum[c0 + c], colsum[c]);
      atomicAdd(&lssq[c0 + c], colsq[c]);
    }
    __syncthreads();
    if (t < 128) { atomicAdd(&sums[t], lsum[t]); atomicAdd(&sumsq[t], lssq[t]); }
  }
}

__global__ void k_finstats(const float* __restrict__ sums, const float* __restrict__ sumsq,
                           float cnt, float* __restrict__ mean, float* __restrict__ rs) {
  int t = threadIdx.x;
  float m = sums[t] / cnt;
  float var = sumsq[t] / cnt - m * m;
  mean[t] = m;
  rs[t] = rsqrtf(var + BN_EPS);
}

// ---------------- superpixel pooling (atomic mean) ----------------
__global__ void k_pool(const float* __restrict__ y, const int* __restrict__ seg,
                       float* __restrict__ spsum, float* __restrict__ spcnt) {
  int gid = blockIdx.x * blockDim.x + threadIdx.x;
  const int n2 = HW * 64;
  for (int i2 = gid; i2 < n2; i2 += gridDim.x * blockDim.x) {
    int row = i2 >> 6, dp = i2 & 63, d0 = dp * 2;
    float2 v = *(const float2*)(y + (size_t)row * 128 + d0);
    int s = seg[row];
    atomicAdd(&spsum[s * 128 + d0], v.x);
    atomicAdd(&spsum[s * 128 + d0 + 1], v.y);
    if (dp == 0) atomicAdd(&spcnt[s], 1.0f);
  }
}

__global__ void k_spfin(const float* __restrict__ spsum, const float* __restrict__ spcnt,
                        const float* __restrict__ mean, const float* __restrict__ rs,
                        float* __restrict__ sp) {
  int gid = blockIdx.x * blockDim.x + threadIdx.x;  // over NSP*128
  int s = gid >> 7, d = gid & 127;
  float v = spsum[gid] / spcnt[s];
  sp[gid] = (v - mean[d]) * rs[d];
}

// ---------------- fused (optional affine) + row l2norm + column stats ----------
__global__ void k_l2stats(const float* __restrict__ in, float* __restrict__ out,
                          float* __restrict__ sums, float* __restrict__ sumsq,
                          int M, const float* __restrict__ mean,
                          const float* __restrict__ rs) {
  __shared__ float lsum[128], lssq[128];
  int t = threadIdx.x;
  if (t < 128) { lsum[t] = 0.f; lssq[t] = 0.f; }
  __syncthreads();
  int wid = t >> 6, lane = t & 63, d0 = lane * 2;
  float m0 = 0.f, m1 = 0.f, r0 = 1.f, r1 = 1.f;
  if (mean) { m0 = mean[d0]; m1 = mean[d0 + 1]; r0 = rs[d0]; r1 = rs[d0 + 1]; }
  float cs0 = 0.f, cs1 = 0.f, cq0 = 0.f, cq1 = 0.f;
  for (int row = blockIdx.x * 4 + wid; row < M; row += gridDim.x * 4) {
    float2 v = *(const float2*)(in + (size_t)row * 128 + d0);
    v.x = (v.x - m0) * r0;
    v.y = (v.y - m1) * r1;
    float ss = v.x * v.x + v.y * v.y;
    #pragma unroll
    for (int o = 1; o < 64; o <<= 1) ss += __shfl_xor(ss, o);
    float sc = 1.0f / fmaxf(sqrtf(ss), 1e-12f);
    v.x *= sc; v.y *= sc;
    *(float2*)(out + (size_t)row * 128 + d0) = v;
    cs0 += v.x; cs1 += v.y; cq0 += v.x * v.x; cq1 += v.y * v.y;
  }
  atomicAdd(&lsum[d0], cs0); atomicAdd(&lsum[d0 + 1], cs1);
  atomicAdd(&lssq[d0], cq0); atomicAdd(&lssq[d0 + 1], cq1);
  __syncthreads();
  if (t < 128) { atomicAdd(&sums[t], lsum[t]); atomicAdd(&sumsq[t], lssq[t]); }
}

// ---------------- fold BN into W: Wp = rs*W, bp = base - sum(m*rs*W) ------------
__global__ void k_prepw(const float* __restrict__ sums, const float* __restrict__ sumsq,
                        float cnt, const float* __restrict__ W,
                        const float* __restrict__ base,
                        float* __restrict__ Wp, float* __restrict__ bp) {
  __shared__ float ms[128], rss[128];
  int k = threadIdx.x;  // 128
  float m = sums[k] / cnt;
  float rsv = rsqrtf(sumsq[k] / cnt - m * m + BN_EPS);
  ms[k] = m; rss[k] = rsv;
  __syncthreads();
  float acc = 0.f;
  for (int j = 0; j < 128; ++j) {
    float wp = rss[j] * W[j * 128 + k];
    Wp[j * 128 + k] = wp;
    acc += ms[j] * wp;
  }
  bp[k] = (base ? base[k] : 0.f) - acc;
}

// ---------------- CSR edge aggregation + bias + leaky (+optional l2norm+stats) --
__global__ __launch_bounds__(256) void k_agg(
    const float* __restrict__ xw, const int* __restrict__ esrc,
    const int* __restrict__ off, const float* __restrict__ dinv,
    const float* __restrict__ bias, float* __restrict__ out,
    int do_norm, float* __restrict__ sums, float* __restrict__ sumsq) {
  __shared__ float lsum[128], lssq[128];
  int t = threadIdx.x;
  if (do_norm) {
    if (t < 128) { lsum[t] = 0.f; lssq[t] = 0.f; }
    __syncthreads();
  }
  int wid = t >> 6, lane = t & 63, d0 = lane * 2;
  float b0 = bias[d0], b1 = bias[d0 + 1];
  float cs0 = 0.f, cs1 = 0.f, cq0 = 0.f, cq1 = 0.f;
  for (int i = blockIdx.x * 4 + wid; i < HW; i += gridDim.x * 4) {
    float di = dinv[i];
    float inv_deg = di * di;
    float2 xwi = *(const float2*)(xw + (size_t)i * 128 + d0);
    float ax = xwi.x * inv_deg, ay = xwi.y * inv_deg;
    int s0 = off[i], s1 = off[i + 1];
    for (int k = s0; k < s1; ++k) {
      int s = esrc[k];
      float w = di * dinv[s];
      float2 v = *(const float2*)(xw + (size_t)s * 128 + d0);
      ax = fmaf(w, v.x, ax);
      ay = fmaf(w, v.y, ay);
    }
    ax += b0; ay += b1;
    ax = (ax >= 0.f) ? ax : LSLOPE * ax;
    ay = (ay >= 0.f) ? ay : LSLOPE * ay;
    if (do_norm) {
      float ss = ax * ax + ay * ay;
      #pragma unroll
      for (int o = 1; o < 64; o <<= 1) ss += __shfl_xor(ss, o);
      float sc = 1.0f / fmaxf(sqrtf(ss), 1e-12f);
      ax *= sc; ay *= sc;
      cs0 += ax; cs1 += ay; cq0 += ax * ax; cq1 += ay * ay;
    }
    *(float2*)(out + (size_t)i * 128 + d0) = make_float2(ax, ay);
  }
  if (do_norm) {
    atomicAdd(&lsum[d0], cs0); atomicAdd(&lsum[d0 + 1], cs1);
    atomicAdd(&lssq[d0], cq0); atomicAdd(&lssq[d0 + 1], cq1);
    __syncthreads();
    if (t < 128) { atomicAdd(&sums[t], lsum[t]); atomicAdd(&sumsq[t], lssq[t]); }
  }
}

// ---------------- final: (m2 + H1[seg]) @ out_W + out_b -> softmax --------------
__global__ __launch_bounds__(256) void k_final(
    const float* __restrict__ m2, const float* __restrict__ H1,
    const int* __restrict__ seg, const float* __restrict__ Wout,
    const float* __restrict__ bout, float* __restrict__ out) {
  __shared__ float rb[16][132];
  __shared__ float WL[128 * 16];
  int t = threadIdx.x;
  int row0 = blockIdx.x * 16;
  for (int idx = t; idx < 128 * NCLS; idx += 256) WL[idx] = Wout[idx];
  for (int idx = t; idx < 16 * 128; idx += 256) {
    int r = idx >> 7, d = idx & 127;
    int row = row0 + r;
    rb[r][d] = m2[(size_t)row * 128 + d] + H1[(size_t)seg[row] * 128 + d];
  }
  __syncthreads();
  int c = t & 15, r = t >> 4;
  float acc = bout[c];
  #pragma unroll 8
  for (int d = 0; d < 128; ++d) acc = fmaf(rb[r][d], WL[d * 16 + c], acc);
  float mx = acc;
  #pragma unroll
  for (int o = 1; o < 16; o <<= 1) mx = fmaxf(mx, __shfl_xor(mx, o));
  float e = expf(acc - mx);
  float s = e;
  #pragma unroll
  for (int o = 1; o < 16; o <<= 1) s += __shfl_xor(s, o);
  out[(size_t)(row0 + r) * NCLS + c] = e / s;
}

// =================================================================================
extern "C" void kernel_launch(void* const* d_in, const int* in_sizes, int n_in,
                              void* d_out, int out_size, void* d_ws, size_t ws_size,
                              hipStream_t stream) {
  const float* x        = (const float*)d_in[0];
  const float* Q        = (const float*)d_in[1];
  const float* A_norm   = (const float*)d_in[2];
  const int*   ei       = (const int*)d_in[3];
  const float* prelin_W = (const float*)d_in[4];
  const float* prelin_b = (const float*)d_in[5];
  const float* gcn1_W   = (const float*)d_in[6];
  const float* gcn1_b   = (const float*)d_in[7];
  const float* gcn2_W   = (const float*)d_in[8];
  const float* gcn2_b   = (const float*)d_in[9];
  const float* mpnn1_W  = (const float*)d_in[10];
  const float* mpnn1_b  = (const float*)d_in[11];
  const float* mpnn2_W  = (const float*)d_in[12];
  const float* mpnn2_b  = (const float*)d_in[13];
  const float* out_W    = (const float*)d_in[14];
  const float* out_b    = (const float*)d_in[15];
  float* outp = (float*)d_out;
  const int* e_src = ei;
  const int* e_dst = ei + NE;

  char* ws = (char*)d_ws;
  size_t o = 0;
  auto alloc = [&](size_t bytes) { size_t r = o; o = (o + bytes + 255) & ~255ULL; return r; };
  size_t bufA_o  = alloc((size_t)HW * 128 * 4);
  size_t bufB_o  = alloc((size_t)HW * 128 * 4);
  // ---- zero group start ----
  size_t cntd_o  = alloc((size_t)HW * 4);
  size_t spsum_o = alloc((size_t)NSP * 128 * 4);
  size_t spcnt_o = alloc((size_t)NSP * 4);
  size_t stats_o = alloc(5 * 256 * 4);   // 5 sum/sumsq pairs (128+128 each)
  size_t zero_end = o;
  // ---- zero group end ----
  size_t seg_o   = alloc((size_t)HW * 4);
  size_t off_o   = alloc((size_t)(HW + 1) * 4);
  size_t cur_o   = alloc((size_t)HW * 4);
  size_t dinv_o  = alloc((size_t)HW * 4);
  size_t esrc_o  = alloc((size_t)NE * 4);
  size_t bsum_o  = alloc(256 * 4);
  size_t bo_o    = alloc(256 * 4);
  size_t spA_o   = alloc((size_t)NSP * 128 * 4);
  size_t spB_o   = alloc((size_t)NSP * 128 * 4);
  size_t spC_o   = alloc((size_t)NSP * 128 * 4);
  size_t Wp_o    = alloc(128 * 128 * 4);
  size_t bp_o    = alloc(128 * 4);
  size_t meanA_o = alloc(128 * 4);
  size_t rsA_o   = alloc(128 * 4);
  if (o > ws_size) return;  // workspace too small; fail visibly

  float* bufA  = (float*)(ws + bufA_o);
  float* bufB  = (float*)(ws + bufB_o);
  int*   cntd  = (int*)(ws + cntd_o);
  float* spsum = (float*)(ws + spsum_o);
  float* spcnt = (float*)(ws + spcnt_o);
  float* stats = (float*)(ws + stats_o);
  float* sA_s  = stats + 0 * 256, *sA_q  = sA_s + 128;   // prelin out stats
  float* sG1_s = stats + 1 * 256, *sG1_q = sG1_s + 128;  // gcn l2 stats 1
  float* sG2_s = stats + 2 * 256, *sG2_q = sG2_s + 128;  // gcn l2 stats 2
  float* sM1_s = stats + 3 * 256, *sM1_q = sM1_s + 128;  // l2(bn(y)) stats
  float* sM2_s = stats + 4 * 256, *sM2_q = sM2_s + 128;  // l2(m1) stats
  int*   seg   = (int*)(ws + seg_o);
  int*   offp  = (int*)(ws + off_o);
  int*   cur   = (int*)(ws + cur_o);
  float* dinv  = (float*)(ws + dinv_o);
  int*   esrc  = (int*)(ws + esrc_o);
  int*   bsum  = (int*)(ws + bsum_o);
  int*   bo    = (int*)(ws + bo_o);
  float* spA   = (float*)(ws + spA_o);
  float* spB   = (float*)(ws + spB_o);
  float* spC   = (float*)(ws + spC_o);
  float* Wp    = (float*)(ws + Wp_o);
  float* bp    = (float*)(ws + bp_o);
  float* meanA = (float*)(ws + meanA_o);
  float* rsA   = (float*)(ws + rsA_o);

  // single memset covers cntd, spsum, spcnt, all stat pairs
  hipMemsetAsync(ws + cntd_o, 0, zero_end - cntd_o, stream);

  // seg + CSR build
  hipLaunchKernelGGL(k_seg, dim3(4096), dim3(256), 0, stream, Q, seg);
  hipLaunchKernelGGL(k_deg, dim3(NE / 256), dim3(256), 0, stream, e_dst, cntd);
  hipLaunchKernelGGL(k_scan_a, dim3(256), dim3(256), 0, stream, cntd, offp, bsum);
  hipLaunchKernelGGL(k_scan_b, dim3(1), dim3(256), 0, stream, bsum, bo);
  hipLaunchKernelGGL(k_scan_c, dim3(256), dim3(256), 0, stream, offp, bo, cur, cntd, dinv);
  hipLaunchKernelGGL(k_scatter, dim3(NE / 256), dim3(256), 0, stream, e_src, e_dst, cur, esrc);

  // prelin GEMM: y = x @ prelin_W + prelin_b -> bufA, fused col stats -> sA
  hipLaunchKernelGGL(k_gemm, dim3(HW / 64), dim3(256), 0, stream,
                     x, prelin_W, prelin_b, bufA, CIN, 0, sA_s, sA_q);
  hipLaunchKernelGGL(k_finstats, dim3(1), dim3(128), 0, stream, sA_s, sA_q, (float)HW, meanA, rsA);
  // pool raw y; BN affine applied after mean (commutes)
  hipLaunchKernelGGL(k_pool, dim3(4096), dim3(256), 0, stream, bufA, seg, spsum, spcnt);
  hipLaunchKernelGGL(k_spfin, dim3(NSP * 128 / 256), dim3(256), 0, stream,
                     spsum, spcnt, meanA, rsA, spA);

  // GCN layer 1 (superpixels)
  hipLaunchKernelGGL(k_l2stats, dim3(256), dim3(256), 0, stream,
                     spA, spB, sG1_s, sG1_q, NSP, (const float*)nullptr, (const float*)nullptr);
  hipLaunchKernelGGL(k_prepw, dim3(1), dim3(128), 0, stream, sG1_s, sG1_q, (float)NSP,
                     gcn1_W, gcn1_b, Wp, bp);
  hipLaunchKernelGGL(k_gemm, dim3(NSP / 64), dim3(256), 0, stream,
                     spB, Wp, bp, spC, 128, 0, (float*)nullptr, (float*)nullptr);
  hipLaunchKernelGGL(k_gemm, dim3(NSP / 64), dim3(256), 0, stream,
                     A_norm, spC, (const float*)nullptr, spA, NSP, 1, (float*)nullptr, (float*)nullptr);
  // GCN layer 2
  hipLaunchKernelGGL(k_l2stats, dim3(256), dim3(256), 0, stream,
                     spA, spB, sG2_s, sG2_q, NSP, (const float*)nullptr, (const float*)nullptr);
  hipLaunchKernelGGL(k_prepw, dim3(1), dim3(128), 0, stream, sG2_s, sG2_q, (float)NSP,
                     gcn2_W, gcn2_b, Wp, bp);
  hipLaunchKernelGGL(k_gemm, dim3(NSP / 64), dim3(256), 0, stream,
                     spB, Wp, bp, spC, 128, 0, (float*)nullptr, (float*)nullptr);
  hipLaunchKernelGGL(k_gemm, dim3(NSP / 64), dim3(256), 0, stream,
                     A_norm, spC, (const float*)nullptr, spA, NSP, 1, (float*)nullptr, (float*)nullptr);
  // H1 -> spA

  // MPNN layer 1: A-input = l2norm(bn(y)) with stats for W-fold
  hipLaunchKernelGGL(k_l2stats, dim3(512), dim3(256), 0, stream,
                     bufA, bufB, sM1_s, sM1_q, HW, meanA, rsA);
  hipLaunchKernelGGL(k_prepw, dim3(1), dim3(128), 0, stream, sM1_s, sM1_q, (float)HW,
                     mpnn1_W, (const float*)nullptr, Wp, bp);
  hipLaunchKernelGGL(k_gemm, dim3(HW / 64), dim3(256), 0, stream,
                     bufB, Wp, bp, bufA, 128, 0, (float*)nullptr, (float*)nullptr);  // xw1 -> bufA
  // agg1 with fused l2norm + stats: bufB = l2norm(m1), stats -> sM2
  hipLaunchKernelGGL(k_agg, dim3(2048), dim3(256), 0, stream,
                     bufA, esrc, offp, dinv, mpnn1_b, bufB, 1, sM2_s, sM2_q);

  // MPNN layer 2
  hipLaunchKernelGGL(k_prepw, dim3(1), dim3(128), 0, stream, sM2_s, sM2_q, (float)HW,
                     mpnn2_W, (const float*)nullptr, Wp, bp);
  hipLaunchKernelGGL(k_gemm, dim3(HW / 64), dim3(256), 0, stream,
                     bufB, Wp, bp, bufA, 128, 0, (float*)nullptr, (float*)nullptr);  // xw2 -> bufA
  hipLaunchKernelGGL(k_agg, dim3(2048), dim3(256), 0, stream,
                     bufA, esrc, offp, dinv, mpnn2_b, bufB, 0, (float*)nullptr, (float*)nullptr);
  // m2 -> bufB

  // final fused head
  hipLaunchKernelGGL(k_final, dim3(HW / 16), dim3(256), 0, stream,
                     bufB, spA, seg, out_W, out_b, outp);
}

// Round 3
// 896.432 us; speedup vs baseline: 1.4048x; 1.0152x over previous
//
#include <hip/hip_runtime.h>

#define HW 65536
#define NSP 1024
#define CIN 200
#define DH 128
#define NE 524288
#define NCLS 16
#define BN_EPS 1e-5f
#define LSLOPE 0.01f

// ---------------- fused: seg + seg_inv build (from one-hot Q) + edge degree ----
__global__ __launch_bounds__(256) void k_setup(
    const float* __restrict__ Q, int* __restrict__ seg, int* __restrict__ seg_inv,
    int* __restrict__ cnt_inv, const int* __restrict__ dst, int* __restrict__ cntd) {
  int b = blockIdx.x, t = threadIdx.x;
  if (b < 4096) {
    const float4* Q4 = (const float4*)Q;
    const int n4 = HW * NSP / 4;
    for (int i = b * 256 + t; i < n4; i += 4096 * 256) {
      float4 q = Q4[i];
      int base = i * 4;
      #pragma unroll
      for (int e = 0; e < 4; ++e) {
        float qv = (e == 0) ? q.x : (e == 1) ? q.y : (e == 2) ? q.z : q.w;
        if (qv > 0.5f) {
          int idx = base + e;
          int r = idx >> 10, s = idx & (NSP - 1);
          seg[r] = s;
          int p = atomicAdd(&cnt_inv[s], 1);
          seg_inv[s * 64 + p] = r;
        }
      }
    }
  } else {
    int e = (b - 4096) * 256 + t;
    if (e < NE) atomicAdd(&cntd[dst[e]], 1);
  }
}

// ---------------- prefix scan (3 stages) ----------------
__global__ void k_scan_a(const int* __restrict__ cntd, int* __restrict__ off,
                         int* __restrict__ bsum) {
  __shared__ int s[256];
  int t = threadIdx.x, b = blockIdx.x;
  int i = b * 256 + t;
  int v = cntd[i];
  s[t] = v; __syncthreads();
  for (int o = 1; o < 256; o <<= 1) {
    int x = (t >= o) ? s[t - o] : 0;
    __syncthreads();
    s[t] += x;
    __syncthreads();
  }
  off[i] = s[t] - v;
  if (t == 255) bsum[b] = s[t];
}
__global__ void k_scan_b(const int* __restrict__ bsum, int* __restrict__ bo) {
  __shared__ int s[256];
  int t = threadIdx.x;
  int v = bsum[t];
  s[t] = v; __syncthreads();
  for (int o = 1; o < 256; o <<= 1) {
    int x = (t >= o) ? s[t - o] : 0;
    __syncthreads();
    s[t] += x;
    __syncthreads();
  }
  bo[t] = s[t] - v;
}
__global__ void k_scan_c(int* __restrict__ off, const int* __restrict__ bo,
                         int* __restrict__ cur, const int* __restrict__ cntd,
                         float* __restrict__ dinv) {
  int i = blockIdx.x * blockDim.x + threadIdx.x;
  int v = off[i] + bo[i >> 8];
  off[i] = v;
  cur[i] = v;
  dinv[i] = rsqrtf((float)cntd[i] + 1.0f);
  if (i == 0) off[HW] = NE;
}

// ---------------- CSR scatter ----------------
__global__ void k_scatter(const int* __restrict__ src, const int* __restrict__ dst,
                          int* __restrict__ cursor, int* __restrict__ esrc) {
  int e = blockIdx.x * blockDim.x + threadIdx.x;
  if (e < NE) {
    int d = dst[e];
    int pos = atomicAdd(&cursor[d], 1);
    esrc[pos] = src[e];
  }
}

// ---------------- register-tiled GEMM: C[M,128] = A[M,K] @ B[K,128] -------------
// 256 thr -> 64 rows x 128 cols; thread 8x4. Epilogue options:
//   invn/cvec: x = invn[row]*(acc - cvec[col]) + bias[col]   (l2norm fold)
//   else:      x = acc + bias[col]
//   leaky, fused col-stats.
__global__ __launch_bounds__(256) void k_gemm(
    const float* __restrict__ A, const float* __restrict__ B,
    const float* __restrict__ bias, float* __restrict__ C,
    int K, int leaky, float* __restrict__ sums, float* __restrict__ sumsq,
    const float* __restrict__ invn, const float* __restrict__ cvec) {
  __shared__ float As[32][68];
  __shared__ float Bs[32][128];
  __shared__ float lsum[128], lssq[128];
  int t = threadIdx.x;
  int c0 = (t & 31) * 4;
  int r0 = (t >> 5) * 8;
  int row0 = blockIdx.x * 64;
  int lr = t >> 2, lkb = (t & 3) * 8;
  float acc[8][4] = {};

  for (int k0 = 0; k0 < K; k0 += 32) {
    int kc = min(32, K - k0);
    __syncthreads();
    for (int idx = t * 4; idx < kc * 128; idx += 1024) {
      *(float4*)&Bs[idx >> 7][idx & 127] = *(const float4*)&B[(size_t)k0 * 128 + idx];
    }
    if (lkb < kc) {
      const float* ap = A + (size_t)(row0 + lr) * K + k0 + lkb;
      int nj = kc - lkb; if (nj > 8) nj = 8;
      if (nj == 8) {
        float4 v0 = *(const float4*)ap;
        float4 v1 = *(const float4*)(ap + 4);
        As[lkb + 0][lr] = v0.x; As[lkb + 1][lr] = v0.y;
        As[lkb + 2][lr] = v0.z; As[lkb + 3][lr] = v0.w;
        As[lkb + 4][lr] = v1.x; As[lkb + 5][lr] = v1.y;
        As[lkb + 6][lr] = v1.z; As[lkb + 7][lr] = v1.w;
      } else {
        for (int j = 0; j < nj; ++j) As[lkb + j][lr] = ap[j];
      }
    }
    __syncthreads();
    #pragma unroll 2
    for (int k = 0; k < kc; ++k) {
      float4 b4 = *(float4*)&Bs[k][c0];
      float4 a0 = *(float4*)&As[k][r0];
      float4 a1 = *(float4*)&As[k][r0 + 4];
      float av[8] = {a0.x, a0.y, a0.z, a0.w, a1.x, a1.y, a1.z, a1.w};
      float bv[4] = {b4.x, b4.y, b4.z, b4.w};
      #pragma unroll
      for (int r = 0; r < 8; ++r)
        #pragma unroll
        for (int c = 0; c < 4; ++c)
          acc[r][c] = fmaf(av[r], bv[c], acc[r][c]);
    }
  }

  float bb[4] = {0.f, 0.f, 0.f, 0.f};
  if (bias) { bb[0] = bias[c0]; bb[1] = bias[c0+1]; bb[2] = bias[c0+2]; bb[3] = bias[c0+3]; }
  float cv[4] = {0.f, 0.f, 0.f, 0.f};
  float inr[8];
  if (invn) {
    cv[0] = cvec[c0]; cv[1] = cvec[c0+1]; cv[2] = cvec[c0+2]; cv[3] = cvec[c0+3];
    #pragma unroll
    for (int r = 0; r < 8; ++r) inr[r] = invn[row0 + r0 + r];
  }
  float colsum[4] = {}, colsq[4] = {};
  #pragma unroll
  for (int r = 0; r < 8; ++r) {
    float4 o;
    float v[4];
    #pragma unroll
    for (int c = 0; c < 4; ++c) {
      float x;
      if (invn) x = inr[r] * (acc[r][c] - cv[c]) + bb[c];
      else      x = acc[r][c] + bb[c];
      if (leaky) x = (x >= 0.f) ? x : LSLOPE * x;
      v[c] = x;
      colsum[c] += x; colsq[c] += x * x;
    }
    o.x = v[0]; o.y = v[1]; o.z = v[2]; o.w = v[3];
    *(float4*)&C[(size_t)(row0 + r0 + r) * 128 + c0] = o;
  }
  if (sums) {
    __syncthreads();
    if (t < 128) { lsum[t] = 0.f; lssq[t] = 0.f; }
    __syncthreads();
    #pragma unroll
    for (int c = 0; c < 4; ++c) {
      atomicAdd(&lsum[c0 + c], colsum[c]);
      atomicAdd(&lssq[c0 + c], colsq[c]);
    }
    __syncthreads();
    if (t < 128) { atomicAdd(&sums[t], lsum[t]); atomicAdd(&sumsq[t], lssq[t]); }
  }
}

// ---------------- superpixel mean-pool via inverted index + inline BN ----------
__global__ __launch_bounds__(256) void k_pool2(
    const float* __restrict__ y, const int* __restrict__ seg_inv,
    const int* __restrict__ cnt_inv, const float* __restrict__ sAs,
    const float* __restrict__ sAq, float* __restrict__ spA) {
  __shared__ float part[128];
  int sp = blockIdx.x, t = threadIdx.x;
  int d = t & 127, h = t >> 7;
  int cnt = cnt_inv[sp];
  float acc = 0.f;
  for (int r = h; r < cnt; r += 2)
    acc += y[(size_t)seg_inv[sp * 64 + r] * 128 + d];
  if (h) part[d] = acc;
  __syncthreads();
  if (!h) {
    float s = acc + part[d];
    float mA = sAs[d] / (float)HW;
    float rsA = rsqrtf(sAq[d] / (float)HW - mA * mA + BN_EPS);
    spA[sp * 128 + d] = (s / (float)cnt - mA) * rsA;
  }
}

// ------- row inv-norms (after optional pre-BN affine) + col-stats of normalized --
__global__ void k_rstats(const float* __restrict__ in, float* __restrict__ invn,
                         float* __restrict__ sums, float* __restrict__ sumsq, int M,
                         const float* __restrict__ preS, const float* __restrict__ preQ,
                         float precnt) {
  __shared__ float lsum[128], lssq[128];
  int t = threadIdx.x;
  if (t < 128) { lsum[t] = 0.f; lssq[t] = 0.f; }
  __syncthreads();
  int wid = t >> 6, lane = t & 63, d0 = lane * 2;
  float m0 = 0.f, m1 = 0.f, r0 = 1.f, r1 = 1.f;
  if (preS) {
    m0 = preS[d0] / precnt;
    r0 = rsqrtf(preQ[d0] / precnt - m0 * m0 + BN_EPS);
    m1 = preS[d0 + 1] / precnt;
    r1 = rsqrtf(preQ[d0 + 1] / precnt - m1 * m1 + BN_EPS);
  }
  float cs0 = 0.f, cs1 = 0.f, cq0 = 0.f, cq1 = 0.f;
  for (int row = blockIdx.x * 4 + wid; row < M; row += gridDim.x * 4) {
    float2 v = *(const float2*)(in + (size_t)row * 128 + d0);
    v.x = (v.x - m0) * r0;
    v.y = (v.y - m1) * r1;
    float ss = v.x * v.x + v.y * v.y;
    #pragma unroll
    for (int o = 1; o < 64; o <<= 1) ss += __shfl_xor(ss, o);
    float sc = 1.0f / fmaxf(sqrtf(ss), 1e-12f);
    if (lane == 0) invn[row] = sc;
    float nx = v.x * sc, ny = v.y * sc;
    cs0 += nx; cs1 += ny; cq0 += nx * nx; cq1 += ny * ny;
  }
  atomicAdd(&lsum[d0], cs0); atomicAdd(&lsum[d0 + 1], cs1);
  atomicAdd(&lssq[d0], cq0); atomicAdd(&lssq[d0 + 1], cq1);
  __syncthreads();
  if (t < 128) { atomicAdd(&sums[t], lsum[t]); atomicAdd(&sumsq[t], lssq[t]); }
}

// -- fold BN(s) into W: W''=rsA*rs2*W; cvec=mA@W''; bp=base-m2@(rs2*W) ----------
__global__ void k_prepw(const float* __restrict__ sums, const float* __restrict__ sumsq,
                        float cnt, const float* __restrict__ W,
                        const float* __restrict__ base,
                        const float* __restrict__ preS, const float* __restrict__ preQ,
                        float precnt,
                        float* __restrict__ Wpp, float* __restrict__ cvec,
                        float* __restrict__ bp) {
  __shared__ float cpart[2][128], bpart[2][128];
  int t = threadIdx.x;
  int k = t & 127, jh = t >> 7;
  float accc = 0.f, accb = 0.f;
  for (int j = jh * 64; j < jh * 64 + 64; ++j) {
    float m2 = sums[j] / cnt;
    float rs2 = rsqrtf(sumsq[j] / cnt - m2 * m2 + BN_EPS);
    float w2 = rs2 * W[j * 128 + k];
    float mA = 0.f, rsA = 1.f;
    if (preS) {
      mA = preS[j] / precnt;
      rsA = rsqrtf(preQ[j] / precnt - mA * mA + BN_EPS);
    }
    float wpp = rsA * w2;
    Wpp[j * 128 + k] = wpp;
    accc += mA * wpp;
    accb += m2 * w2;
  }
  cpart[jh][k] = accc; bpart[jh][k] = accb;
  __syncthreads();
  if (t < 128) {
    cvec[k] = cpart[0][k] + cpart[1][k];
    bp[k] = (base ? base[k] : 0.f) - (bpart[0][k] + bpart[1][k]);
  }
}

// ---------------- CSR edge aggregation + bias + leaky (+optional l2norm+stats) --
__global__ __launch_bounds__(256) void k_agg(
    const float* __restrict__ xw, const int* __restrict__ esrc,
    const int* __restrict__ off, const float* __restrict__ dinv,
    const float* __restrict__ bias, float* __restrict__ out,
    int do_norm, float* __restrict__ sums, float* __restrict__ sumsq) {
  __shared__ float lsum[128], lssq[128];
  int t = threadIdx.x;
  if (do_norm) {
    if (t < 128) { lsum[t] = 0.f; lssq[t] = 0.f; }
    __syncthreads();
  }
  int wid = t >> 6, lane = t & 63, d0 = lane * 2;
  float b0 = bias[d0], b1 = bias[d0 + 1];
  float cs0 = 0.f, cs1 = 0.f, cq0 = 0.f, cq1 = 0.f;
  for (int i = blockIdx.x * 4 + wid; i < HW; i += gridDim.x * 4) {
    float di = dinv[i];
    float inv_deg = di * di;
    float2 xwi = *(const float2*)(xw + (size_t)i * 128 + d0);
    float ax = xwi.x * inv_deg, ay = xwi.y * inv_deg;
    int s0 = off[i], s1 = off[i + 1];
    for (int k = s0; k < s1; ++k) {
      int s = esrc[k];
      float w = di * dinv[s];
      float2 v = *(const float2*)(xw + (size_t)s * 128 + d0);
      ax = fmaf(w, v.x, ax);
      ay = fmaf(w, v.y, ay);
    }
    ax += b0; ay += b1;
    ax = (ax >= 0.f) ? ax : LSLOPE * ax;
    ay = (ay >= 0.f) ? ay : LSLOPE * ay;
    if (do_norm) {
      float ss = ax * ax + ay * ay;
      #pragma unroll
      for (int o = 1; o < 64; o <<= 1) ss += __shfl_xor(ss, o);
      float sc = 1.0f / fmaxf(sqrtf(ss), 1e-12f);
      ax *= sc; ay *= sc;
      cs0 += ax; cs1 += ay; cq0 += ax * ax; cq1 += ay * ay;
    }
    *(float2*)(out + (size_t)i * 128 + d0) = make_float2(ax, ay);
  }
  if (do_norm) {
    atomicAdd(&lsum[d0], cs0); atomicAdd(&lsum[d0 + 1], cs1);
    atomicAdd(&lssq[d0], cq0); atomicAdd(&lssq[d0 + 1], cq1);
    __syncthreads();
    if (t < 128) { atomicAdd(&sums[t], lsum[t]); atomicAdd(&sumsq[t], lssq[t]); }
  }
}

// ---------------- final: (m2 + H1[seg]) @ out_W + out_b -> softmax --------------
__global__ __launch_bounds__(256) void k_final(
    const float* __restrict__ m2, const float* __restrict__ H1,
    const int* __restrict__ seg, const float* __restrict__ Wout,
    const float* __restrict__ bout, float* __restrict__ out) {
  __shared__ float rb[16][132];
  __shared__ float WL[128 * 16];
  int t = threadIdx.x;
  int row0 = blockIdx.x * 16;
  for (int idx = t; idx < 128 * NCLS; idx += 256) WL[idx] = Wout[idx];
  for (int idx = t; idx < 16 * 128; idx += 256) {
    int r = idx >> 7, d = idx & 127;
    int row = row0 + r;
    rb[r][d] = m2[(size_t)row * 128 + d] + H1[(size_t)seg[row] * 128 + d];
  }
  __syncthreads();
  int c = t & 15, r = t >> 4;
  float acc = bout[c];
  #pragma unroll 8
  for (int d = 0; d < 128; ++d) acc = fmaf(rb[r][d], WL[d * 16 + c], acc);
  float mx = acc;
  #pragma unroll
  for (int o = 1; o < 16; o <<= 1) mx = fmaxf(mx, __shfl_xor(mx, o));
  float e = expf(acc - mx);
  float s = e;
  #pragma unroll
  for (int o = 1; o < 16; o <<= 1) s += __shfl_xor(s, o);
  out[(size_t)(row0 + r) * NCLS + c] = e / s;
}

// =================================================================================
extern "C" void kernel_launch(void* const* d_in, const int* in_sizes, int n_in,
                              void* d_out, int out_size, void* d_ws, size_t ws_size,
                              hipStream_t stream) {
  const float* x        = (const float*)d_in[0];
  const float* Q        = (const float*)d_in[1];
  const float* A_norm   = (const float*)d_in[2];
  const int*   ei       = (const int*)d_in[3];
  const float* prelin_W = (const float*)d_in[4];
  const float* prelin_b = (const float*)d_in[5];
  const float* gcn1_W   = (const float*)d_in[6];
  const float* gcn1_b   = (const float*)d_in[7];
  const float* gcn2_W   = (const float*)d_in[8];
  const float* gcn2_b   = (const float*)d_in[9];
  const float* mpnn1_W  = (const float*)d_in[10];
  const float* mpnn1_b  = (const float*)d_in[11];
  const float* mpnn2_W  = (const float*)d_in[12];
  const float* mpnn2_b  = (const float*)d_in[13];
  const float* out_W    = (const float*)d_in[14];
  const float* out_b    = (const float*)d_in[15];
  float* outp = (float*)d_out;
  const int* e_src = ei;
  const int* e_dst = ei + NE;

  char* ws = (char*)d_ws;
  size_t o = 0;
  auto alloc = [&](size_t bytes) { size_t r = o; o = (o + bytes + 255) & ~255ULL; return r; };
  size_t bufA_o   = alloc((size_t)HW * 128 * 4);
  size_t bufB_o   = alloc((size_t)HW * 128 * 4);
  // ---- zero group start ----
  size_t cntd_o   = alloc((size_t)HW * 4);
  size_t cntinv_o = alloc((size_t)NSP * 4);
  size_t stats_o  = alloc(5 * 256 * 4);
  size_t zero_end = o;
  // ---- zero group end ----
  size_t seg_o    = alloc((size_t)HW * 4);
  size_t seginv_o = alloc((size_t)HW * 4);
  size_t off_o    = alloc((size_t)(HW + 1) * 4);
  size_t cur_o    = alloc((size_t)HW * 4);
  size_t dinv_o   = alloc((size_t)HW * 4);
  size_t esrc_o   = alloc((size_t)NE * 4);
  size_t bsum_o   = alloc(256 * 4);
  size_t bo_o     = alloc(256 * 4);
  size_t spA_o    = alloc((size_t)NSP * 128 * 4);
  size_t spC_o    = alloc((size_t)NSP * 128 * 4);
  size_t spD_o    = alloc((size_t)NSP * 128 * 4);
  size_t spH_o    = alloc((size_t)NSP * 128 * 4);
  size_t Wpp_o    = alloc(128 * 128 * 4);
  size_t cv_o     = alloc(128 * 4);
  size_t bp_o     = alloc(128 * 4);
  size_t invG1_o  = alloc((size_t)NSP * 4);
  size_t invG2_o  = alloc((size_t)NSP * 4);
  size_t invM1_o  = alloc((size_t)HW * 4);
  if (o > ws_size) return;

  float* bufA   = (float*)(ws + bufA_o);
  float* bufB   = (float*)(ws + bufB_o);
  int*   cntd   = (int*)(ws + cntd_o);
  int*   cntinv = (int*)(ws + cntinv_o);
  float* stats  = (float*)(ws + stats_o);
  float* sA_s  = stats + 0 * 256, *sA_q  = sA_s + 128;
  float* sG1_s = stats + 1 * 256, *sG1_q = sG1_s + 128;
  float* sG2_s = stats + 2 * 256, *sG2_q = sG2_s + 128;
  float* sM1_s = stats + 3 * 256, *sM1_q = sM1_s + 128;
  float* sM2_s = stats + 4 * 256, *sM2_q = sM2_s + 128;
  int*   seg    = (int*)(ws + seg_o);
  int*   seginv = (int*)(ws + seginv_o);
  int*   offp   = (int*)(ws + off_o);
  int*   cur    = (int*)(ws + cur_o);
  float* dinv   = (float*)(ws + dinv_o);
  int*   esrc   = (int*)(ws + esrc_o);
  int*   bsum   = (int*)(ws + bsum_o);
  int*   bo     = (int*)(ws + bo_o);
  float* spA    = (float*)(ws + spA_o);
  float* spC    = (float*)(ws + spC_o);
  float* spD    = (float*)(ws + spD_o);
  float* spH    = (float*)(ws + spH_o);
  float* Wpp    = (float*)(ws + Wpp_o);
  float* cv     = (float*)(ws + cv_o);
  float* bp     = (float*)(ws + bp_o);
  float* invG1  = (float*)(ws + invG1_o);
  float* invG2  = (float*)(ws + invG2_o);
  float* invM1  = (float*)(ws + invM1_o);

  hipMemsetAsync(ws + cntd_o, 0, zero_end - cntd_o, stream);

  // seg/seg_inv/degree + CSR build
  hipLaunchKernelGGL(k_setup, dim3(4096 + NE / 256), dim3(256), 0, stream,
                     Q, seg, seginv, cntinv, e_dst, cntd);
  hipLaunchKernelGGL(k_scan_a, dim3(256), dim3(256), 0, stream, cntd, offp, bsum);
  hipLaunchKernelGGL(k_scan_b, dim3(1), dim3(256), 0, stream, bsum, bo);
  hipLaunchKernelGGL(k_scan_c, dim3(256), dim3(256), 0, stream, offp, bo, cur, cntd, dinv);
  hipLaunchKernelGGL(k_scatter, dim3(NE / 256), dim3(256), 0, stream, e_src, e_dst, cur, esrc);

  // prelin GEMM: y = x @ prelin_W + prelin_b -> bufA, fused col stats -> sA
  hipLaunchKernelGGL(k_gemm, dim3(HW / 64), dim3(256), 0, stream,
                     x, prelin_W, prelin_b, bufA, CIN, 0, sA_s, sA_q,
                     (const float*)nullptr, (const float*)nullptr);
  // pool (mean over inverted lists) + inline BN -> spA
  hipLaunchKernelGGL(k_pool2, dim3(NSP), dim3(256), 0, stream,
                     bufA, seginv, cntinv, sA_s, sA_q, spA);

  // ---- GCN layer 1 ----
  hipLaunchKernelGGL(k_rstats, dim3(16), dim3(256), 0, stream,
                     spA, invG1, sG1_s, sG1_q, NSP,
                     (const float*)nullptr, (const float*)nullptr, 1.f);
  hipLaunchKernelGGL(k_prepw, dim3(1), dim3(256), 0, stream, sG1_s, sG1_q, (float)NSP,
                     gcn1_W, gcn1_b, (const float*)nullptr, (const float*)nullptr, 1.f,
                     Wpp, cv, bp);
  hipLaunchKernelGGL(k_gemm, dim3(NSP / 64), dim3(256), 0, stream,
                     spA, Wpp, bp, spC, 128, 0, (float*)nullptr, (float*)nullptr, invG1, cv);
  hipLaunchKernelGGL(k_gemm, dim3(NSP / 64), dim3(256), 0, stream,
                     A_norm, spC, (const float*)nullptr, spD, NSP, 1,
                     (float*)nullptr, (float*)nullptr, (const float*)nullptr, (const float*)nullptr);
  // ---- GCN layer 2 ----
  hipLaunchKernelGGL(k_rstats, dim3(16), dim3(256), 0, stream,
                     spD, invG2, sG2_s, sG2_q, NSP,
                     (const float*)nullptr, (const float*)nullptr, 1.f);
  hipLaunchKernelGGL(k_prepw, dim3(1), dim3(256), 0, stream, sG2_s, sG2_q, (float)NSP,
                     gcn2_W, gcn2_b, (const float*)nullptr, (const float*)nullptr, 1.f,
                     Wpp, cv, bp);
  hipLaunchKernelGGL(k_gemm, dim3(NSP / 64), dim3(256), 0, stream,
                     spD, Wpp, bp, spC, 128, 0, (float*)nullptr, (float*)nullptr, invG2, cv);
  hipLaunchKernelGGL(k_gemm, dim3(NSP / 64), dim3(256), 0, stream,
                     A_norm, spC, (const float*)nullptr, spH, NSP, 1,
                     (float*)nullptr, (float*)nullptr, (const float*)nullptr, (const float*)nullptr);
  // H1 -> spH

  // ---- MPNN layer 1: invn over h=bn(y), both BN affines folded into W ----
  hipLaunchKernelGGL(k_rstats, dim3(512), dim3(256), 0, stream,
                     bufA, invM1, sM1_s, sM1_q, HW, sA_s, sA_q, (float)HW);
  hipLaunchKernelGGL(k_prepw, dim3(1), dim3(256), 0, stream, sM1_s, sM1_q, (float)HW,
                     mpnn1_W, (const float*)nullptr, sA_s, sA_q, (float)HW,
                     Wpp, cv, bp);
  hipLaunchKernelGGL(k_gemm, dim3(HW / 64), dim3(256), 0, stream,
                     bufA, Wpp, bp, bufB, 128, 0, (float*)nullptr, (float*)nullptr, invM1, cv);
  // agg + fused l2norm + stats: bufA = l2norm(m1), stats -> sM2
  hipLaunchKernelGGL(k_agg, dim3(2048), dim3(256), 0, stream,
                     bufB, esrc, offp, dinv, mpnn1_b, bufA, 1, sM2_s, sM2_q);

  // ---- MPNN layer 2 ----
  hipLaunchKernelGGL(k_prepw, dim3(1), dim3(256), 0, stream, sM2_s, sM2_q, (float)HW,
                     mpnn2_W, (const float*)nullptr, (const float*)nullptr, (const float*)nullptr, 1.f,
                     Wpp, cv, bp);
  hipLaunchKernelGGL(k_gemm, dim3(HW / 64), dim3(256), 0, stream,
                     bufA, Wpp, bp, bufB, 128, 0, (float*)nullptr, (float*)nullptr,
                     (const float*)nullptr, (const float*)nullptr);
  hipLaunchKernelGGL(k_agg, dim3(2048), dim3(256), 0, stream,
                     bufB, esrc, offp, dinv, mpnn2_b, bufA, 0, (float*)nullptr, (float*)nullptr);
  // m2 -> bufA

  // final fused head
  hipLaunchKernelGGL(k_final, dim3(HW / 16), dim3(256), 0, stream,
                     bufA, spH, seg, out_W, out_b, outp);
}

// Round 4
// 727.509 us; speedup vs baseline: 1.7310x; 1.2322x over previous
//
#include <hip/hip_runtime.h>

#define HW 65536
#define NSP 1024
#define CIN 200
#define DH 128
#define NE 524288
#define NCLS 16
#define BN_EPS 1e-5f
#define LSLOPE 0.01f

// ---------------- fused: seg + seg_inv build (from one-hot Q) + edge degree ----
__global__ __launch_bounds__(256) void k_setup(
    const float* __restrict__ Q, int* __restrict__ seg, int* __restrict__ seg_inv,
    int* __restrict__ cnt_inv, const int* __restrict__ dst, int* __restrict__ cntd) {
  int b = blockIdx.x, t = threadIdx.x;
  if (b < 4096) {
    const float4* Q4 = (const float4*)Q;
    const int n4 = HW * NSP / 4;
    for (int i = b * 256 + t; i < n4; i += 4096 * 256) {
      float4 q = Q4[i];
      int base = i * 4;
      #pragma unroll
      for (int e = 0; e < 4; ++e) {
        float qv = (e == 0) ? q.x : (e == 1) ? q.y : (e == 2) ? q.z : q.w;
        if (qv > 0.5f) {
          int idx = base + e;
          int r = idx >> 10, s = idx & (NSP - 1);
          seg[r] = s;
          int p = atomicAdd(&cnt_inv[s], 1);
          seg_inv[s * 64 + p] = r;
        }
      }
    }
  } else {
    int e = (b - 4096) * 256 + t;
    if (e < NE) atomicAdd(&cntd[dst[e]], 1);
  }
}

// ---------------- prefix scan (3 stages) ----------------
__global__ void k_scan_a(const int* __restrict__ cntd, int* __restrict__ off,
                         int* __restrict__ bsum) {
  __shared__ int s[256];
  int t = threadIdx.x, b = blockIdx.x;
  int i = b * 256 + t;
  int v = cntd[i];
  s[t] = v; __syncthreads();
  for (int o = 1; o < 256; o <<= 1) {
    int x = (t >= o) ? s[t - o] : 0;
    __syncthreads();
    s[t] += x;
    __syncthreads();
  }
  off[i] = s[t] - v;
  if (t == 255) bsum[b] = s[t];
}
__global__ void k_scan_b(const int* __restrict__ bsum, int* __restrict__ bo) {
  __shared__ int s[256];
  int t = threadIdx.x;
  int v = bsum[t];
  s[t] = v; __syncthreads();
  for (int o = 1; o < 256; o <<= 1) {
    int x = (t >= o) ? s[t - o] : 0;
    __syncthreads();
    s[t] += x;
    __syncthreads();
  }
  bo[t] = s[t] - v;
}
__global__ void k_scan_c(int* __restrict__ off, const int* __restrict__ bo,
                         int* __restrict__ cur, const int* __restrict__ cntd,
                         float* __restrict__ dinv) {
  int i = blockIdx.x * blockDim.x + threadIdx.x;
  int v = off[i] + bo[i >> 8];
  off[i] = v;
  cur[i] = v;
  dinv[i] = rsqrtf((float)cntd[i] + 1.0f);
  if (i == 0) off[HW] = NE;
}

// ---------------- CSR scatter with precomputed edge weight ----------------
__global__ void k_scatter(const int* __restrict__ src, const int* __restrict__ dst,
                          int* __restrict__ cursor, const float* __restrict__ dinv,
                          int2* __restrict__ e2) {
  int e = blockIdx.x * blockDim.x + threadIdx.x;
  if (e < NE) {
    int d = dst[e], s = src[e];
    float w = dinv[d] * dinv[s];
    int pos = atomicAdd(&cursor[d], 1);
    e2[pos] = make_int2(s, __float_as_int(w));
  }
}

// ---------------- register-tiled GEMM with register double-buffered staging ----
// 256 thr -> 64 rows x 128 cols; thread 8x4. Epilogue:
//   invn/cvec: x = invn[row]*(acc - cvec[col]) + bias[col]; leaky; fused col-stats
__global__ __launch_bounds__(256) void k_gemm(
    const float* __restrict__ A, const float* __restrict__ B,
    const float* __restrict__ bias, float* __restrict__ C,
    int K, int leaky, float* __restrict__ sums, float* __restrict__ sumsq,
    const float* __restrict__ invn, const float* __restrict__ cvec) {
  __shared__ float As[32][68];
  __shared__ float Bs[32][128];
  __shared__ float lsum[128], lssq[128];
  int t = threadIdx.x;
  int c0 = (t & 31) * 4;
  int r0 = (t >> 5) * 8;
  int row0 = blockIdx.x * 64;
  int lr = t >> 2, lkb = (t & 3) * 8;
  float acc[8][4] = {};

  int nch = (K + 31) >> 5;
  float4 bpre[4];
  float4 apre0 = {0,0,0,0}, apre1 = {0,0,0,0};
  int cur_kc = min(32, K);

  // prefetch chunk 0
  {
    int kc = cur_kc;
    #pragma unroll
    for (int q = 0; q < 4; ++q) {
      int idx = t * 4 + q * 1024;
      int r = idx >> 7, c = idx & 127;
      bpre[q] = (r < kc) ? *(const float4*)&B[(size_t)r * 128 + c] : make_float4(0,0,0,0);
    }
    const float* ap = A + (size_t)(row0 + lr) * K + lkb;
    if (lkb + 4 <= kc) apre0 = *(const float4*)ap;
    if (lkb + 8 <= kc) apre1 = *(const float4*)(ap + 4);
  }

  for (int ch = 0; ch < nch; ++ch) {
    int kc = cur_kc;
    __syncthreads();
    // store staged regs -> LDS
    #pragma unroll
    for (int q = 0; q < 4; ++q) {
      int idx = t * 4 + q * 1024;
      int r = idx >> 7, c = idx & 127;
      if (r < kc) *(float4*)&Bs[r][c] = bpre[q];
    }
    if (lkb + 4 <= kc) {
      As[lkb + 0][lr] = apre0.x; As[lkb + 1][lr] = apre0.y;
      As[lkb + 2][lr] = apre0.z; As[lkb + 3][lr] = apre0.w;
    }
    if (lkb + 8 <= kc) {
      As[lkb + 4][lr] = apre1.x; As[lkb + 5][lr] = apre1.y;
      As[lkb + 6][lr] = apre1.z; As[lkb + 7][lr] = apre1.w;
    }
    __syncthreads();

    // prefetch next chunk while computing this one
    if (ch + 1 < nch) {
      int k1 = (ch + 1) * 32;
      int kn = min(32, K - k1);
      #pragma unroll
      for (int q = 0; q < 4; ++q) {
        int idx = t * 4 + q * 1024;
        int r = idx >> 7, c = idx & 127;
        bpre[q] = (r < kn) ? *(const float4*)&B[(size_t)(k1 + r) * 128 + c] : make_float4(0,0,0,0);
      }
      const float* ap = A + (size_t)(row0 + lr) * K + k1 + lkb;
      if (lkb + 4 <= kn) apre0 = *(const float4*)ap;
      if (lkb + 8 <= kn) apre1 = *(const float4*)(ap + 4);
      cur_kc = kn;
    }

    #pragma unroll 2
    for (int k = 0; k < kc; ++k) {
      float4 b4 = *(float4*)&Bs[k][c0];
      float4 a0 = *(float4*)&As[k][r0];
      float4 a1 = *(float4*)&As[k][r0 + 4];
      float av[8] = {a0.x, a0.y, a0.z, a0.w, a1.x, a1.y, a1.z, a1.w};
      float bv[4] = {b4.x, b4.y, b4.z, b4.w};
      #pragma unroll
      for (int r = 0; r < 8; ++r)
        #pragma unroll
        for (int c = 0; c < 4; ++c)
          acc[r][c] = fmaf(av[r], bv[c], acc[r][c]);
    }
  }

  float bb[4] = {0.f, 0.f, 0.f, 0.f};
  if (bias) { bb[0] = bias[c0]; bb[1] = bias[c0+1]; bb[2] = bias[c0+2]; bb[3] = bias[c0+3]; }
  float cv[4] = {0.f, 0.f, 0.f, 0.f};
  float inr[8];
  if (invn) {
    cv[0] = cvec[c0]; cv[1] = cvec[c0+1]; cv[2] = cvec[c0+2]; cv[3] = cvec[c0+3];
    #pragma unroll
    for (int r = 0; r < 8; ++r) inr[r] = invn[row0 + r0 + r];
  }
  float colsum[4] = {}, colsq[4] = {};
  #pragma unroll
  for (int r = 0; r < 8; ++r) {
    float4 o;
    float v[4];
    #pragma unroll
    for (int c = 0; c < 4; ++c) {
      float x;
      if (invn) x = inr[r] * (acc[r][c] - cv[c]) + bb[c];
      else      x = acc[r][c] + bb[c];
      if (leaky) x = (x >= 0.f) ? x : LSLOPE * x;
      v[c] = x;
      colsum[c] += x; colsq[c] += x * x;
    }
    o.x = v[0]; o.y = v[1]; o.z = v[2]; o.w = v[3];
    *(float4*)&C[(size_t)(row0 + r0 + r) * 128 + c0] = o;
  }
  if (sums) {
    __syncthreads();
    if (t < 128) { lsum[t] = 0.f; lssq[t] = 0.f; }
    __syncthreads();
    #pragma unroll
    for (int c = 0; c < 4; ++c) {
      atomicAdd(&lsum[c0 + c], colsum[c]);
      atomicAdd(&lssq[c0 + c], colsq[c]);
    }
    __syncthreads();
    if (t < 128) { atomicAdd(&sums[t], lsum[t]); atomicAdd(&sumsq[t], lssq[t]); }
  }
}

// ---------------- superpixel mean-pool via inverted index + inline BN ----------
__global__ __launch_bounds__(256) void k_pool2(
    const float* __restrict__ y, const int* __restrict__ seg_inv,
    const int* __restrict__ cnt_inv, const float* __restrict__ sAs,
    const float* __restrict__ sAq, float* __restrict__ spA) {
  __shared__ float part[128];
  int sp = blockIdx.x, t = threadIdx.x;
  int d = t & 127, h = t >> 7;
  int cnt = cnt_inv[sp];
  float acc = 0.f;
  for (int r = h; r < cnt; r += 2)
    acc += y[(size_t)seg_inv[sp * 64 + r] * 128 + d];
  if (h) part[d] = acc;
  __syncthreads();
  if (!h) {
    float s = acc + part[d];
    float mA = sAs[d] / (float)HW;
    float rsA = rsqrtf(sAq[d] / (float)HW - mA * mA + BN_EPS);
    spA[sp * 128 + d] = (s / (float)cnt - mA) * rsA;
  }
}

// ------- row inv-norms (after optional pre-BN affine) + col-stats of normalized --
__global__ void k_rstats(const float* __restrict__ in, float* __restrict__ invn,
                         float* __restrict__ sums, float* __restrict__ sumsq, int M,
                         const float* __restrict__ preS, const float* __restrict__ preQ,
                         float precnt) {
  __shared__ float lsum[128], lssq[128];
  int t = threadIdx.x;
  if (t < 128) { lsum[t] = 0.f; lssq[t] = 0.f; }
  __syncthreads();
  int wid = t >> 6, lane = t & 63, d0 = lane * 2;
  float m0 = 0.f, m1 = 0.f, r0 = 1.f, r1 = 1.f;
  if (preS) {
    m0 = preS[d0] / precnt;
    r0 = rsqrtf(preQ[d0] / precnt - m0 * m0 + BN_EPS);
    m1 = preS[d0 + 1] / precnt;
    r1 = rsqrtf(preQ[d0 + 1] / precnt - m1 * m1 + BN_EPS);
  }
  float cs0 = 0.f, cs1 = 0.f, cq0 = 0.f, cq1 = 0.f;
  for (int row = blockIdx.x * 4 + wid; row < M; row += gridDim.x * 4) {
    float2 v = *(const float2*)(in + (size_t)row * 128 + d0);
    v.x = (v.x - m0) * r0;
    v.y = (v.y - m1) * r1;
    float ss = v.x * v.x + v.y * v.y;
    #pragma unroll
    for (int o = 1; o < 64; o <<= 1) ss += __shfl_xor(ss, o);
    float sc = 1.0f / fmaxf(sqrtf(ss), 1e-12f);
    if (lane == 0) invn[row] = sc;
    float nx = v.x * sc, ny = v.y * sc;
    cs0 += nx; cs1 += ny; cq0 += nx * nx; cq1 += ny * ny;
  }
  atomicAdd(&lsum[d0], cs0); atomicAdd(&lsum[d0 + 1], cs1);
  atomicAdd(&lssq[d0], cq0); atomicAdd(&lssq[d0 + 1], cq1);
  __syncthreads();
  if (t < 128) { atomicAdd(&sums[t], lsum[t]); atomicAdd(&sumsq[t], lssq[t]); }
}

// -- fold BN(s) into W: W''=rsA*rs2*W; cvec=mA@W''; bp=base-m2@(rs2*W) ----------
// coalesced float4 version: thread t -> col quad kq=(t&31)*4, j-group jg=t>>5
__global__ void k_prepw(const float* __restrict__ sums, const float* __restrict__ sumsq,
                        float cnt, const float* __restrict__ W,
                        const float* __restrict__ base,
                        const float* __restrict__ preS, const float* __restrict__ preQ,
                        float precnt,
                        float* __restrict__ Wpp, float* __restrict__ cvec,
                        float* __restrict__ bp) {
  __shared__ float redc[8][128], redb[8][128];
  int t = threadIdx.x;
  int kq = (t & 31) * 4, jg = t >> 5;
  float cx = 0.f, cy = 0.f, cz = 0.f, cw = 0.f;
  float bx = 0.f, by = 0.f, bz = 0.f, bw = 0.f;
  for (int j = jg; j < 128; j += 8) {
    float m2 = sums[j] / cnt;
    float rs2 = rsqrtf(sumsq[j] / cnt - m2 * m2 + BN_EPS);
    float mA = 0.f, rsA = 1.f;
    if (preS) {
      mA = preS[j] / precnt;
      rsA = rsqrtf(preQ[j] / precnt - mA * mA + BN_EPS);
    }
    float4 w = *(const float4*)&W[j * 128 + kq];
    float s2 = rs2, sA = rsA * rs2;
    float4 wpp = make_float4(sA * w.x, sA * w.y, sA * w.z, sA * w.w);
    *(float4*)&Wpp[j * 128 + kq] = wpp;
    cx = fmaf(mA, wpp.x, cx); cy = fmaf(mA, wpp.y, cy);
    cz = fmaf(mA, wpp.z, cz); cw = fmaf(mA, wpp.w, cw);
    float m2s = m2 * s2;
    bx = fmaf(m2s, w.x, bx); by = fmaf(m2s, w.y, by);
    bz = fmaf(m2s, w.z, bz); bw = fmaf(m2s, w.w, bw);
  }
  *(float4*)&redc[jg][kq] = make_float4(cx, cy, cz, cw);
  *(float4*)&redb[jg][kq] = make_float4(bx, by, bz, bw);
  __syncthreads();
  if (t < 32) {
    int k4 = t * 4;
    float4 sc = *(float4*)&redc[0][k4];
    float4 sb = *(float4*)&redb[0][k4];
    #pragma unroll
    for (int g = 1; g < 8; ++g) {
      float4 ac = *(float4*)&redc[g][k4];
      float4 ab = *(float4*)&redb[g][k4];
      sc.x += ac.x; sc.y += ac.y; sc.z += ac.z; sc.w += ac.w;
      sb.x += ab.x; sb.y += ab.y; sb.z += ab.z; sb.w += ab.w;
    }
    *(float4*)&cvec[k4] = sc;
    float4 bs = base ? *(const float4*)&base[k4] : make_float4(0,0,0,0);
    *(float4*)&bp[k4] = make_float4(bs.x - sb.x, bs.y - sb.y, bs.z - sb.z, bs.w - sb.w);
  }
}

// ---- CSR edge aggregation: float4 lanes, 2 edges in flight per wave ----
__global__ __launch_bounds__(256) void k_agg(
    const float* __restrict__ xw, const int2* __restrict__ e2,
    const int* __restrict__ off, const float* __restrict__ dinv,
    const float* __restrict__ bias, float* __restrict__ out,
    int do_norm, float* __restrict__ sums, float* __restrict__ sumsq) {
  __shared__ float lsum[128], lssq[128];
  int t = threadIdx.x;
  if (do_norm) {
    if (t < 128) { lsum[t] = 0.f; lssq[t] = 0.f; }
    __syncthreads();
  }
  int wid = t >> 6, lane = t & 63;
  int hi = lane >> 5, l32 = lane & 31;
  const float4* xw4 = (const float4*)xw;
  float4 bb = ((const float4*)bias)[l32];
  float cs[4] = {}, cq[4] = {};
  for (int i = blockIdx.x * 4 + wid; i < HW; i += gridDim.x * 4) {
    float4 acc = make_float4(0.f, 0.f, 0.f, 0.f);
    int s0 = off[i], s1 = off[i + 1];
    for (int kk = s0 + hi; kk < s1; kk += 2) {
      int2 e = e2[kk];
      float w = __int_as_float(e.y);
      float4 v = xw4[(size_t)e.x * 32 + l32];
      acc.x = fmaf(w, v.x, acc.x); acc.y = fmaf(w, v.y, acc.y);
      acc.z = fmaf(w, v.z, acc.z); acc.w = fmaf(w, v.w, acc.w);
    }
    // combine half-waves
    acc.x += __shfl_xor(acc.x, 32); acc.y += __shfl_xor(acc.y, 32);
    acc.z += __shfl_xor(acc.z, 32); acc.w += __shfl_xor(acc.w, 32);
    if (hi == 0) {
      float di = dinv[i];
      float inv_deg = di * di;
      float4 xi = xw4[(size_t)i * 32 + l32];
      float r[4];
      r[0] = fmaf(xi.x, inv_deg, acc.x) + bb.x;
      r[1] = fmaf(xi.y, inv_deg, acc.y) + bb.y;
      r[2] = fmaf(xi.z, inv_deg, acc.z) + bb.z;
      r[3] = fmaf(xi.w, inv_deg, acc.w) + bb.w;
      #pragma unroll
      for (int c = 0; c < 4; ++c) r[c] = (r[c] >= 0.f) ? r[c] : LSLOPE * r[c];
      if (do_norm) {
        float ss = r[0]*r[0] + r[1]*r[1] + r[2]*r[2] + r[3]*r[3];
        #pragma unroll
        for (int o = 1; o < 32; o <<= 1) ss += __shfl_xor(ss, o);
        float sc = 1.0f / fmaxf(sqrtf(ss), 1e-12f);
        #pragma unroll
        for (int c = 0; c < 4; ++c) {
          r[c] *= sc;
          cs[c] += r[c]; cq[c] += r[c] * r[c];
        }
      }
      ((float4*)out)[(size_t)i * 32 + l32] = make_float4(r[0], r[1], r[2], r[3]);
    }
  }
  if (do_norm) {
    if (hi == 0) {
      #pragma unroll
      for (int c = 0; c < 4; ++c) {
        atomicAdd(&lsum[l32 * 4 + c], cs[c]);
        atomicAdd(&lssq[l32 * 4 + c], cq[c]);
      }
    }
    __syncthreads();
    if (t < 128) { atomicAdd(&sums[t], lsum[t]); atomicAdd(&sumsq[t], lssq[t]); }
  }
}

// ---------------- final: (m2 + H1[seg]) @ out_W + out_b -> softmax --------------
__global__ __launch_bounds__(256) void k_final(
    const float* __restrict__ m2, const float* __restrict__ H1,
    const int* __restrict__ seg, const float* __restrict__ Wout,
    const float* __restrict__ bout, float* __restrict__ out) {
  __shared__ float rb[16][132];
  __shared__ float WL[128 * 16];
  int t = threadIdx.x;
  int row0 = blockIdx.x * 16;
  for (int idx = t; idx < 128 * NCLS; idx += 256) WL[idx] = Wout[idx];
  for (int idx = t; idx < 16 * 128; idx += 256) {
    int r = idx >> 7, d = idx & 127;
    int row = row0 + r;
    rb[r][d] = m2[(size_t)row * 128 + d] + H1[(size_t)seg[row] * 128 + d];
  }
  __syncthreads();
  int c = t & 15, r = t >> 4;
  float acc = bout[c];
  #pragma unroll 8
  for (int d = 0; d < 128; ++d) acc = fmaf(rb[r][d], WL[d * 16 + c], acc);
  float mx = acc;
  #pragma unroll
  for (int o = 1; o < 16; o <<= 1) mx = fmaxf(mx, __shfl_xor(mx, o));
  float e = expf(acc - mx);
  float s = e;
  #pragma unroll
  for (int o = 1; o < 16; o <<= 1) s += __shfl_xor(s, o);
  out[(size_t)(row0 + r) * NCLS + c] = e / s;
}

// =================================================================================
extern "C" void kernel_launch(void* const* d_in, const int* in_sizes, int n_in,
                              void* d_out, int out_size, void* d_ws, size_t ws_size,
                              hipStream_t stream) {
  const float* x        = (const float*)d_in[0];
  const float* Q        = (const float*)d_in[1];
  const float* A_norm   = (const float*)d_in[2];
  const int*   ei       = (const int*)d_in[3];
  const float* prelin_W = (const float*)d_in[4];
  const float* prelin_b = (const float*)d_in[5];
  const float* gcn1_W   = (const float*)d_in[6];
  const float* gcn1_b   = (const float*)d_in[7];
  const float* gcn2_W   = (const float*)d_in[8];
  const float* gcn2_b   = (const float*)d_in[9];
  const float* mpnn1_W  = (const float*)d_in[10];
  const float* mpnn1_b  = (const float*)d_in[11];
  const float* mpnn2_W  = (const float*)d_in[12];
  const float* mpnn2_b  = (const float*)d_in[13];
  const float* out_W    = (const float*)d_in[14];
  const float* out_b    = (const float*)d_in[15];
  float* outp = (float*)d_out;
  const int* e_src = ei;
  const int* e_dst = ei + NE;

  char* ws = (char*)d_ws;
  size_t o = 0;
  auto alloc = [&](size_t bytes) { size_t r = o; o = (o + bytes + 255) & ~255ULL; return r; };
  size_t bufA_o   = alloc((size_t)HW * 128 * 4);
  size_t bufB_o   = alloc((size_t)HW * 128 * 4);
  // ---- zero group start ----
  size_t cntd_o   = alloc((size_t)HW * 4);
  size_t cntinv_o = alloc((size_t)NSP * 4);
  size_t stats_o  = alloc(5 * 256 * 4);
  size_t zero_end = o;
  // ---- zero group end ----
  size_t seg_o    = alloc((size_t)HW * 4);
  size_t seginv_o = alloc((size_t)HW * 4);
  size_t off_o    = alloc((size_t)(HW + 1) * 4);
  size_t cur_o    = alloc((size_t)HW * 4);
  size_t dinv_o   = alloc((size_t)HW * 4);
  size_t e2_o     = alloc((size_t)NE * 8);
  size_t bsum_o   = alloc(256 * 4);
  size_t bo_o     = alloc(256 * 4);
  size_t spA_o    = alloc((size_t)NSP * 128 * 4);
  size_t spC_o    = alloc((size_t)NSP * 128 * 4);
  size_t spD_o    = alloc((size_t)NSP * 128 * 4);
  size_t spH_o    = alloc((size_t)NSP * 128 * 4);
  size_t Wpp_o    = alloc(128 * 128 * 4);
  size_t cv_o     = alloc(128 * 4);
  size_t bp_o     = alloc(128 * 4);
  size_t invG1_o  = alloc((size_t)NSP * 4);
  size_t invG2_o  = alloc((size_t)NSP * 4);
  size_t invM1_o  = alloc((size_t)HW * 4);
  if (o > ws_size) return;

  float* bufA   = (float*)(ws + bufA_o);
  float* bufB   = (float*)(ws + bufB_o);
  int*   cntd   = (int*)(ws + cntd_o);
  int*   cntinv = (int*)(ws + cntinv_o);
  float* stats  = (float*)(ws + stats_o);
  float* sA_s  = stats + 0 * 256, *sA_q  = sA_s + 128;
  float* sG1_s = stats + 1 * 256, *sG1_q = sG1_s + 128;
  float* sG2_s = stats + 2 * 256, *sG2_q = sG2_s + 128;
  float* sM1_s = stats + 3 * 256, *sM1_q = sM1_s + 128;
  float* sM2_s = stats + 4 * 256, *sM2_q = sM2_s + 128;
  int*   seg    = (int*)(ws + seg_o);
  int*   seginv = (int*)(ws + seginv_o);
  int*   offp   = (int*)(ws + off_o);
  int*   cur    = (int*)(ws + cur_o);
  float* dinv   = (float*)(ws + dinv_o);
  int2*  e2     = (int2*)(ws + e2_o);
  int*   bsum   = (int*)(ws + bsum_o);
  int*   bo     = (int*)(ws + bo_o);
  float* spA    = (float*)(ws + spA_o);
  float* spC    = (float*)(ws + spC_o);
  float* spD    = (float*)(ws + spD_o);
  float* spH    = (float*)(ws + spH_o);
  float* Wpp    = (float*)(ws + Wpp_o);
  float* cv     = (float*)(ws + cv_o);
  float* bp     = (float*)(ws + bp_o);
  float* invG1  = (float*)(ws + invG1_o);
  float* invG2  = (float*)(ws + invG2_o);
  float* invM1  = (float*)(ws + invM1_o);

  hipMemsetAsync(ws + cntd_o, 0, zero_end - cntd_o, stream);

  // seg/seg_inv/degree + CSR build
  hipLaunchKernelGGL(k_setup, dim3(4096 + NE / 256), dim3(256), 0, stream,
                     Q, seg, seginv, cntinv, e_dst, cntd);
  hipLaunchKernelGGL(k_scan_a, dim3(256), dim3(256), 0, stream, cntd, offp, bsum);
  hipLaunchKernelGGL(k_scan_b, dim3(1), dim3(256), 0, stream, bsum, bo);
  hipLaunchKernelGGL(k_scan_c, dim3(256), dim3(256), 0, stream, offp, bo, cur, cntd, dinv);
  hipLaunchKernelGGL(k_scatter, dim3(NE / 256), dim3(256), 0, stream, e_src, e_dst, cur, dinv, e2);

  // prelin GEMM: y = x @ prelin_W + prelin_b -> bufA, fused col stats -> sA
  hipLaunchKernelGGL(k_gemm, dim3(HW / 64), dim3(256), 0, stream,
                     x, prelin_W, prelin_b, bufA, CIN, 0, sA_s, sA_q,
                     (const float*)nullptr, (const float*)nullptr);
  // pool (mean over inverted lists) + inline BN -> spA
  hipLaunchKernelGGL(k_pool2, dim3(NSP), dim3(256), 0, stream,
                     bufA, seginv, cntinv, sA_s, sA_q, spA);

  // ---- GCN layer 1 ----
  hipLaunchKernelGGL(k_rstats, dim3(16), dim3(256), 0, stream,
                     spA, invG1, sG1_s, sG1_q, NSP,
                     (const float*)nullptr, (const float*)nullptr, 1.f);
  hipLaunchKernelGGL(k_prepw, dim3(1), dim3(256), 0, stream, sG1_s, sG1_q, (float)NSP,
                     gcn1_W, gcn1_b, (const float*)nullptr, (const float*)nullptr, 1.f,
                     Wpp, cv, bp);
  hipLaunchKernelGGL(k_gemm, dim3(NSP / 64), dim3(256), 0, stream,
                     spA, Wpp, bp, spC, 128, 0, (float*)nullptr, (float*)nullptr, invG1, cv);
  hipLaunchKernelGGL(k_gemm, dim3(NSP / 64), dim3(256), 0, stream,
                     A_norm, spC, (const float*)nullptr, spD, NSP, 1,
                     (float*)nullptr, (float*)nullptr, (const float*)nullptr, (const float*)nullptr);
  // ---- GCN layer 2 ----
  hipLaunchKernelGGL(k_rstats, dim3(16), dim3(256), 0, stream,
                     spD, invG2, sG2_s, sG2_q, NSP,
                     (const float*)nullptr, (const float*)nullptr, 1.f);
  hipLaunchKernelGGL(k_prepw, dim3(1), dim3(256), 0, stream, sG2_s, sG2_q, (float)NSP,
                     gcn2_W, gcn2_b, (const float*)nullptr, (const float*)nullptr, 1.f,
                     Wpp, cv, bp);
  hipLaunchKernelGGL(k_gemm, dim3(NSP / 64), dim3(256), 0, stream,
                     spD, Wpp, bp, spC, 128, 0, (float*)nullptr, (float*)nullptr, invG2, cv);
  hipLaunchKernelGGL(k_gemm, dim3(NSP / 64), dim3(256), 0, stream,
                     A_norm, spC, (const float*)nullptr, spH, NSP, 1,
                     (float*)nullptr, (float*)nullptr, (const float*)nullptr, (const float*)nullptr);
  // H1 -> spH

  // ---- MPNN layer 1: invn over h=bn(y), both BN affines folded into W ----
  hipLaunchKernelGGL(k_rstats, dim3(512), dim3(256), 0, stream,
                     bufA, invM1, sM1_s, sM1_q, HW, sA_s, sA_q, (float)HW);
  hipLaunchKernelGGL(k_prepw, dim3(1), dim3(256), 0, stream, sM1_s, sM1_q, (float)HW,
                     mpnn1_W, (const float*)nullptr, sA_s, sA_q, (float)HW,
                     Wpp, cv, bp);
  hipLaunchKernelGGL(k_gemm, dim3(HW / 64), dim3(256), 0, stream,
                     bufA, Wpp, bp, bufB, 128, 0, (float*)nullptr, (float*)nullptr, invM1, cv);
  // agg + fused l2norm + stats: bufA = l2norm(m1), stats -> sM2
  hipLaunchKernelGGL(k_agg, dim3(2048), dim3(256), 0, stream,
                     bufB, e2, offp, dinv, mpnn1_b, bufA, 1, sM2_s, sM2_q);

  // ---- MPNN layer 2 ----
  hipLaunchKernelGGL(k_prepw, dim3(1), dim3(256), 0, stream, sM2_s, sM2_q, (float)HW,
                     mpnn2_W, (const float*)nullptr, (const float*)nullptr, (const float*)nullptr, 1.f,
                     Wpp, cv, bp);
  hipLaunchKernelGGL(k_gemm, dim3(HW / 64), dim3(256), 0, stream,
                     bufA, Wpp, bp, bufB, 128, 0, (float*)nullptr, (float*)nullptr,
                     (const float*)nullptr, (const float*)nullptr);
  hipLaunchKernelGGL(k_agg, dim3(2048), dim3(256), 0, stream,
                     bufB, e2, offp, dinv, mpnn2_b, bufA, 0, (float*)nullptr, (float*)nullptr);
  // m2 -> bufA

  // final fused head
  hipLaunchKernelGGL(k_final, dim3(HW / 16), dim3(256), 0, stream,
                     bufA, spH, seg, out_W, out_b, outp);
}

// Round 5
// 620.086 us; speedup vs baseline: 2.0308x; 1.1732x over previous
//
#include <hip/hip_runtime.h>

#define HW 65536
#define NSP 1024
#define CIN 200
#define DH 128
#define NE 524288
#define NCLS 16
#define BN_EPS 1e-5f
#define LSLOPE 0.01f

// ---------------- fused: seg + seg_inv build (from one-hot Q) + edge degree ----
__global__ __launch_bounds__(256) void k_setup(
    const float* __restrict__ Q, int* __restrict__ seg, int* __restrict__ seg_inv,
    int* __restrict__ cnt_inv, const int* __restrict__ dst, int* __restrict__ cntd) {
  int b = blockIdx.x, t = threadIdx.x;
  if (b < 4096) {
    const float4* Q4 = (const float4*)Q;
    const int n4 = HW * NSP / 4;
    for (int i = b * 256 + t; i < n4; i += 4096 * 256) {
      float4 q = Q4[i];
      int base = i * 4;
      #pragma unroll
      for (int e = 0; e < 4; ++e) {
        float qv = (e == 0) ? q.x : (e == 1) ? q.y : (e == 2) ? q.z : q.w;
        if (qv > 0.5f) {
          int idx = base + e;
          int r = idx >> 10, s = idx & (NSP - 1);
          seg[r] = s;
          int p = atomicAdd(&cnt_inv[s], 1);
          seg_inv[s * 64 + p] = r;
        }
      }
    }
  } else {
    int e = (b - 4096) * 256 + t;
    if (e < NE) atomicAdd(&cntd[dst[e]], 1);
  }
}

// ---------------- prefix scan (3 stages) ----------------
__global__ void k_scan_a(const int* __restrict__ cntd, int* __restrict__ off,
                         int* __restrict__ bsum) {
  __shared__ int s[256];
  int t = threadIdx.x, b = blockIdx.x;
  int i = b * 256 + t;
  int v = cntd[i];
  s[t] = v; __syncthreads();
  for (int o = 1; o < 256; o <<= 1) {
    int x = (t >= o) ? s[t - o] : 0;
    __syncthreads();
    s[t] += x;
    __syncthreads();
  }
  off[i] = s[t] - v;
  if (t == 255) bsum[b] = s[t];
}
__global__ void k_scan_b(const int* __restrict__ bsum, int* __restrict__ bo) {
  __shared__ int s[256];
  int t = threadIdx.x;
  int v = bsum[t];
  s[t] = v; __syncthreads();
  for (int o = 1; o < 256; o <<= 1) {
    int x = (t >= o) ? s[t - o] : 0;
    __syncthreads();
    s[t] += x;
    __syncthreads();
  }
  bo[t] = s[t] - v;
}
__global__ void k_scan_c(int* __restrict__ off, const int* __restrict__ bo,
                         int* __restrict__ cur, const int* __restrict__ cntd,
                         float* __restrict__ dinv) {
  int i = blockIdx.x * blockDim.x + threadIdx.x;
  int v = off[i] + bo[i >> 8];
  off[i] = v;
  cur[i] = v;
  dinv[i] = rsqrtf((float)cntd[i] + 1.0f);
  if (i == 0) off[HW] = NE;
}

// ---------------- CSR scatter with precomputed edge weight ----------------
__global__ void k_scatter(const int* __restrict__ src, const int* __restrict__ dst,
                          int* __restrict__ cursor, const float* __restrict__ dinv,
                          int2* __restrict__ e2) {
  int e = blockIdx.x * blockDim.x + threadIdx.x;
  if (e < NE) {
    int d = dst[e], s = src[e];
    float w = dinv[d] * dinv[s];
    int pos = atomicAdd(&cursor[d], 1);
    e2[pos] = make_int2(s, __float_as_int(w));
  }
}

// ---------------- register-tiled GEMM with register double-buffered staging ----
__global__ __launch_bounds__(256) void k_gemm(
    const float* __restrict__ A, const float* __restrict__ B,
    const float* __restrict__ bias, float* __restrict__ C,
    int K, int leaky, float* __restrict__ sums, float* __restrict__ sumsq,
    const float* __restrict__ invn, const float* __restrict__ cvec) {
  __shared__ float As[32][68];
  __shared__ float Bs[32][128];
  __shared__ float lsum[128], lssq[128];
  int t = threadIdx.x;
  int c0 = (t & 31) * 4;
  int r0 = (t >> 5) * 8;
  int row0 = blockIdx.x * 64;
  int lr = t >> 2, lkb = (t & 3) * 8;
  float acc[8][4] = {};

  int nch = (K + 31) >> 5;
  float4 bpre[4];
  float4 apre0 = {0,0,0,0}, apre1 = {0,0,0,0};
  int cur_kc = min(32, K);

  {
    int kc = cur_kc;
    #pragma unroll
    for (int q = 0; q < 4; ++q) {
      int idx = t * 4 + q * 1024;
      int r = idx >> 7, c = idx & 127;
      bpre[q] = (r < kc) ? *(const float4*)&B[(size_t)r * 128 + c] : make_float4(0,0,0,0);
    }
    const float* ap = A + (size_t)(row0 + lr) * K + lkb;
    if (lkb + 4 <= kc) apre0 = *(const float4*)ap;
    if (lkb + 8 <= kc) apre1 = *(const float4*)(ap + 4);
  }

  for (int ch = 0; ch < nch; ++ch) {
    int kc = cur_kc;
    __syncthreads();
    #pragma unroll
    for (int q = 0; q < 4; ++q) {
      int idx = t * 4 + q * 1024;
      int r = idx >> 7, c = idx & 127;
      if (r < kc) *(float4*)&Bs[r][c] = bpre[q];
    }
    if (lkb + 4 <= kc) {
      As[lkb + 0][lr] = apre0.x; As[lkb + 1][lr] = apre0.y;
      As[lkb + 2][lr] = apre0.z; As[lkb + 3][lr] = apre0.w;
    }
    if (lkb + 8 <= kc) {
      As[lkb + 4][lr] = apre1.x; As[lkb + 5][lr] = apre1.y;
      As[lkb + 6][lr] = apre1.z; As[lkb + 7][lr] = apre1.w;
    }
    __syncthreads();

    if (ch + 1 < nch) {
      int k1 = (ch + 1) * 32;
      int kn = min(32, K - k1);
      #pragma unroll
      for (int q = 0; q < 4; ++q) {
        int idx = t * 4 + q * 1024;
        int r = idx >> 7, c = idx & 127;
        bpre[q] = (r < kn) ? *(const float4*)&B[(size_t)(k1 + r) * 128 + c] : make_float4(0,0,0,0);
      }
      const float* ap = A + (size_t)(row0 + lr) * K + k1 + lkb;
      if (lkb + 4 <= kn) apre0 = *(const float4*)ap;
      if (lkb + 8 <= kn) apre1 = *(const float4*)(ap + 4);
      cur_kc = kn;
    }

    #pragma unroll 2
    for (int k = 0; k < kc; ++k) {
      float4 b4 = *(float4*)&Bs[k][c0];
      float4 a0 = *(float4*)&As[k][r0];
      float4 a1 = *(float4*)&As[k][r0 + 4];
      float av[8] = {a0.x, a0.y, a0.z, a0.w, a1.x, a1.y, a1.z, a1.w};
      float bv[4] = {b4.x, b4.y, b4.z, b4.w};
      #pragma unroll
      for (int r = 0; r < 8; ++r)
        #pragma unroll
        for (int c = 0; c < 4; ++c)
          acc[r][c] = fmaf(av[r], bv[c], acc[r][c]);
    }
  }

  float bb[4] = {0.f, 0.f, 0.f, 0.f};
  if (bias) { bb[0] = bias[c0]; bb[1] = bias[c0+1]; bb[2] = bias[c0+2]; bb[3] = bias[c0+3]; }
  float cv[4] = {0.f, 0.f, 0.f, 0.f};
  float inr[8];
  if (invn) {
    cv[0] = cvec[c0]; cv[1] = cvec[c0+1]; cv[2] = cvec[c0+2]; cv[3] = cvec[c0+3];
    #pragma unroll
    for (int r = 0; r < 8; ++r) inr[r] = invn[row0 + r0 + r];
  }
  float colsum[4] = {}, colsq[4] = {};
  #pragma unroll
  for (int r = 0; r < 8; ++r) {
    float4 o;
    float v[4];
    #pragma unroll
    for (int c = 0; c < 4; ++c) {
      float x;
      if (invn) x = inr[r] * (acc[r][c] - cv[c]) + bb[c];
      else      x = acc[r][c] + bb[c];
      if (leaky) x = (x >= 0.f) ? x : LSLOPE * x;
      v[c] = x;
      colsum[c] += x; colsq[c] += x * x;
    }
    o.x = v[0]; o.y = v[1]; o.z = v[2]; o.w = v[3];
    *(float4*)&C[(size_t)(row0 + r0 + r) * 128 + c0] = o;
  }
  if (sums) {
    __syncthreads();
    if (t < 128) { lsum[t] = 0.f; lssq[t] = 0.f; }
    __syncthreads();
    #pragma unroll
    for (int c = 0; c < 4; ++c) {
      atomicAdd(&lsum[c0 + c], colsum[c]);
      atomicAdd(&lssq[c0 + c], colsq[c]);
    }
    __syncthreads();
    if (t < 128) { atomicAdd(&sums[t], lsum[t]); atomicAdd(&sumsq[t], lssq[t]); }
  }
}

// ------ split-K GEMM: C[M,128] += A[M,K(chunk)] @ B[K,128], atomic partials -----
// grid (M/64, K/KS); output is PRE-ACTIVATION (no bias/leaky), C must be zeroed.
__global__ __launch_bounds__(256) void k_gemm_ks(
    const float* __restrict__ A, const float* __restrict__ B,
    float* __restrict__ C, int K, int ks) {
  __shared__ float As[32][68];
  __shared__ float Bs[32][128];
  int t = threadIdx.x;
  int c0 = (t & 31) * 4;
  int r0 = (t >> 5) * 8;
  int row0 = blockIdx.x * 64;
  int kbeg = blockIdx.y * ks;
  int kend = min(K, kbeg + ks);
  int lr = t >> 2, lkb = (t & 3) * 8;
  float acc[8][4] = {};

  for (int k0 = kbeg; k0 < kend; k0 += 32) {
    int kc = min(32, kend - k0);
    __syncthreads();
    for (int idx = t * 4; idx < kc * 128; idx += 1024) {
      *(float4*)&Bs[idx >> 7][idx & 127] = *(const float4*)&B[(size_t)k0 * 128 + idx];
    }
    if (lkb < kc) {
      const float* ap = A + (size_t)(row0 + lr) * K + k0 + lkb;
      float4 v0 = *(const float4*)ap;
      float4 v1 = *(const float4*)(ap + 4);
      As[lkb + 0][lr] = v0.x; As[lkb + 1][lr] = v0.y;
      As[lkb + 2][lr] = v0.z; As[lkb + 3][lr] = v0.w;
      As[lkb + 4][lr] = v1.x; As[lkb + 5][lr] = v1.y;
      As[lkb + 6][lr] = v1.z; As[lkb + 7][lr] = v1.w;
    }
    __syncthreads();
    #pragma unroll 2
    for (int k = 0; k < kc; ++k) {
      float4 b4 = *(float4*)&Bs[k][c0];
      float4 a0 = *(float4*)&As[k][r0];
      float4 a1 = *(float4*)&As[k][r0 + 4];
      float av[8] = {a0.x, a0.y, a0.z, a0.w, a1.x, a1.y, a1.z, a1.w};
      float bv[4] = {b4.x, b4.y, b4.z, b4.w};
      #pragma unroll
      for (int r = 0; r < 8; ++r)
        #pragma unroll
        for (int c = 0; c < 4; ++c)
          acc[r][c] = fmaf(av[r], bv[c], acc[r][c]);
    }
  }
  #pragma unroll
  for (int r = 0; r < 8; ++r)
    #pragma unroll
    for (int c = 0; c < 4; ++c)
      atomicAdd(&C[(size_t)(row0 + r0 + r) * 128 + c0 + c], acc[r][c]);
}

// ---------------- superpixel mean-pool: float4 lanes, 8 row-groups, inline BN ---
__global__ __launch_bounds__(256) void k_pool2(
    const float* __restrict__ y, const int* __restrict__ seg_inv,
    const int* __restrict__ cnt_inv, const float* __restrict__ sAs,
    const float* __restrict__ sAq, float* __restrict__ spA) {
  __shared__ float4 part[8][32];
  int sp = blockIdx.x, t = threadIdx.x;
  int l32 = t & 31, g = t >> 5;
  int cnt = cnt_inv[sp];
  const float4* y4 = (const float4*)y;
  const int* lst = seg_inv + sp * 64;
  float4 acc = make_float4(0.f, 0.f, 0.f, 0.f);
  int r = g;
  for (; r + 8 < cnt; r += 16) {
    int i0 = lst[r], i1 = lst[r + 8];
    float4 a = y4[(size_t)i0 * 32 + l32];
    float4 b = y4[(size_t)i1 * 32 + l32];
    acc.x += a.x + b.x; acc.y += a.y + b.y;
    acc.z += a.z + b.z; acc.w += a.w + b.w;
  }
  for (; r < cnt; r += 8) {
    float4 a = y4[(size_t)lst[r] * 32 + l32];
    acc.x += a.x; acc.y += a.y; acc.z += a.z; acc.w += a.w;
  }
  part[g][l32] = acc;
  __syncthreads();
  if (g == 0) {
    float4 s = part[0][l32];
    #pragma unroll
    for (int q = 1; q < 8; ++q) {
      float4 p = part[q][l32];
      s.x += p.x; s.y += p.y; s.z += p.z; s.w += p.w;
    }
    int d0 = l32 * 4;
    float4 ss = *(const float4*)&sAs[d0];
    float4 sq = *(const float4*)&sAq[d0];
    float inv = 1.0f / (float)cnt;
    float4 o;
    float m, rs;
    m = ss.x / HW; rs = rsqrtf(sq.x / HW - m * m + BN_EPS); o.x = (s.x * inv - m) * rs;
    m = ss.y / HW; rs = rsqrtf(sq.y / HW - m * m + BN_EPS); o.y = (s.y * inv - m) * rs;
    m = ss.z / HW; rs = rsqrtf(sq.z / HW - m * m + BN_EPS); o.z = (s.z * inv - m) * rs;
    m = ss.w / HW; rs = rsqrtf(sq.w / HW - m * m + BN_EPS); o.w = (s.w * inv - m) * rs;
    *(float4*)&spA[sp * 128 + d0] = o;
  }
}

// ------- row inv-norms (+opt pre-BN affine, +opt leaky-in, +opt act write) ------
__global__ void k_rstats(const float* __restrict__ in, float* __restrict__ act_out,
                         float* __restrict__ invn,
                         float* __restrict__ sums, float* __restrict__ sumsq, int M,
                         const float* __restrict__ preS, const float* __restrict__ preQ,
                         float precnt, int leaky_in) {
  __shared__ float lsum[128], lssq[128];
  int t = threadIdx.x;
  if (t < 128) { lsum[t] = 0.f; lssq[t] = 0.f; }
  __syncthreads();
  int wid = t >> 6, lane = t & 63, d0 = lane * 2;
  float m0 = 0.f, m1 = 0.f, r0 = 1.f, r1 = 1.f;
  if (preS) {
    m0 = preS[d0] / precnt;
    r0 = rsqrtf(preQ[d0] / precnt - m0 * m0 + BN_EPS);
    m1 = preS[d0 + 1] / precnt;
    r1 = rsqrtf(preQ[d0 + 1] / precnt - m1 * m1 + BN_EPS);
  }
  float cs0 = 0.f, cs1 = 0.f, cq0 = 0.f, cq1 = 0.f;
  for (int row = blockIdx.x * 4 + wid; row < M; row += gridDim.x * 4) {
    float2 v = *(const float2*)(in + (size_t)row * 128 + d0);
    v.x = (v.x - m0) * r0;
    v.y = (v.y - m1) * r1;
    if (leaky_in) {
      v.x = (v.x >= 0.f) ? v.x : LSLOPE * v.x;
      v.y = (v.y >= 0.f) ? v.y : LSLOPE * v.y;
    }
    if (act_out) *(float2*)(act_out + (size_t)row * 128 + d0) = v;
    float ss = v.x * v.x + v.y * v.y;
    #pragma unroll
    for (int o = 1; o < 64; o <<= 1) ss += __shfl_xor(ss, o);
    float sc = 1.0f / fmaxf(sqrtf(ss), 1e-12f);
    if (lane == 0) invn[row] = sc;
    float nx = v.x * sc, ny = v.y * sc;
    cs0 += nx; cs1 += ny; cq0 += nx * nx; cq1 += ny * ny;
  }
  atomicAdd(&lsum[d0], cs0); atomicAdd(&lsum[d0 + 1], cs1);
  atomicAdd(&lssq[d0], cq0); atomicAdd(&lssq[d0 + 1], cq1);
  __syncthreads();
  if (t < 128) { atomicAdd(&sums[t], lsum[t]); atomicAdd(&sumsq[t], lssq[t]); }
}

// -- fold BN(s) into W: W''=rsA*rs2*W; cvec=mA@W''; bp=base-m2@(rs2*W) ----------
__global__ void k_prepw(const float* __restrict__ sums, const float* __restrict__ sumsq,
                        float cnt, const float* __restrict__ W,
                        const float* __restrict__ base,
                        const float* __restrict__ preS, const float* __restrict__ preQ,
                        float precnt,
                        float* __restrict__ Wpp, float* __restrict__ cvec,
                        float* __restrict__ bp) {
  __shared__ float redc[8][128], redb[8][128];
  int t = threadIdx.x;
  int kq = (t & 31) * 4, jg = t >> 5;
  float cx = 0.f, cy = 0.f, cz = 0.f, cw = 0.f;
  float bx = 0.f, by = 0.f, bz = 0.f, bw = 0.f;
  for (int j = jg; j < 128; j += 8) {
    float m2 = sums[j] / cnt;
    float rs2 = rsqrtf(sumsq[j] / cnt - m2 * m2 + BN_EPS);
    float mA = 0.f, rsA = 1.f;
    if (preS) {
      mA = preS[j] / precnt;
      rsA = rsqrtf(preQ[j] / precnt - mA * mA + BN_EPS);
    }
    float4 w = *(const float4*)&W[j * 128 + kq];
    float s2 = rs2, sA = rsA * rs2;
    float4 wpp = make_float4(sA * w.x, sA * w.y, sA * w.z, sA * w.w);
    *(float4*)&Wpp[j * 128 + kq] = wpp;
    cx = fmaf(mA, wpp.x, cx); cy = fmaf(mA, wpp.y, cy);
    cz = fmaf(mA, wpp.z, cz); cw = fmaf(mA, wpp.w, cw);
    float m2s = m2 * s2;
    bx = fmaf(m2s, w.x, bx); by = fmaf(m2s, w.y, by);
    bz = fmaf(m2s, w.z, bz); bw = fmaf(m2s, w.w, bw);
  }
  *(float4*)&redc[jg][kq] = make_float4(cx, cy, cz, cw);
  *(float4*)&redb[jg][kq] = make_float4(bx, by, bz, bw);
  __syncthreads();
  if (t < 32) {
    int k4 = t * 4;
    float4 sc = *(float4*)&redc[0][k4];
    float4 sb = *(float4*)&redb[0][k4];
    #pragma unroll
    for (int g = 1; g < 8; ++g) {
      float4 ac = *(float4*)&redc[g][k4];
      float4 ab = *(float4*)&redb[g][k4];
      sc.x += ac.x; sc.y += ac.y; sc.z += ac.z; sc.w += ac.w;
      sb.x += ab.x; sb.y += ab.y; sb.z += ab.z; sb.w += ab.w;
    }
    *(float4*)&cvec[k4] = sc;
    float4 bs = base ? *(const float4*)&base[k4] : make_float4(0,0,0,0);
    *(float4*)&bp[k4] = make_float4(bs.x - sb.x, bs.y - sb.y, bs.z - sb.z, bs.w - sb.w);
  }
}

// ---- CSR edge aggregation: float4 lanes, 2 edges/wave in flight, 4-deep unroll --
__global__ __launch_bounds__(256) void k_agg(
    const float* __restrict__ xw, const int2* __restrict__ elist,
    const int* __restrict__ off, const float* __restrict__ dinv,
    const float* __restrict__ bias, float* __restrict__ out,
    int do_norm, float* __restrict__ sums, float* __restrict__ sumsq) {
  __shared__ float lsum[128], lssq[128];
  int t = threadIdx.x;
  if (do_norm) {
    if (t < 128) { lsum[t] = 0.f; lssq[t] = 0.f; }
    __syncthreads();
  }
  int wid = t >> 6, lane = t & 63;
  int hi = lane >> 5, l32 = lane & 31;
  const float4* xw4 = (const float4*)xw;
  float4 bb = ((const float4*)bias)[l32];
  float cs[4] = {}, cq[4] = {};
  for (int i = blockIdx.x * 4 + wid; i < HW; i += gridDim.x * 4) {
    int s0 = off[i], s1 = off[i + 1];
    float di = dinv[i];
    float4 xi = xw4[(size_t)i * 32 + l32];   // early: overlap with edge loop
    float4 acc = make_float4(0.f, 0.f, 0.f, 0.f);
    int kk = s0 + hi;
    // 4 edges in flight per half-wave
    for (; kk + 6 < s1; kk += 8) {
      int2 ea = elist[kk], eb = elist[kk + 2], ec = elist[kk + 4], ed = elist[kk + 6];
      float4 va = xw4[(size_t)ea.x * 32 + l32];
      float4 vb = xw4[(size_t)eb.x * 32 + l32];
      float4 vc = xw4[(size_t)ec.x * 32 + l32];
      float4 vd = xw4[(size_t)ed.x * 32 + l32];
      float wa = __int_as_float(ea.y), wb = __int_as_float(eb.y);
      float wc = __int_as_float(ec.y), wd = __int_as_float(ed.y);
      acc.x = fmaf(wa, va.x, acc.x); acc.y = fmaf(wa, va.y, acc.y);
      acc.z = fmaf(wa, va.z, acc.z); acc.w = fmaf(wa, va.w, acc.w);
      acc.x = fmaf(wb, vb.x, acc.x); acc.y = fmaf(wb, vb.y, acc.y);
      acc.z = fmaf(wb, vb.z, acc.z); acc.w = fmaf(wb, vb.w, acc.w);
      acc.x = fmaf(wc, vc.x, acc.x); acc.y = fmaf(wc, vc.y, acc.y);
      acc.z = fmaf(wc, vc.z, acc.z); acc.w = fmaf(wc, vc.w, acc.w);
      acc.x = fmaf(wd, vd.x, acc.x); acc.y = fmaf(wd, vd.y, acc.y);
      acc.z = fmaf(wd, vd.z, acc.z); acc.w = fmaf(wd, vd.w, acc.w);
    }
    for (; kk < s1; kk += 2) {
      int2 e = elist[kk];
      float w = __int_as_float(e.y);
      float4 v = xw4[(size_t)e.x * 32 + l32];
      acc.x = fmaf(w, v.x, acc.x); acc.y = fmaf(w, v.y, acc.y);
      acc.z = fmaf(w, v.z, acc.z); acc.w = fmaf(w, v.w, acc.w);
    }
    acc.x += __shfl_xor(acc.x, 32); acc.y += __shfl_xor(acc.y, 32);
    acc.z += __shfl_xor(acc.z, 32); acc.w += __shfl_xor(acc.w, 32);
    if (hi == 0) {
      float inv_deg = di * di;
      float r[4];
      r[0] = fmaf(xi.x, inv_deg, acc.x) + bb.x;
      r[1] = fmaf(xi.y, inv_deg, acc.y) + bb.y;
      r[2] = fmaf(xi.z, inv_deg, acc.z) + bb.z;
      r[3] = fmaf(xi.w, inv_deg, acc.w) + bb.w;
      #pragma unroll
      for (int c = 0; c < 4; ++c) r[c] = (r[c] >= 0.f) ? r[c] : LSLOPE * r[c];
      if (do_norm) {
        float ss = r[0]*r[0] + r[1]*r[1] + r[2]*r[2] + r[3]*r[3];
        #pragma unroll
        for (int o = 1; o < 32; o <<= 1) ss += __shfl_xor(ss, o);
        float sc = 1.0f / fmaxf(sqrtf(ss), 1e-12f);
        #pragma unroll
        for (int c = 0; c < 4; ++c) {
          r[c] *= sc;
          cs[c] += r[c]; cq[c] += r[c] * r[c];
        }
      }
      ((float4*)out)[(size_t)i * 32 + l32] = make_float4(r[0], r[1], r[2], r[3]);
    }
  }
  if (do_norm) {
    if (hi == 0) {
      #pragma unroll
      for (int c = 0; c < 4; ++c) {
        atomicAdd(&lsum[l32 * 4 + c], cs[c]);
        atomicAdd(&lssq[l32 * 4 + c], cq[c]);
      }
    }
    __syncthreads();
    if (t < 128) { atomicAdd(&sums[t], lsum[t]); atomicAdd(&sumsq[t], lssq[t]); }
  }
}

// -------- final: (m2 + leaky(H1p[seg])) @ out_W + out_b -> softmax --------------
__global__ __launch_bounds__(256) void k_final(
    const float* __restrict__ m2, const float* __restrict__ H1p,
    const int* __restrict__ seg, const float* __restrict__ Wout,
    const float* __restrict__ bout, float* __restrict__ out) {
  __shared__ float rb[16][132];
  __shared__ float WL[128 * 16];
  int t = threadIdx.x;
  int row0 = blockIdx.x * 16;
  for (int idx = t; idx < 128 * NCLS; idx += 256) WL[idx] = Wout[idx];
  for (int idx = t; idx < 16 * 128; idx += 256) {
    int r = idx >> 7, d = idx & 127;
    int row = row0 + r;
    float h = H1p[(size_t)seg[row] * 128 + d];
    h = (h >= 0.f) ? h : LSLOPE * h;
    rb[r][d] = m2[(size_t)row * 128 + d] + h;
  }
  __syncthreads();
  int c = t & 15, r = t >> 4;
  float acc = bout[c];
  #pragma unroll 8
  for (int d = 0; d < 128; ++d) acc = fmaf(rb[r][d], WL[d * 16 + c], acc);
  float mx = acc;
  #pragma unroll
  for (int o = 1; o < 16; o <<= 1) mx = fmaxf(mx, __shfl_xor(mx, o));
  float e = expf(acc - mx);
  float s = e;
  #pragma unroll
  for (int o = 1; o < 16; o <<= 1) s += __shfl_xor(s, o);
  out[(size_t)(row0 + r) * NCLS + c] = e / s;
}

// =================================================================================
extern "C" void kernel_launch(void* const* d_in, const int* in_sizes, int n_in,
                              void* d_out, int out_size, void* d_ws, size_t ws_size,
                              hipStream_t stream) {
  const float* x        = (const float*)d_in[0];
  const float* Q        = (const float*)d_in[1];
  const float* A_norm   = (const float*)d_in[2];
  const int*   ei       = (const int*)d_in[3];
  const float* prelin_W = (const float*)d_in[4];
  const float* prelin_b = (const float*)d_in[5];
  const float* gcn1_W   = (const float*)d_in[6];
  const float* gcn1_b   = (const float*)d_in[7];
  const float* gcn2_W   = (const float*)d_in[8];
  const float* gcn2_b   = (const float*)d_in[9];
  const float* mpnn1_W  = (const float*)d_in[10];
  const float* mpnn1_b  = (const float*)d_in[11];
  const float* mpnn2_W  = (const float*)d_in[12];
  const float* mpnn2_b  = (const float*)d_in[13];
  const float* out_W    = (const float*)d_in[14];
  const float* out_b    = (const float*)d_in[15];
  float* outp = (float*)d_out;
  const int* e_src = ei;
  const int* e_dst = ei + NE;

  char* ws = (char*)d_ws;
  size_t o = 0;
  auto alloc = [&](size_t bytes) { size_t r = o; o = (o + bytes + 255) & ~255ULL; return r; };
  size_t bufA_o   = alloc((size_t)HW * 128 * 4);
  size_t bufB_o   = alloc((size_t)HW * 128 * 4);
  // ---- zero group start ----
  size_t cntd_o   = alloc((size_t)HW * 4);
  size_t cntinv_o = alloc((size_t)NSP * 4);
  size_t stats_o  = alloc(5 * 256 * 4);
  size_t spDp_o   = alloc((size_t)NSP * 128 * 4);  // GCN1 A_norm out (pre-act), atomic
  size_t spHp_o   = alloc((size_t)NSP * 128 * 4);  // GCN2 A_norm out (pre-act), atomic
  size_t zero_end = o;
  // ---- zero group end ----
  size_t seg_o    = alloc((size_t)HW * 4);
  size_t seginv_o = alloc((size_t)HW * 4);
  size_t off_o    = alloc((size_t)(HW + 1) * 4);
  size_t cur_o    = alloc((size_t)HW * 4);
  size_t dinv_o   = alloc((size_t)HW * 4);
  size_t e2_o     = alloc((size_t)NE * 8);
  size_t bsum_o   = alloc(256 * 4);
  size_t bo_o     = alloc(256 * 4);
  size_t spA_o    = alloc((size_t)NSP * 128 * 4);
  size_t spC_o    = alloc((size_t)NSP * 128 * 4);
  size_t spDa_o   = alloc((size_t)NSP * 128 * 4);  // leaky(spDp)
  size_t Wpp_o    = alloc(128 * 128 * 4);
  size_t cv_o     = alloc(128 * 4);
  size_t bp_o     = alloc(128 * 4);
  size_t invG1_o  = alloc((size_t)NSP * 4);
  size_t invG2_o  = alloc((size_t)NSP * 4);
  size_t invM1_o  = alloc((size_t)HW * 4);
  if (o > ws_size) return;

  float* bufA   = (float*)(ws + bufA_o);
  float* bufB   = (float*)(ws + bufB_o);
  int*   cntd   = (int*)(ws + cntd_o);
  int*   cntinv = (int*)(ws + cntinv_o);
  float* stats  = (float*)(ws + stats_o);
  float* sA_s  = stats + 0 * 256, *sA_q  = sA_s + 128;
  float* sG1_s = stats + 1 * 256, *sG1_q = sG1_s + 128;
  float* sG2_s = stats + 2 * 256, *sG2_q = sG2_s + 128;
  float* sM1_s = stats + 3 * 256, *sM1_q = sM1_s + 128;
  float* sM2_s = stats + 4 * 256, *sM2_q = sM2_s + 128;
  float* spDp   = (float*)(ws + spDp_o);
  float* spHp   = (float*)(ws + spHp_o);
  int*   seg    = (int*)(ws + seg_o);
  int*   seginv = (int*)(ws + seginv_o);
  int*   offp   = (int*)(ws + off_o);
  int*   cur    = (int*)(ws + cur_o);
  float* dinv   = (float*)(ws + dinv_o);
  int2*  e2     = (int2*)(ws + e2_o);
  int*   bsum   = (int*)(ws + bsum_o);
  int*   bo     = (int*)(ws + bo_o);
  float* spA    = (float*)(ws + spA_o);
  float* spC    = (float*)(ws + spC_o);
  float* spDa   = (float*)(ws + spDa_o);
  float* Wpp    = (float*)(ws + Wpp_o);
  float* cv     = (float*)(ws + cv_o);
  float* bp     = (float*)(ws + bp_o);
  float* invG1  = (float*)(ws + invG1_o);
  float* invG2  = (float*)(ws + invG2_o);
  float* invM1  = (float*)(ws + invM1_o);

  hipMemsetAsync(ws + cntd_o, 0, zero_end - cntd_o, stream);

  // seg/seg_inv/degree + CSR build
  hipLaunchKernelGGL(k_setup, dim3(4096 + NE / 256), dim3(256), 0, stream,
                     Q, seg, seginv, cntinv, e_dst, cntd);
  hipLaunchKernelGGL(k_scan_a, dim3(256), dim3(256), 0, stream, cntd, offp, bsum);
  hipLaunchKernelGGL(k_scan_b, dim3(1), dim3(256), 0, stream, bsum, bo);
  hipLaunchKernelGGL(k_scan_c, dim3(256), dim3(256), 0, stream, offp, bo, cur, cntd, dinv);
  hipLaunchKernelGGL(k_scatter, dim3(NE / 256), dim3(256), 0, stream, e_src, e_dst, cur, dinv, e2);

  // prelin GEMM: y = x @ prelin_W + prelin_b -> bufA, fused col stats -> sA
  hipLaunchKernelGGL(k_gemm, dim3(HW / 64), dim3(256), 0, stream,
                     x, prelin_W, prelin_b, bufA, CIN, 0, sA_s, sA_q,
                     (const float*)nullptr, (const float*)nullptr);
  // pool + inline BN -> spA
  hipLaunchKernelGGL(k_pool2, dim3(NSP), dim3(256), 0, stream,
                     bufA, seginv, cntinv, sA_s, sA_q, spA);

  // ---- GCN layer 1 ----
  hipLaunchKernelGGL(k_rstats, dim3(16), dim3(256), 0, stream,
                     spA, (float*)nullptr, invG1, sG1_s, sG1_q, NSP,
                     (const float*)nullptr, (const float*)nullptr, 1.f, 0);
  hipLaunchKernelGGL(k_prepw, dim3(1), dim3(256), 0, stream, sG1_s, sG1_q, (float)NSP,
                     gcn1_W, gcn1_b, (const float*)nullptr, (const float*)nullptr, 1.f,
                     Wpp, cv, bp);
  hipLaunchKernelGGL(k_gemm, dim3(NSP / 64), dim3(256), 0, stream,
                     spA, Wpp, bp, spC, 128, 0, (float*)nullptr, (float*)nullptr, invG1, cv);
  hipLaunchKernelGGL(k_gemm_ks, dim3(NSP / 64, 8), dim3(256), 0, stream,
                     A_norm, spC, spDp, NSP, 128);
  // ---- GCN layer 2 ----
  hipLaunchKernelGGL(k_rstats, dim3(16), dim3(256), 0, stream,
                     spDp, spDa, invG2, sG2_s, sG2_q, NSP,
                     (const float*)nullptr, (const float*)nullptr, 1.f, 1);
  hipLaunchKernelGGL(k_prepw, dim3(1), dim3(256), 0, stream, sG2_s, sG2_q, (float)NSP,
                     gcn2_W, gcn2_b, (const float*)nullptr, (const float*)nullptr, 1.f,
                     Wpp, cv, bp);
  hipLaunchKernelGGL(k_gemm, dim3(NSP / 64), dim3(256), 0, stream,
                     spDa, Wpp, bp, spC, 128, 0, (float*)nullptr, (float*)nullptr, invG2, cv);
  hipLaunchKernelGGL(k_gemm_ks, dim3(NSP / 64, 8), dim3(256), 0, stream,
                     A_norm, spC, spHp, NSP, 128);
  // H1 (pre-act) -> spHp

  // ---- MPNN layer 1 ----
  hipLaunchKernelGGL(k_rstats, dim3(512), dim3(256), 0, stream,
                     bufA, (float*)nullptr, invM1, sM1_s, sM1_q, HW, sA_s, sA_q, (float)HW, 0);
  hipLaunchKernelGGL(k_prepw, dim3(1), dim3(256), 0, stream, sM1_s, sM1_q, (float)HW,
                     mpnn1_W, (const float*)nullptr, sA_s, sA_q, (float)HW,
                     Wpp, cv, bp);
  hipLaunchKernelGGL(k_gemm, dim3(HW / 64), dim3(256), 0, stream,
                     bufA, Wpp, bp, bufB, 128, 0, (float*)nullptr, (float*)nullptr, invM1, cv);
  hipLaunchKernelGGL(k_agg, dim3(2048), dim3(256), 0, stream,
                     bufB, e2, offp, dinv, mpnn1_b, bufA, 1, sM2_s, sM2_q);

  // ---- MPNN layer 2 ----
  hipLaunchKernelGGL(k_prepw, dim3(1), dim3(256), 0, stream, sM2_s, sM2_q, (float)HW,
                     mpnn2_W, (const float*)nullptr, (const float*)nullptr, (const float*)nullptr, 1.f,
                     Wpp, cv, bp);
  hipLaunchKernelGGL(k_gemm, dim3(HW / 64), dim3(256), 0, stream,
                     bufA, Wpp, bp, bufB, 128, 0, (float*)nullptr, (float*)nullptr,
                     (const float*)nullptr, (const float*)nullptr);
  hipLaunchKernelGGL(k_agg, dim3(2048), dim3(256), 0, stream,
                     bufB, e2, offp, dinv, mpnn2_b, bufA, 0, (float*)nullptr, (float*)nullptr);
  // m2 -> bufA

  // final fused head
  hipLaunchKernelGGL(k_final, dim3(HW / 16), dim3(256), 0, stream,
                     bufA, spHp, seg, out_W, out_b, outp);
}

// Round 6
// 563.195 us; speedup vs baseline: 2.2360x; 1.1010x over previous
//
#include <hip/hip_runtime.h>

#define HW 65536
#define NSP 1024
#define CIN 200
#define DH 128
#define NE 524288
#define NCLS 16
#define BN_EPS 1e-5f
#define LSLOPE 0.01f

typedef unsigned short u16;
typedef short s16x8 __attribute__((ext_vector_type(8)));
typedef u16 u16x8 __attribute__((ext_vector_type(8)));
typedef u16 u16x4 __attribute__((ext_vector_type(4)));
typedef float f32x4 __attribute__((ext_vector_type(4)));

__device__ inline u16 f2b(float x) {            // f32 -> bf16 RNE
  unsigned int u = __float_as_uint(x);
  unsigned int r = ((u >> 16) & 1u) + 0x7FFFu;
  return (u16)((u + r) >> 16);
}
__device__ inline float b2f(u16 u) { return __uint_as_float(((unsigned int)u) << 16); }

#define NQB 4096
#define NDB (NE / 256)
#define CXB (HW * 56 / 256)
#define CWB 112

// ---- fused: seg/seg_inv from Q + edge degree + x->bf16 pad224 + prelinW->bf16 T --
__global__ __launch_bounds__(256) void k_setup(
    const float* __restrict__ Q, int* __restrict__ seg, int* __restrict__ seg_inv,
    int* __restrict__ cnt_inv, const int* __restrict__ dst, int* __restrict__ cntd,
    const float* __restrict__ x, const float* __restrict__ preW,
    u16* __restrict__ xb, u16* __restrict__ wtpre) {
  int b = blockIdx.x, t = threadIdx.x;
  if (b < NQB) {
    const float4* Q4 = (const float4*)Q;
    const int n4 = HW * NSP / 4;
    for (int i = b * 256 + t; i < n4; i += NQB * 256) {
      float4 q = Q4[i];
      int base = i * 4;
      #pragma unroll
      for (int e = 0; e < 4; ++e) {
        float qv = (e == 0) ? q.x : (e == 1) ? q.y : (e == 2) ? q.z : q.w;
        if (qv > 0.5f) {
          int idx = base + e;
          int r = idx >> 10, s = idx & (NSP - 1);
          seg[r] = s;
          int p = atomicAdd(&cnt_inv[s], 1);
          seg_inv[s * 64 + p] = r;
        }
      }
    }
  } else if (b < NQB + NDB) {
    int e = (b - NQB) * 256 + t;
    if (e < NE) atomicAdd(&cntd[dst[e]], 1);
  } else if (b < NQB + NDB + CXB) {
    int g = (b - NQB - NDB) * 256 + t;
    int row = g / 56, qd = g - row * 56;
    int k0 = qd * 4;
    u16x4 o;
    if (k0 < 200) {
      float4 v = *(const float4*)&x[(size_t)row * 200 + k0];
      o[0] = f2b(v.x); o[1] = f2b(v.y); o[2] = f2b(v.z); o[3] = f2b(v.w);
    } else { o[0] = 0; o[1] = 0; o[2] = 0; o[3] = 0; }
    *(u16x4*)&xb[(size_t)row * 224 + k0] = o;
  } else {
    int g = (b - NQB - NDB - CXB) * 256 + t;
    if (g < 128 * 224) {
      int n = g / 224, k = g - n * 224;
      wtpre[g] = (k < 200) ? f2b(preW[(size_t)k * 128 + n]) : (u16)0;
    }
  }
}

// ---------------- prefix scan (3 stages) ----------------
__global__ void k_scan_a(const int* __restrict__ cntd, int* __restrict__ off,
                         int* __restrict__ bsum) {
  __shared__ int s[256];
  int t = threadIdx.x, b = blockIdx.x;
  int i = b * 256 + t;
  int v = cntd[i];
  s[t] = v; __syncthreads();
  for (int o = 1; o < 256; o <<= 1) {
    int x = (t >= o) ? s[t - o] : 0;
    __syncthreads();
    s[t] += x;
    __syncthreads();
  }
  off[i] = s[t] - v;
  if (t == 255) bsum[b] = s[t];
}
__global__ void k_scan_b(const int* __restrict__ bsum, int* __restrict__ bo) {
  __shared__ int s[256];
  int t = threadIdx.x;
  int v = bsum[t];
  s[t] = v; __syncthreads();
  for (int o = 1; o < 256; o <<= 1) {
    int x = (t >= o) ? s[t - o] : 0;
    __syncthreads();
    s[t] += x;
    __syncthreads();
  }
  bo[t] = s[t] - v;
}
__global__ void k_scan_c(int* __restrict__ off, const int* __restrict__ bo,
                         int* __restrict__ cur, const int* __restrict__ cntd,
                         float* __restrict__ dinv) {
  int i = blockIdx.x * blockDim.x + threadIdx.x;
  int v = off[i] + bo[i >> 8];
  off[i] = v;
  cur[i] = v;
  dinv[i] = rsqrtf((float)cntd[i] + 1.0f);
  if (i == 0) off[HW] = NE;
}

// ---------------- CSR scatter with precomputed edge weight ----------------
__global__ void k_scatter(const int* __restrict__ src, const int* __restrict__ dst,
                          int* __restrict__ cursor, const float* __restrict__ dinv,
                          int2* __restrict__ e2) {
  int e = blockIdx.x * blockDim.x + threadIdx.x;
  if (e < NE) {
    int d = dst[e], s = src[e];
    float w = dinv[d] * dinv[s];
    int pos = atomicAdd(&cursor[d], 1);
    e2[pos] = make_int2(s, __float_as_int(w));
  }
}

// ================= MFMA bf16 GEMM: C[M,128] = A[M,K] @ B[K,128] ==================
// 256 thr = 4 waves (2x2 of 32x64). A: f32 or bf16 (inline cvt). B: WT bf16 [n][k].
// Epilogue: x = invn[row]*(acc - cvec[c]) + bias[c]; optional bf16 out + col stats.
__global__ __launch_bounds__(256) void k_mgemm(
    const void* __restrict__ Ap, int a_bf16, int lda,
    const u16* __restrict__ WT, int ldb, int K,
    const float* __restrict__ bias, const float* __restrict__ cvec,
    const float* __restrict__ invn,
    void* __restrict__ Cp, int c_bf16,
    float* __restrict__ sums, float* __restrict__ sumsq) {
  __shared__ u16 As[2][64][40];
  __shared__ u16 Bs[2][128][40];
  __shared__ float lsum[128], lssq[128];
  int t = threadIdx.x;
  if (sums && t < 128) { lsum[t] = 0.f; lssq[t] = 0.f; }
  int row0 = blockIdx.x * 64;
  int ar = t >> 2, ak = (t & 3) * 8;
  u16x8 aReg; u16x8 bReg[2];

  auto loadRegs = [&](int k0) {
    if (a_bf16) {
      aReg = *(const u16x8*)((const u16*)Ap + (size_t)(row0 + ar) * lda + k0 + ak);
    } else {
      const float* ap = (const float*)Ap + (size_t)(row0 + ar) * lda + k0 + ak;
      float4 f0 = *(const float4*)ap;
      float4 f1 = *(const float4*)(ap + 4);
      u16x8 v;
      v[0] = f2b(f0.x); v[1] = f2b(f0.y); v[2] = f2b(f0.z); v[3] = f2b(f0.w);
      v[4] = f2b(f1.x); v[5] = f2b(f1.y); v[6] = f2b(f1.z); v[7] = f2b(f1.w);
      aReg = v;
    }
    #pragma unroll
    for (int it = 0; it < 2; ++it) {
      int slot = t + it * 256;
      int bn = slot >> 2, kg = (slot & 3) * 8;
      bReg[it] = *(const u16x8*)(WT + (size_t)bn * ldb + k0 + kg);
    }
  };
  auto dsWrite = [&](int bq) {
    *(u16x8*)&As[bq][ar][ak] = aReg;
    #pragma unroll
    for (int it = 0; it < 2; ++it) {
      int slot = t + it * 256;
      int bn = slot >> 2, kg = (slot & 3) * 8;
      *(u16x8*)&Bs[bq][bn][kg] = bReg[it];
    }
  };

  int lane = t & 63, wv = t >> 6;
  int m0 = (wv >> 1) * 32, n0 = (wv & 1) * 64;
  int fr = lane & 15, fk = (lane >> 4) * 8;
  f32x4 acc[2][4];
  #pragma unroll
  for (int mt = 0; mt < 2; ++mt)
    #pragma unroll
    for (int nt = 0; nt < 4; ++nt)
      acc[mt][nt] = (f32x4){0.f, 0.f, 0.f, 0.f};

  int nch = K >> 5;
  loadRegs(0);
  int cur = 0;
  for (int ch = 0; ch < nch; ++ch) {
    dsWrite(cur);
    __syncthreads();
    if (ch + 1 < nch) loadRegs((ch + 1) << 5);
    s16x8 afr0 = *(const s16x8*)&As[cur][m0 + fr][fk];
    s16x8 afr1 = *(const s16x8*)&As[cur][m0 + 16 + fr][fk];
    s16x8 bfr[4];
    #pragma unroll
    for (int nt = 0; nt < 4; ++nt)
      bfr[nt] = *(const s16x8*)&Bs[cur][n0 + nt * 16 + fr][fk];
    #pragma unroll
    for (int nt = 0; nt < 4; ++nt) {
      acc[0][nt] = __builtin_amdgcn_mfma_f32_16x16x32_bf16(afr0, bfr[nt], acc[0][nt], 0, 0, 0);
      acc[1][nt] = __builtin_amdgcn_mfma_f32_16x16x32_bf16(afr1, bfr[nt], acc[1][nt], 0, 0, 0);
    }
    cur ^= 1;
  }

  float bb4[4], cv4[4];
  #pragma unroll
  for (int nt = 0; nt < 4; ++nt) {
    int c = n0 + nt * 16 + fr;
    bb4[nt] = bias ? bias[c] : 0.f;
    cv4[nt] = cvec ? cvec[c] : 0.f;
  }
  int rg = lane >> 4;
  float cs4[4] = {}, cq4[4] = {};
  #pragma unroll
  for (int mt = 0; mt < 2; ++mt) {
    int rbase = row0 + m0 + mt * 16 + rg * 4;
    float inr[4];
    #pragma unroll
    for (int j = 0; j < 4; ++j) inr[j] = invn ? invn[rbase + j] : 1.f;
    #pragma unroll
    for (int nt = 0; nt < 4; ++nt) {
      int c = n0 + nt * 16 + fr;
      #pragma unroll
      for (int j = 0; j < 4; ++j) {
        float xv = inr[j] * (acc[mt][nt][j] - cv4[nt]) + bb4[nt];
        if (sums) { cs4[nt] += xv; cq4[nt] += xv * xv; }
        if (c_bf16) ((u16*)Cp)[(size_t)(rbase + j) * 128 + c] = f2b(xv);
        else        ((float*)Cp)[(size_t)(rbase + j) * 128 + c] = xv;
      }
    }
  }
  if (sums) {
    __syncthreads();
    #pragma unroll
    for (int nt = 0; nt < 4; ++nt) {
      int c = n0 + nt * 16 + fr;
      atomicAdd(&lsum[c], cs4[nt]);
      atomicAdd(&lssq[c], cq4[nt]);
    }
    __syncthreads();
    if (t < 128) { atomicAdd(&sums[t], lsum[t]); atomicAdd(&sumsq[t], lssq[t]); }
  }
}

// ---------------- f32 register-tiled GEMM (GCN path only) ----------------
__global__ __launch_bounds__(256) void k_gemm(
    const float* __restrict__ A, const float* __restrict__ B,
    const float* __restrict__ bias, float* __restrict__ C,
    int K, int leaky, float* __restrict__ sums, float* __restrict__ sumsq,
    const float* __restrict__ invn, const float* __restrict__ cvec) {
  __shared__ float As[32][68];
  __shared__ float Bs[32][128];
  int t = threadIdx.x;
  int c0 = (t & 31) * 4;
  int r0 = (t >> 5) * 8;
  int row0 = blockIdx.x * 64;
  int lr = t >> 2, lkb = (t & 3) * 8;
  float acc[8][4] = {};
  for (int k0 = 0; k0 < K; k0 += 32) {
    int kc = min(32, K - k0);
    __syncthreads();
    for (int idx = t * 4; idx < kc * 128; idx += 1024)
      *(float4*)&Bs[idx >> 7][idx & 127] = *(const float4*)&B[(size_t)k0 * 128 + idx];
    if (lkb < kc) {
      const float* ap = A + (size_t)(row0 + lr) * K + k0 + lkb;
      float4 v0 = *(const float4*)ap;
      float4 v1 = *(const float4*)(ap + 4);
      As[lkb + 0][lr] = v0.x; As[lkb + 1][lr] = v0.y;
      As[lkb + 2][lr] = v0.z; As[lkb + 3][lr] = v0.w;
      As[lkb + 4][lr] = v1.x; As[lkb + 5][lr] = v1.y;
      As[lkb + 6][lr] = v1.z; As[lkb + 7][lr] = v1.w;
    }
    __syncthreads();
    #pragma unroll 2
    for (int k = 0; k < kc; ++k) {
      float4 b4 = *(float4*)&Bs[k][c0];
      float4 a0 = *(float4*)&As[k][r0];
      float4 a1 = *(float4*)&As[k][r0 + 4];
      float av[8] = {a0.x, a0.y, a0.z, a0.w, a1.x, a1.y, a1.z, a1.w};
      float bv[4] = {b4.x, b4.y, b4.z, b4.w};
      #pragma unroll
      for (int r = 0; r < 8; ++r)
        #pragma unroll
        for (int c = 0; c < 4; ++c)
          acc[r][c] = fmaf(av[r], bv[c], acc[r][c]);
    }
  }
  float bb[4] = {0.f, 0.f, 0.f, 0.f};
  if (bias) { bb[0] = bias[c0]; bb[1] = bias[c0+1]; bb[2] = bias[c0+2]; bb[3] = bias[c0+3]; }
  float cv[4] = {0.f, 0.f, 0.f, 0.f};
  float inr[8];
  if (invn) {
    cv[0] = cvec[c0]; cv[1] = cvec[c0+1]; cv[2] = cvec[c0+2]; cv[3] = cvec[c0+3];
    #pragma unroll
    for (int r = 0; r < 8; ++r) inr[r] = invn[row0 + r0 + r];
  }
  #pragma unroll
  for (int r = 0; r < 8; ++r) {
    float4 o;
    float v[4];
    #pragma unroll
    for (int c = 0; c < 4; ++c) {
      float x;
      if (invn) x = inr[r] * (acc[r][c] - cv[c]) + bb[c];
      else      x = acc[r][c] + bb[c];
      if (leaky) x = (x >= 0.f) ? x : LSLOPE * x;
      v[c] = x;
    }
    o.x = v[0]; o.y = v[1]; o.z = v[2]; o.w = v[3];
    *(float4*)&C[(size_t)(row0 + r0 + r) * 128 + c0] = o;
  }
}

// ------ split-K GEMM: C += A[M,Kchunk] @ B (atomic partials, pre-activation) ----
__global__ __launch_bounds__(256) void k_gemm_ks(
    const float* __restrict__ A, const float* __restrict__ B,
    float* __restrict__ C, int K, int ks) {
  __shared__ float As[32][68];
  __shared__ float Bs[32][128];
  int t = threadIdx.x;
  int c0 = (t & 31) * 4;
  int r0 = (t >> 5) * 8;
  int row0 = blockIdx.x * 64;
  int kbeg = blockIdx.y * ks;
  int kend = min(K, kbeg + ks);
  int lr = t >> 2, lkb = (t & 3) * 8;
  float acc[8][4] = {};
  for (int k0 = kbeg; k0 < kend; k0 += 32) {
    int kc = min(32, kend - k0);
    __syncthreads();
    for (int idx = t * 4; idx < kc * 128; idx += 1024)
      *(float4*)&Bs[idx >> 7][idx & 127] = *(const float4*)&B[(size_t)k0 * 128 + idx];
    if (lkb < kc) {
      const float* ap = A + (size_t)(row0 + lr) * K + k0 + lkb;
      float4 v0 = *(const float4*)ap;
      float4 v1 = *(const float4*)(ap + 4);
      As[lkb + 0][lr] = v0.x; As[lkb + 1][lr] = v0.y;
      As[lkb + 2][lr] = v0.z; As[lkb + 3][lr] = v0.w;
      As[lkb + 4][lr] = v1.x; As[lkb + 5][lr] = v1.y;
      As[lkb + 6][lr] = v1.z; As[lkb + 7][lr] = v1.w;
    }
    __syncthreads();
    #pragma unroll 2
    for (int k = 0; k < kc; ++k) {
      float4 b4 = *(float4*)&Bs[k][c0];
      float4 a0 = *(float4*)&As[k][r0];
      float4 a1 = *(float4*)&As[k][r0 + 4];
      float av[8] = {a0.x, a0.y, a0.z, a0.w, a1.x, a1.y, a1.z, a1.w};
      float bv[4] = {b4.x, b4.y, b4.z, b4.w};
      #pragma unroll
      for (int r = 0; r < 8; ++r)
        #pragma unroll
        for (int c = 0; c < 4; ++c)
          acc[r][c] = fmaf(av[r], bv[c], acc[r][c]);
    }
  }
  #pragma unroll
  for (int r = 0; r < 8; ++r)
    #pragma unroll
    for (int c = 0; c < 4; ++c)
      atomicAdd(&C[(size_t)(row0 + r0 + r) * 128 + c0 + c], acc[r][c]);
}

// ---------------- superpixel mean-pool: float4 lanes, inline BN ----------------
__global__ __launch_bounds__(256) void k_pool2(
    const float* __restrict__ y, const int* __restrict__ seg_inv,
    const int* __restrict__ cnt_inv, const float* __restrict__ sAs,
    const float* __restrict__ sAq, float* __restrict__ spA) {
  __shared__ float4 part[8][32];
  int sp = blockIdx.x, t = threadIdx.x;
  int l32 = t & 31, g = t >> 5;
  int cnt = cnt_inv[sp];
  const float4* y4 = (const float4*)y;
  const int* lst = seg_inv + sp * 64;
  float4 acc = make_float4(0.f, 0.f, 0.f, 0.f);
  int r = g;
  for (; r + 8 < cnt; r += 16) {
    int i0 = lst[r], i1 = lst[r + 8];
    float4 a = y4[(size_t)i0 * 32 + l32];
    float4 b = y4[(size_t)i1 * 32 + l32];
    acc.x += a.x + b.x; acc.y += a.y + b.y;
    acc.z += a.z + b.z; acc.w += a.w + b.w;
  }
  for (; r < cnt; r += 8) {
    float4 a = y4[(size_t)lst[r] * 32 + l32];
    acc.x += a.x; acc.y += a.y; acc.z += a.z; acc.w += a.w;
  }
  part[g][l32] = acc;
  __syncthreads();
  if (g == 0) {
    float4 s = part[0][l32];
    #pragma unroll
    for (int q = 1; q < 8; ++q) {
      float4 p = part[q][l32];
      s.x += p.x; s.y += p.y; s.z += p.z; s.w += p.w;
    }
    int d0 = l32 * 4;
    float4 ss = *(const float4*)&sAs[d0];
    float4 sq = *(const float4*)&sAq[d0];
    float inv = 1.0f / (float)cnt;
    float4 o;
    float m, rs;
    m = ss.x / HW; rs = rsqrtf(sq.x / HW - m * m + BN_EPS); o.x = (s.x * inv - m) * rs;
    m = ss.y / HW; rs = rsqrtf(sq.y / HW - m * m + BN_EPS); o.y = (s.y * inv - m) * rs;
    m = ss.z / HW; rs = rsqrtf(sq.z / HW - m * m + BN_EPS); o.z = (s.z * inv - m) * rs;
    m = ss.w / HW; rs = rsqrtf(sq.w / HW - m * m + BN_EPS); o.w = (s.w * inv - m) * rs;
    *(float4*)&spA[sp * 128 + d0] = o;
  }
}

// ------- row inv-norms (+opt pre-BN affine, +opt leaky-in, +opt act write) ------
__global__ void k_rstats(const float* __restrict__ in, float* __restrict__ act_out,
                         float* __restrict__ invn,
                         float* __restrict__ sums, float* __restrict__ sumsq, int M,
                         const float* __restrict__ preS, const float* __restrict__ preQ,
                         float precnt, int leaky_in) {
  __shared__ float lsum[128], lssq[128];
  int t = threadIdx.x;
  if (t < 128) { lsum[t] = 0.f; lssq[t] = 0.f; }
  __syncthreads();
  int wid = t >> 6, lane = t & 63, d0 = lane * 2;
  float m0 = 0.f, m1 = 0.f, r0 = 1.f, r1 = 1.f;
  if (preS) {
    m0 = preS[d0] / precnt;
    r0 = rsqrtf(preQ[d0] / precnt - m0 * m0 + BN_EPS);
    m1 = preS[d0 + 1] / precnt;
    r1 = rsqrtf(preQ[d0 + 1] / precnt - m1 * m1 + BN_EPS);
  }
  float cs0 = 0.f, cs1 = 0.f, cq0 = 0.f, cq1 = 0.f;
  for (int row = blockIdx.x * 4 + wid; row < M; row += gridDim.x * 4) {
    float2 v = *(const float2*)(in + (size_t)row * 128 + d0);
    v.x = (v.x - m0) * r0;
    v.y = (v.y - m1) * r1;
    if (leaky_in) {
      v.x = (v.x >= 0.f) ? v.x : LSLOPE * v.x;
      v.y = (v.y >= 0.f) ? v.y : LSLOPE * v.y;
    }
    if (act_out) *(float2*)(act_out + (size_t)row * 128 + d0) = v;
    float ss = v.x * v.x + v.y * v.y;
    #pragma unroll
    for (int o = 1; o < 64; o <<= 1) ss += __shfl_xor(ss, o);
    float sc = 1.0f / fmaxf(sqrtf(ss), 1e-12f);
    if (lane == 0) invn[row] = sc;
    float nx = v.x * sc, ny = v.y * sc;
    cs0 += nx; cs1 += ny; cq0 += nx * nx; cq1 += ny * ny;
  }
  atomicAdd(&lsum[d0], cs0); atomicAdd(&lsum[d0 + 1], cs1);
  atomicAdd(&lssq[d0], cq0); atomicAdd(&lssq[d0 + 1], cq1);
  __syncthreads();
  if (t < 128) { atomicAdd(&sums[t], lsum[t]); atomicAdd(&sumsq[t], lssq[t]); }
}

// -- fold BN(s) into W: Wpp(f32) + WT(bf16 transposed) + cvec + bp ---------------
__global__ void k_prepw(const float* __restrict__ sums, const float* __restrict__ sumsq,
                        float cnt, const float* __restrict__ W,
                        const float* __restrict__ base,
                        const float* __restrict__ preS, const float* __restrict__ preQ,
                        float precnt,
                        float* __restrict__ Wpp, u16* __restrict__ WT,
                        float* __restrict__ cvec, float* __restrict__ bp) {
  __shared__ float redc[8][128], redb[8][128];
  int t = threadIdx.x;
  int kq = (t & 31) * 4, jg = t >> 5;
  float cx = 0.f, cy = 0.f, cz = 0.f, cw = 0.f;
  float bx = 0.f, by = 0.f, bz = 0.f, bw = 0.f;
  for (int j = jg; j < 128; j += 8) {
    float m2 = sums[j] / cnt;
    float rs2 = rsqrtf(sumsq[j] / cnt - m2 * m2 + BN_EPS);
    float mA = 0.f, rsA = 1.f;
    if (preS) {
      mA = preS[j] / precnt;
      rsA = rsqrtf(preQ[j] / precnt - mA * mA + BN_EPS);
    }
    float4 w = *(const float4*)&W[j * 128 + kq];
    float s2 = rs2, sA = rsA * rs2;
    float4 wpp = make_float4(sA * w.x, sA * w.y, sA * w.z, sA * w.w);
    *(float4*)&Wpp[j * 128 + kq] = wpp;
    WT[(size_t)(kq + 0) * 128 + j] = f2b(wpp.x);
    WT[(size_t)(kq + 1) * 128 + j] = f2b(wpp.y);
    WT[(size_t)(kq + 2) * 128 + j] = f2b(wpp.z);
    WT[(size_t)(kq + 3) * 128 + j] = f2b(wpp.w);
    cx = fmaf(mA, wpp.x, cx); cy = fmaf(mA, wpp.y, cy);
    cz = fmaf(mA, wpp.z, cz); cw = fmaf(mA, wpp.w, cw);
    float m2s = m2 * s2;
    bx = fmaf(m2s, w.x, bx); by = fmaf(m2s, w.y, by);
    bz = fmaf(m2s, w.z, bz); bw = fmaf(m2s, w.w, bw);
  }
  *(float4*)&redc[jg][kq] = make_float4(cx, cy, cz, cw);
  *(float4*)&redb[jg][kq] = make_float4(bx, by, bz, bw);
  __syncthreads();
  if (t < 32) {
    int k4 = t * 4;
    float4 sc = *(float4*)&redc[0][k4];
    float4 sb = *(float4*)&redb[0][k4];
    #pragma unroll
    for (int g = 1; g < 8; ++g) {
      float4 ac = *(float4*)&redc[g][k4];
      float4 ab = *(float4*)&redb[g][k4];
      sc.x += ac.x; sc.y += ac.y; sc.z += ac.z; sc.w += ac.w;
      sb.x += ab.x; sb.y += ab.y; sb.z += ab.z; sb.w += ab.w;
    }
    *(float4*)&cvec[k4] = sc;
    float4 bs = base ? *(const float4*)&base[k4] : make_float4(0, 0, 0, 0);
    *(float4*)&bp[k4] = make_float4(bs.x - sb.x, bs.y - sb.y, bs.z - sb.z, bs.w - sb.w);
  }
}

// ---- CSR edge agg over bf16 table: quarter-wave rows, 8 edges in flight/wave ----
__global__ __launch_bounds__(256) void k_aggb(
    const u16* __restrict__ xwB, const int2* __restrict__ elist,
    const int* __restrict__ off, const float* __restrict__ dinv,
    const float* __restrict__ bias, void* __restrict__ outp,
    int norm_bf16, float* __restrict__ sums, float* __restrict__ sumsq) {
  __shared__ float lsum[128], lssq[128];
  int t = threadIdx.x;
  if (norm_bf16) {
    if (t < 128) { lsum[t] = 0.f; lssq[t] = 0.f; }
    __syncthreads();
  }
  int wid = t >> 6, lane = t & 63;
  int q = lane >> 4, l16 = lane & 15, c0 = l16 * 8;
  float bb[8];
  #pragma unroll
  for (int j = 0; j < 8; ++j) bb[j] = bias[c0 + j];
  float cs[8] = {}, cq[8] = {};
  for (int i = blockIdx.x * 4 + wid; i < HW; i += gridDim.x * 4) {
    int s0 = off[i], s1 = off[i + 1];
    float di = dinv[i];
    u16x8 xi = *(const u16x8*)&xwB[(size_t)i * 128 + c0];
    float acc[8] = {};
    int kk = s0 + q;
    for (; kk + 4 < s1; kk += 8) {
      int2 ea = elist[kk], eb = elist[kk + 4];
      u16x8 va = *(const u16x8*)&xwB[(size_t)ea.x * 128 + c0];
      u16x8 vb = *(const u16x8*)&xwB[(size_t)eb.x * 128 + c0];
      float wa = __int_as_float(ea.y), wb = __int_as_float(eb.y);
      #pragma unroll
      for (int j = 0; j < 8; ++j) acc[j] = fmaf(wa, b2f(va[j]), acc[j]);
      #pragma unroll
      for (int j = 0; j < 8; ++j) acc[j] = fmaf(wb, b2f(vb[j]), acc[j]);
    }
    for (; kk < s1; kk += 4) {
      int2 e = elist[kk];
      u16x8 v = *(const u16x8*)&xwB[(size_t)e.x * 128 + c0];
      float w = __int_as_float(e.y);
      #pragma unroll
      for (int j = 0; j < 8; ++j) acc[j] = fmaf(w, b2f(v[j]), acc[j]);
    }
    #pragma unroll
    for (int j = 0; j < 8; ++j) {
      acc[j] += __shfl_xor(acc[j], 16);
      acc[j] += __shfl_xor(acc[j], 32);
    }
    float inv_deg = di * di;
    float r[8];
    #pragma unroll
    for (int j = 0; j < 8; ++j) {
      r[j] = fmaf(b2f(xi[j]), inv_deg, acc[j]) + bb[j];
      r[j] = (r[j] >= 0.f) ? r[j] : LSLOPE * r[j];
    }
    if (norm_bf16) {
      float ss = 0.f;
      #pragma unroll
      for (int j = 0; j < 8; ++j) ss += r[j] * r[j];
      ss += __shfl_xor(ss, 1); ss += __shfl_xor(ss, 2);
      ss += __shfl_xor(ss, 4); ss += __shfl_xor(ss, 8);
      float sc = 1.0f / fmaxf(sqrtf(ss), 1e-12f);
      if (q == 0) {
        u16x8 o;
        #pragma unroll
        for (int j = 0; j < 8; ++j) {
          r[j] *= sc;
          o[j] = f2b(r[j]);
          cs[j] += r[j]; cq[j] += r[j] * r[j];
        }
        *(u16x8*)&((u16*)outp)[(size_t)i * 128 + c0] = o;
      }
    } else if (q == 0) {
      float* op = (float*)outp + (size_t)i * 128 + c0;
      *(float4*)op = make_float4(r[0], r[1], r[2], r[3]);
      *(float4*)(op + 4) = make_float4(r[4], r[5], r[6], r[7]);
    }
  }
  if (norm_bf16) {
    if (q == 0) {
      #pragma unroll
      for (int j = 0; j < 8; ++j) {
        atomicAdd(&lsum[c0 + j], cs[j]);
        atomicAdd(&lssq[c0 + j], cq[j]);
      }
    }
    __syncthreads();
    if (t < 128) { atomicAdd(&sums[t], lsum[t]); atomicAdd(&sumsq[t], lssq[t]); }
  }
}

// -------- final: (m2 + leaky(H1p[seg])) @ out_W + out_b -> softmax --------------
__global__ __launch_bounds__(256) void k_final(
    const float* __restrict__ m2, const float* __restrict__ H1p,
    const int* __restrict__ seg, const float* __restrict__ Wout,
    const float* __restrict__ bout, float* __restrict__ out) {
  __shared__ float rb[16][132];
  __shared__ float WL[128 * 16];
  int t = threadIdx.x;
  int row0 = blockIdx.x * 16;
  for (int idx = t; idx < 128 * NCLS; idx += 256) WL[idx] = Wout[idx];
  for (int idx = t; idx < 16 * 128; idx += 256) {
    int r = idx >> 7, d = idx & 127;
    int row = row0 + r;
    float h = H1p[(size_t)seg[row] * 128 + d];
    h = (h >= 0.f) ? h : LSLOPE * h;
    rb[r][d] = m2[(size_t)row * 128 + d] + h;
  }
  __syncthreads();
  int c = t & 15, r = t >> 4;
  float acc = bout[c];
  #pragma unroll 8
  for (int d = 0; d < 128; ++d) acc = fmaf(rb[r][d], WL[d * 16 + c], acc);
  float mx = acc;
  #pragma unroll
  for (int o = 1; o < 16; o <<= 1) mx = fmaxf(mx, __shfl_xor(mx, o));
  float e = expf(acc - mx);
  float s = e;
  #pragma unroll
  for (int o = 1; o < 16; o <<= 1) s += __shfl_xor(s, o);
  out[(size_t)(row0 + r) * NCLS + c] = e / s;
}

// =================================================================================
extern "C" void kernel_launch(void* const* d_in, const int* in_sizes, int n_in,
                              void* d_out, int out_size, void* d_ws, size_t ws_size,
                              hipStream_t stream) {
  const float* x        = (const float*)d_in[0];
  const float* Q        = (const float*)d_in[1];
  const float* A_norm   = (const float*)d_in[2];
  const int*   ei       = (const int*)d_in[3];
  const float* prelin_W = (const float*)d_in[4];
  const float* prelin_b = (const float*)d_in[5];
  const float* gcn1_W   = (const float*)d_in[6];
  const float* gcn1_b   = (const float*)d_in[7];
  const float* gcn2_W   = (const float*)d_in[8];
  const float* gcn2_b   = (const float*)d_in[9];
  const float* mpnn1_W  = (const float*)d_in[10];
  const float* mpnn1_b  = (const float*)d_in[11];
  const float* mpnn2_W  = (const float*)d_in[12];
  const float* mpnn2_b  = (const float*)d_in[13];
  const float* out_W    = (const float*)d_in[14];
  const float* out_b    = (const float*)d_in[15];
  float* outp = (float*)d_out;
  const int* e_src = ei;
  const int* e_dst = ei + NE;

  char* ws = (char*)d_ws;
  size_t o = 0;
  auto alloc = [&](size_t bytes) { size_t r = o; o = (o + bytes + 255) & ~255ULL; return r; };
  size_t bufA_o   = alloc((size_t)HW * 128 * 4);
  size_t bufB_o   = alloc((size_t)HW * 128 * 4);
  // ---- zero group start ----
  size_t cntd_o   = alloc((size_t)HW * 4);
  size_t cntinv_o = alloc((size_t)NSP * 4);
  size_t stats_o  = alloc(5 * 256 * 4);
  size_t spDp_o   = alloc((size_t)NSP * 128 * 4);
  size_t spHp_o   = alloc((size_t)NSP * 128 * 4);
  size_t zero_end = o;
  // ---- zero group end ----
  size_t seg_o    = alloc((size_t)HW * 4);
  size_t seginv_o = alloc((size_t)HW * 4);
  size_t off_o    = alloc((size_t)(HW + 1) * 4);
  size_t cur_o    = alloc((size_t)HW * 4);
  size_t dinv_o   = alloc((size_t)HW * 4);
  size_t e2_o     = alloc((size_t)NE * 8);
  size_t bsum_o   = alloc(256 * 4);
  size_t bo_o     = alloc(256 * 4);
  size_t spA_o    = alloc((size_t)NSP * 128 * 4);
  size_t spC_o    = alloc((size_t)NSP * 128 * 4);
  size_t spDa_o   = alloc((size_t)NSP * 128 * 4);
  size_t Wpp_o    = alloc(128 * 128 * 4);
  size_t WTmp_o   = alloc(128 * 128 * 2);
  size_t WTpre_o  = alloc(128 * 224 * 2);
  size_t cv_o     = alloc(128 * 4);
  size_t bp_o     = alloc(128 * 4);
  size_t invG1_o  = alloc((size_t)NSP * 4);
  size_t invG2_o  = alloc((size_t)NSP * 4);
  size_t invM1_o  = alloc((size_t)HW * 4);
  size_t xb_o     = alloc((size_t)HW * 224 * 2);
  size_t xwB_o    = alloc((size_t)HW * 128 * 2);
  size_t bufN_o   = alloc((size_t)HW * 128 * 2);
  if (o > ws_size) return;

  float* bufA   = (float*)(ws + bufA_o);
  float* bufB   = (float*)(ws + bufB_o);
  int*   cntd   = (int*)(ws + cntd_o);
  int*   cntinv = (int*)(ws + cntinv_o);
  float* stats  = (float*)(ws + stats_o);
  float* sA_s  = stats + 0 * 256, *sA_q  = sA_s + 128;
  float* sG1_s = stats + 1 * 256, *sG1_q = sG1_s + 128;
  float* sG2_s = stats + 2 * 256, *sG2_q = sG2_s + 128;
  float* sM1_s = stats + 3 * 256, *sM1_q = sM1_s + 128;
  float* sM2_s = stats + 4 * 256, *sM2_q = sM2_s + 128;
  float* spDp   = (float*)(ws + spDp_o);
  float* spHp   = (float*)(ws + spHp_o);
  int*   seg    = (int*)(ws + seg_o);
  int*   seginv = (int*)(ws + seginv_o);
  int*   offp   = (int*)(ws + off_o);
  int*   cur    = (int*)(ws + cur_o);
  float* dinv   = (float*)(ws + dinv_o);
  int2*  e2     = (int2*)(ws + e2_o);
  int*   bsum   = (int*)(ws + bsum_o);
  int*   bo     = (int*)(ws + bo_o);
  float* spA    = (float*)(ws + spA_o);
  float* spC    = (float*)(ws + spC_o);
  float* spDa   = (float*)(ws + spDa_o);
  float* Wpp    = (float*)(ws + Wpp_o);
  u16*   WTmp   = (u16*)(ws + WTmp_o);
  u16*   WTpre  = (u16*)(ws + WTpre_o);
  float* cv     = (float*)(ws + cv_o);
  float* bp     = (float*)(ws + bp_o);
  float* invG1  = (float*)(ws + invG1_o);
  float* invG2  = (float*)(ws + invG2_o);
  float* invM1  = (float*)(ws + invM1_o);
  u16*   xb     = (u16*)(ws + xb_o);
  u16*   xwB    = (u16*)(ws + xwB_o);
  u16*   bufN   = (u16*)(ws + bufN_o);

  hipMemsetAsync(ws + cntd_o, 0, zero_end - cntd_o, stream);

  // seg/seg_inv/degree + x->bf16 + prelinW->bf16T, then CSR build
  hipLaunchKernelGGL(k_setup, dim3(NQB + NDB + CXB + CWB), dim3(256), 0, stream,
                     Q, seg, seginv, cntinv, e_dst, cntd, x, prelin_W, xb, WTpre);
  hipLaunchKernelGGL(k_scan_a, dim3(256), dim3(256), 0, stream, cntd, offp, bsum);
  hipLaunchKernelGGL(k_scan_b, dim3(1), dim3(256), 0, stream, bsum, bo);
  hipLaunchKernelGGL(k_scan_c, dim3(256), dim3(256), 0, stream, offp, bo, cur, cntd, dinv);
  hipLaunchKernelGGL(k_scatter, dim3(NE / 256), dim3(256), 0, stream, e_src, e_dst, cur, dinv, e2);

  // prelin MFMA GEMM: y = xb @ WTpre^T + prelin_b -> bufA (f32), fused stats
  hipLaunchKernelGGL(k_mgemm, dim3(HW / 64), dim3(256), 0, stream,
                     (const void*)xb, 1, 224, WTpre, 224, 224,
                     prelin_b, (const float*)nullptr, (const float*)nullptr,
                     (void*)bufA, 0, sA_s, sA_q);
  hipLaunchKernelGGL(k_pool2, dim3(NSP), dim3(256), 0, stream,
                     bufA, seginv, cntinv, sA_s, sA_q, spA);

  // ---- GCN layer 1 (f32 path) ----
  hipLaunchKernelGGL(k_rstats, dim3(16), dim3(256), 0, stream,
                     spA, (float*)nullptr, invG1, sG1_s, sG1_q, NSP,
                     (const float*)nullptr, (const float*)nullptr, 1.f, 0);
  hipLaunchKernelGGL(k_prepw, dim3(1), dim3(256), 0, stream, sG1_s, sG1_q, (float)NSP,
                     gcn1_W, gcn1_b, (const float*)nullptr, (const float*)nullptr, 1.f,
                     Wpp, WTmp, cv, bp);
  hipLaunchKernelGGL(k_gemm, dim3(NSP / 64), dim3(256), 0, stream,
                     spA, Wpp, bp, spC, 128, 0, (float*)nullptr, (float*)nullptr, invG1, cv);
  hipLaunchKernelGGL(k_gemm_ks, dim3(NSP / 64, 8), dim3(256), 0, stream,
                     A_norm, spC, spDp, NSP, 128);
  // ---- GCN layer 2 ----
  hipLaunchKernelGGL(k_rstats, dim3(16), dim3(256), 0, stream,
                     spDp, spDa, invG2, sG2_s, sG2_q, NSP,
                     (const float*)nullptr, (const float*)nullptr, 1.f, 1);
  hipLaunchKernelGGL(k_prepw, dim3(1), dim3(256), 0, stream, sG2_s, sG2_q, (float)NSP,
                     gcn2_W, gcn2_b, (const float*)nullptr, (const float*)nullptr, 1.f,
                     Wpp, WTmp, cv, bp);
  hipLaunchKernelGGL(k_gemm, dim3(NSP / 64), dim3(256), 0, stream,
                     spDa, Wpp, bp, spC, 128, 0, (float*)nullptr, (float*)nullptr, invG2, cv);
  hipLaunchKernelGGL(k_gemm_ks, dim3(NSP / 64, 8), dim3(256), 0, stream,
                     A_norm, spC, spHp, NSP, 128);

  // ---- MPNN layer 1 ----
  hipLaunchKernelGGL(k_rstats, dim3(512), dim3(256), 0, stream,
                     bufA, (float*)nullptr, invM1, sM1_s, sM1_q, HW, sA_s, sA_q, (float)HW, 0);
  hipLaunchKernelGGL(k_prepw, dim3(1), dim3(256), 0, stream, sM1_s, sM1_q, (float)HW,
                     mpnn1_W, (const float*)nullptr, sA_s, sA_q, (float)HW,
                     Wpp, WTmp, cv, bp);
  hipLaunchKernelGGL(k_mgemm, dim3(HW / 64), dim3(256), 0, stream,
                     (const void*)bufA, 0, 128, WTmp, 128, 128,
                     bp, cv, invM1, (void*)xwB, 1, (float*)nullptr, (float*)nullptr);
  hipLaunchKernelGGL(k_aggb, dim3(2048), dim3(256), 0, stream,
                     xwB, e2, offp, dinv, mpnn1_b, (void*)bufN, 1, sM2_s, sM2_q);

  // ---- MPNN layer 2 ----
  hipLaunchKernelGGL(k_prepw, dim3(1), dim3(256), 0, stream, sM2_s, sM2_q, (float)HW,
                     mpnn2_W, (const float*)nullptr, (const float*)nullptr, (const float*)nullptr, 1.f,
                     Wpp, WTmp, cv, bp);
  hipLaunchKernelGGL(k_mgemm, dim3(HW / 64), dim3(256), 0, stream,
                     (const void*)bufN, 1, 128, WTmp, 128, 128,
                     bp, cv, (const float*)nullptr, (void*)xwB, 1,
                     (float*)nullptr, (float*)nullptr);
  hipLaunchKernelGGL(k_aggb, dim3(2048), dim3(256), 0, stream,
                     xwB, e2, offp, dinv, mpnn2_b, (void*)bufB, 0,
                     (float*)nullptr, (float*)nullptr);

  // final fused head
  hipLaunchKernelGGL(k_final, dim3(HW / 16), dim3(256), 0, stream,
                     bufB, spHp, seg, out_W, out_b, outp);
}

// Round 7
// 449.058 us; speedup vs baseline: 2.8043x; 1.2542x over previous
//
#include <hip/hip_runtime.h>

#define HW 65536
#define NSP 1024
#define NE 524288
#define NCLS 16
#define BN_EPS 1e-5f
#define LSLOPE 0.01f

typedef unsigned short u16;
typedef short s16x8 __attribute__((ext_vector_type(8)));
typedef u16 u16x8 __attribute__((ext_vector_type(8)));
typedef u16 u16x4 __attribute__((ext_vector_type(4)));
typedef float f32x4 __attribute__((ext_vector_type(4)));

__device__ inline u16 f2b(float x) {            // f32 -> bf16 RNE
  unsigned int u = __float_as_uint(x);
  unsigned int r = ((u >> 16) & 1u) + 0x7FFFu;
  return (u16)((u + r) >> 16);
}
__device__ inline float b2f(u16 u) { return __uint_as_float(((unsigned int)u) << 16); }

struct P {
  const float *x, *Q, *A_norm;
  const int *e_src, *e_dst;
  const float *preW, *preB;
  const float *g1W, *g1b, *g2W, *g2b;
  const float *m1W, *m1b, *m2W, *m2b;
  const float *oW, *ob;
  float *outp;
  float *bufA, *bufB;
  int *cntd, *cntinv;
  float *stats;                       // 5 pairs of (sum[128], sumsq[128])
  float *spDp, *spHp;
  int *seg, *seginv, *offp, *cur;
  float *dinv;
  int2 *e2;
  int *bsum;
  float *spA, *spC, *spDa;
  float *WppG1, *WppG2;
  u16 *WTm1, *WTm2, *WTpre;
  float *cvG1, *bpG1, *cvG2, *bpG2, *cvM1, *bpM1, *cvM2, *bpM2;
  float *invG1, *invG2, *invM1;
  u16 *xb, *xwB, *bufN;
};

#define S_A(p)  ((p).stats + 0*256)
#define S_G1(p) ((p).stats + 1*256)
#define S_G2(p) ((p).stats + 2*256)
#define S_M1(p) ((p).stats + 3*256)
#define S_M2(p) ((p).stats + 4*256)

#define NQB 4096
#define NDB (NE / 256)
#define CXB (HW * 56 / 256)
#define CWB 112

// ================== k_setup: seg/seg_inv + degree + x->bf16 + preW->bf16T =======
__global__ __launch_bounds__(256) void k_setup(P p) {
  int b = blockIdx.x, t = threadIdx.x;
  if (b < NQB) {
    const float4* Q4 = (const float4*)p.Q;
    const int n4 = HW * NSP / 4;
    for (int i = b * 256 + t; i < n4; i += NQB * 256) {
      float4 q = Q4[i];
      int base = i * 4;
      #pragma unroll
      for (int e = 0; e < 4; ++e) {
        float qv = (e == 0) ? q.x : (e == 1) ? q.y : (e == 2) ? q.z : q.w;
        if (qv > 0.5f) {
          int idx = base + e;
          int r = idx >> 10, s = idx & (NSP - 1);
          p.seg[r] = s;
          int pos = atomicAdd(&p.cntinv[s], 1);
          p.seginv[s * 64 + pos] = r;
        }
      }
    }
  } else if (b < NQB + NDB) {
    int e = (b - NQB) * 256 + t;
    if (e < NE) atomicAdd(&p.cntd[p.e_dst[e]], 1);
  } else if (b < NQB + NDB + CXB) {
    int g = (b - NQB - NDB) * 256 + t;
    int row = g / 56, qd = g - row * 56;
    int k0 = qd * 4;
    u16x4 o;
    if (k0 < 200) {
      float4 v = *(const float4*)&p.x[(size_t)row * 200 + k0];
      o[0] = f2b(v.x); o[1] = f2b(v.y); o[2] = f2b(v.z); o[3] = f2b(v.w);
    } else { o[0] = 0; o[1] = 0; o[2] = 0; o[3] = 0; }
    *(u16x4*)&p.xb[(size_t)row * 224 + k0] = o;
  } else {
    int g = (b - NQB - NDB - CXB) * 256 + t;
    if (g < 128 * 224) {
      int n = g / 224, k = g - n * 224;
      p.WTpre[g] = (k < 200) ? f2b(p.preW[(size_t)k * 128 + n]) : (u16)0;
    }
  }
}

// =========================== device: scan_a =====================================
__device__ void dev_scan_a(P& p, int b, char* smem) {
  int* s = (int*)smem;
  int t = threadIdx.x;
  int i = b * 256 + t;
  int v = p.cntd[i];
  s[t] = v; __syncthreads();
  for (int o = 1; o < 256; o <<= 1) {
    int x = (t >= o) ? s[t - o] : 0;
    __syncthreads();
    s[t] += x;
    __syncthreads();
  }
  p.offp[i] = s[t] - v;
  if (t == 255) p.bsum[b] = s[t];
}

// ================== device: scan_c2 (merged scan_b + scan_c) ====================
__device__ void dev_scan_c2(P& p, int b, char* smem) {
  int* w4 = (int*)smem;
  int t = threadIdx.x;
  int v = (t < b) ? p.bsum[t] : 0;
  #pragma unroll
  for (int o = 1; o < 64; o <<= 1) v += __shfl_xor(v, o);
  if ((t & 63) == 0) w4[t >> 6] = v;
  __syncthreads();
  int base = w4[0] + w4[1] + w4[2] + w4[3];
  int i = b * 256 + t;
  int ov = p.offp[i] + base;
  p.offp[i] = ov;
  p.cur[i] = ov;
  p.dinv[i] = rsqrtf((float)p.cntd[i] + 1.0f);
  if (i == 0) p.offp[HW] = NE;
}

// ============================ device: scatter ====================================
__device__ void dev_scatter(P& p, int b) {
  int e = b * 256 + threadIdx.x;
  if (e < NE) {
    int d = p.e_dst[e], s = p.e_src[e];
    float w = p.dinv[d] * p.dinv[s];
    int pos = atomicAdd(&p.cur[d], 1);
    p.e2[pos] = make_int2(s, __float_as_int(w));
  }
}

// ====================== device: MFMA bf16 GEMM (needs 31744B smem) ===============
__device__ void dev_mgemm(const void* Ap, int a_bf16, int lda,
                          const u16* WT, int ldb, int K,
                          const float* bias, const float* cvec, const float* invn,
                          void* Cp, int c_bf16,
                          float* sums, float* sumsq, int bid, char* smem) {
  u16* As = (u16*)smem;                 // [2][64][40]
  u16* Bs = (u16*)(smem + 10240);       // [2][128][40]
  float* lsum = (float*)(smem + 30720);
  float* lssq = lsum + 128;
  int t = threadIdx.x;
  if (sums && t < 128) { lsum[t] = 0.f; lssq[t] = 0.f; }
  int row0 = bid * 64;
  int ar = t >> 2, ak = (t & 3) * 8;
  u16x8 aReg; u16x8 bReg[2];

  auto loadRegs = [&](int k0) {
    if (a_bf16) {
      aReg = *(const u16x8*)((const u16*)Ap + (size_t)(row0 + ar) * lda + k0 + ak);
    } else {
      const float* ap = (const float*)Ap + (size_t)(row0 + ar) * lda + k0 + ak;
      float4 f0 = *(const float4*)ap;
      float4 f1 = *(const float4*)(ap + 4);
      u16x8 v;
      v[0] = f2b(f0.x); v[1] = f2b(f0.y); v[2] = f2b(f0.z); v[3] = f2b(f0.w);
      v[4] = f2b(f1.x); v[5] = f2b(f1.y); v[6] = f2b(f1.z); v[7] = f2b(f1.w);
      aReg = v;
    }
    #pragma unroll
    for (int it = 0; it < 2; ++it) {
      int slot = t + it * 256;
      int bn = slot >> 2, kg = (slot & 3) * 8;
      bReg[it] = *(const u16x8*)(WT + (size_t)bn * ldb + k0 + kg);
    }
  };
  auto dsWrite = [&](int bq) {
    *(u16x8*)&As[(bq * 64 + ar) * 40 + ak] = aReg;
    #pragma unroll
    for (int it = 0; it < 2; ++it) {
      int slot = t + it * 256;
      int bn = slot >> 2, kg = (slot & 3) * 8;
      *(u16x8*)&Bs[(bq * 128 + bn) * 40 + kg] = bReg[it];
    }
  };

  int lane = t & 63, wv = t >> 6;
  int m0 = (wv >> 1) * 32, n0 = (wv & 1) * 64;
  int fr = lane & 15, fk = (lane >> 4) * 8;
  f32x4 acc[2][4];
  #pragma unroll
  for (int mt = 0; mt < 2; ++mt)
    #pragma unroll
    for (int nt = 0; nt < 4; ++nt)
      acc[mt][nt] = (f32x4){0.f, 0.f, 0.f, 0.f};

  int nch = K >> 5;
  loadRegs(0);
  int cur = 0;
  for (int ch = 0; ch < nch; ++ch) {
    dsWrite(cur);
    __syncthreads();
    if (ch + 1 < nch) loadRegs((ch + 1) << 5);
    s16x8 afr0 = *(const s16x8*)&As[(cur * 64 + m0 + fr) * 40 + fk];
    s16x8 afr1 = *(const s16x8*)&As[(cur * 64 + m0 + 16 + fr) * 40 + fk];
    s16x8 bfr[4];
    #pragma unroll
    for (int nt = 0; nt < 4; ++nt)
      bfr[nt] = *(const s16x8*)&Bs[(cur * 128 + n0 + nt * 16 + fr) * 40 + fk];
    #pragma unroll
    for (int nt = 0; nt < 4; ++nt) {
      acc[0][nt] = __builtin_amdgcn_mfma_f32_16x16x32_bf16(afr0, bfr[nt], acc[0][nt], 0, 0, 0);
      acc[1][nt] = __builtin_amdgcn_mfma_f32_16x16x32_bf16(afr1, bfr[nt], acc[1][nt], 0, 0, 0);
    }
    cur ^= 1;
  }

  float bb4[4], cv4[4];
  #pragma unroll
  for (int nt = 0; nt < 4; ++nt) {
    int c = n0 + nt * 16 + fr;
    bb4[nt] = bias ? bias[c] : 0.f;
    cv4[nt] = cvec ? cvec[c] : 0.f;
  }
  int rg = lane >> 4;
  float cs4[4] = {}, cq4[4] = {};
  #pragma unroll
  for (int mt = 0; mt < 2; ++mt) {
    int rbase = row0 + m0 + mt * 16 + rg * 4;
    float inr[4];
    #pragma unroll
    for (int j = 0; j < 4; ++j) inr[j] = invn ? invn[rbase + j] : 1.f;
    #pragma unroll
    for (int nt = 0; nt < 4; ++nt) {
      int c = n0 + nt * 16 + fr;
      #pragma unroll
      for (int j = 0; j < 4; ++j) {
        float xv = inr[j] * (acc[mt][nt][j] - cv4[nt]) + bb4[nt];
        if (sums) { cs4[nt] += xv; cq4[nt] += xv * xv; }
        if (c_bf16) ((u16*)Cp)[(size_t)(rbase + j) * 128 + c] = f2b(xv);
        else        ((float*)Cp)[(size_t)(rbase + j) * 128 + c] = xv;
      }
    }
  }
  if (sums) {
    __syncthreads();
    #pragma unroll
    for (int nt = 0; nt < 4; ++nt) {
      int c = n0 + nt * 16 + fr;
      atomicAdd(&lsum[c], cs4[nt]);
      atomicAdd(&lssq[c], cq4[nt]);
    }
    __syncthreads();
    if (t < 128) { atomicAdd(&sums[t], lsum[t]); atomicAdd(&sumsq[t], lssq[t]); }
  }
}

// =================== device: superpixel mean-pool (4096B smem) ==================
__device__ void dev_pool2(P& p, int sp, char* smem) {
  float4* part = (float4*)smem;   // [8][32]
  int t = threadIdx.x;
  int l32 = t & 31, g = t >> 5;
  int cnt = p.cntinv[sp];
  const float4* y4 = (const float4*)p.bufA;
  const int* lst = p.seginv + sp * 64;
  float4 acc = make_float4(0.f, 0.f, 0.f, 0.f);
  int r = g;
  for (; r + 8 < cnt; r += 16) {
    int i0 = lst[r], i1 = lst[r + 8];
    float4 a = y4[(size_t)i0 * 32 + l32];
    float4 b = y4[(size_t)i1 * 32 + l32];
    acc.x += a.x + b.x; acc.y += a.y + b.y;
    acc.z += a.z + b.z; acc.w += a.w + b.w;
  }
  for (; r < cnt; r += 8) {
    float4 a = y4[(size_t)lst[r] * 32 + l32];
    acc.x += a.x; acc.y += a.y; acc.z += a.z; acc.w += a.w;
  }
  part[g * 32 + l32] = acc;
  __syncthreads();
  if (g == 0) {
    float4 s = part[l32];
    #pragma unroll
    for (int q = 1; q < 8; ++q) {
      float4 pp = part[q * 32 + l32];
      s.x += pp.x; s.y += pp.y; s.z += pp.z; s.w += pp.w;
    }
    int d0 = l32 * 4;
    const float* sAs = S_A(p);
    const float* sAq = S_A(p) + 128;
    float4 ss = *(const float4*)&sAs[d0];
    float4 sq = *(const float4*)&sAq[d0];
    float inv = 1.0f / (float)cnt;
    float4 o;
    float m, rs;
    m = ss.x / HW; rs = rsqrtf(sq.x / HW - m * m + BN_EPS); o.x = (s.x * inv - m) * rs;
    m = ss.y / HW; rs = rsqrtf(sq.y / HW - m * m + BN_EPS); o.y = (s.y * inv - m) * rs;
    m = ss.z / HW; rs = rsqrtf(sq.z / HW - m * m + BN_EPS); o.z = (s.z * inv - m) * rs;
    m = ss.w / HW; rs = rsqrtf(sq.w / HW - m * m + BN_EPS); o.w = (s.w * inv - m) * rs;
    *(float4*)&p.spA[sp * 128 + d0] = o;
  }
}

// ================ device: row inv-norms + col-stats (1024B smem) =================
__device__ void dev_rstats(const float* in, float* act_out, float* invn,
                           float* sums, float* sumsq, int M,
                           const float* preS, const float* preQ, float precnt,
                           int leaky_in, int bid, int nb, char* smem) {
  float* lsum = (float*)smem;
  float* lssq = lsum + 128;
  int t = threadIdx.x;
  if (t < 128) { lsum[t] = 0.f; lssq[t] = 0.f; }
  __syncthreads();
  int wid = t >> 6, lane = t & 63, d0 = lane * 2;
  float m0 = 0.f, m1 = 0.f, r0 = 1.f, r1 = 1.f;
  if (preS) {
    m0 = preS[d0] / precnt;
    r0 = rsqrtf(preQ[d0] / precnt - m0 * m0 + BN_EPS);
    m1 = preS[d0 + 1] / precnt;
    r1 = rsqrtf(preQ[d0 + 1] / precnt - m1 * m1 + BN_EPS);
  }
  float cs0 = 0.f, cs1 = 0.f, cq0 = 0.f, cq1 = 0.f;
  for (int row = bid * 4 + wid; row < M; row += nb * 4) {
    float2 v = *(const float2*)(in + (size_t)row * 128 + d0);
    v.x = (v.x - m0) * r0;
    v.y = (v.y - m1) * r1;
    if (leaky_in) {
      v.x = (v.x >= 0.f) ? v.x : LSLOPE * v.x;
      v.y = (v.y >= 0.f) ? v.y : LSLOPE * v.y;
    }
    if (act_out) *(float2*)(act_out + (size_t)row * 128 + d0) = v;
    float ss = v.x * v.x + v.y * v.y;
    #pragma unroll
    for (int o = 1; o < 64; o <<= 1) ss += __shfl_xor(ss, o);
    float sc = 1.0f / fmaxf(sqrtf(ss), 1e-12f);
    if (lane == 0) invn[row] = sc;
    float nx = v.x * sc, ny = v.y * sc;
    cs0 += nx; cs1 += ny; cq0 += nx * nx; cq1 += ny * ny;
  }
  atomicAdd(&lsum[d0], cs0); atomicAdd(&lsum[d0 + 1], cs1);
  atomicAdd(&lssq[d0], cq0); atomicAdd(&lssq[d0 + 1], cq1);
  __syncthreads();
  if (t < 128) { atomicAdd(&sums[t], lsum[t]); atomicAdd(&sumsq[t], lssq[t]); }
}

// ====== device: fold BN(s) into W -> optional Wpp(f32) / WT(bf16 T) (8192B) =====
__device__ void dev_prepw(const float* sums, const float* sumsq, float cnt,
                          const float* W, const float* base,
                          const float* preS, const float* preQ, float precnt,
                          float* Wpp, u16* WT, float* cvec, float* bp, char* smem) {
  float* redc = (float*)smem;            // [8][128]
  float* redb = redc + 1024;
  int t = threadIdx.x;
  int kq = (t & 31) * 4, jg = t >> 5;
  float cx = 0.f, cy = 0.f, cz = 0.f, cw = 0.f;
  float bx = 0.f, by = 0.f, bz = 0.f, bw = 0.f;
  for (int j = jg; j < 128; j += 8) {
    float m2 = sums[j] / cnt;
    float rs2 = rsqrtf(sumsq[j] / cnt - m2 * m2 + BN_EPS);
    float mA = 0.f, rsA = 1.f;
    if (preS) {
      mA = preS[j] / precnt;
      rsA = rsqrtf(preQ[j] / precnt - mA * mA + BN_EPS);
    }
    float4 w = *(const float4*)&W[j * 128 + kq];
    float sA = rsA * rs2;
    float4 wpp = make_float4(sA * w.x, sA * w.y, sA * w.z, sA * w.w);
    if (Wpp) *(float4*)&Wpp[j * 128 + kq] = wpp;
    if (WT) {
      WT[(size_t)(kq + 0) * 128 + j] = f2b(wpp.x);
      WT[(size_t)(kq + 1) * 128 + j] = f2b(wpp.y);
      WT[(size_t)(kq + 2) * 128 + j] = f2b(wpp.z);
      WT[(size_t)(kq + 3) * 128 + j] = f2b(wpp.w);
    }
    cx = fmaf(mA, wpp.x, cx); cy = fmaf(mA, wpp.y, cy);
    cz = fmaf(mA, wpp.z, cz); cw = fmaf(mA, wpp.w, cw);
    float m2s = m2 * rs2;
    bx = fmaf(m2s, w.x, bx); by = fmaf(m2s, w.y, by);
    bz = fmaf(m2s, w.z, bz); bw = fmaf(m2s, w.w, bw);
  }
  *(float4*)&redc[jg * 128 + kq] = make_float4(cx, cy, cz, cw);
  *(float4*)&redb[jg * 128 + kq] = make_float4(bx, by, bz, bw);
  __syncthreads();
  if (t < 32) {
    int k4 = t * 4;
    float4 sc = *(float4*)&redc[k4];
    float4 sb = *(float4*)&redb[k4];
    #pragma unroll
    for (int g = 1; g < 8; ++g) {
      float4 ac = *(float4*)&redc[g * 128 + k4];
      float4 ab = *(float4*)&redb[g * 128 + k4];
      sc.x += ac.x; sc.y += ac.y; sc.z += ac.z; sc.w += ac.w;
      sb.x += ab.x; sb.y += ab.y; sb.z += ab.z; sb.w += ab.w;
    }
    *(float4*)&cvec[k4] = sc;
    float4 bs = base ? *(const float4*)&base[k4] : make_float4(0, 0, 0, 0);
    *(float4*)&bp[k4] = make_float4(bs.x - sb.x, bs.y - sb.y, bs.z - sb.z, bs.w - sb.w);
  }
}

// ========== device: CSR edge agg over bf16 table (1024B smem) ===================
__device__ void dev_aggb(P& p, const u16* tbl, const float* bias, void* outp,
                         int norm_bf16, float* sums, float* sumsq,
                         int bid, int nb, char* smem) {
  float* lsum = (float*)smem;
  float* lssq = lsum + 128;
  int t = threadIdx.x;
  if (norm_bf16) {
    if (t < 128) { lsum[t] = 0.f; lssq[t] = 0.f; }
    __syncthreads();
  }
  int wid = t >> 6, lane = t & 63;
  int q = lane >> 4, l16 = lane & 15, c0 = l16 * 8;
  float bb[8];
  #pragma unroll
  for (int j = 0; j < 8; ++j) bb[j] = bias[c0 + j];
  float cs[8] = {}, cq[8] = {};
  for (int i = bid * 4 + wid; i < HW; i += nb * 4) {
    int s0 = p.offp[i], s1 = p.offp[i + 1];
    float di = p.dinv[i];
    u16x8 xi = *(const u16x8*)&tbl[(size_t)i * 128 + c0];
    float acc[8] = {};
    int kk = s0 + q;
    for (; kk + 4 < s1; kk += 8) {
      int2 ea = p.e2[kk], eb = p.e2[kk + 4];
      u16x8 va = *(const u16x8*)&tbl[(size_t)ea.x * 128 + c0];
      u16x8 vb = *(const u16x8*)&tbl[(size_t)eb.x * 128 + c0];
      float wa = __int_as_float(ea.y), wb = __int_as_float(eb.y);
      #pragma unroll
      for (int j = 0; j < 8; ++j) acc[j] = fmaf(wa, b2f(va[j]), acc[j]);
      #pragma unroll
      for (int j = 0; j < 8; ++j) acc[j] = fmaf(wb, b2f(vb[j]), acc[j]);
    }
    for (; kk < s1; kk += 4) {
      int2 e = p.e2[kk];
      u16x8 v = *(const u16x8*)&tbl[(size_t)e.x * 128 + c0];
      float w = __int_as_float(e.y);
      #pragma unroll
      for (int j = 0; j < 8; ++j) acc[j] = fmaf(w, b2f(v[j]), acc[j]);
    }
    #pragma unroll
    for (int j = 0; j < 8; ++j) {
      acc[j] += __shfl_xor(acc[j], 16);
      acc[j] += __shfl_xor(acc[j], 32);
    }
    float inv_deg = di * di;
    float r[8];
    #pragma unroll
    for (int j = 0; j < 8; ++j) {
      r[j] = fmaf(b2f(xi[j]), inv_deg, acc[j]) + bb[j];
      r[j] = (r[j] >= 0.f) ? r[j] : LSLOPE * r[j];
    }
    if (norm_bf16) {
      float ss = 0.f;
      #pragma unroll
      for (int j = 0; j < 8; ++j) ss += r[j] * r[j];
      ss += __shfl_xor(ss, 1); ss += __shfl_xor(ss, 2);
      ss += __shfl_xor(ss, 4); ss += __shfl_xor(ss, 8);
      float sc = 1.0f / fmaxf(sqrtf(ss), 1e-12f);
      if (q == 0) {
        u16x8 o;
        #pragma unroll
        for (int j = 0; j < 8; ++j) {
          r[j] *= sc;
          o[j] = f2b(r[j]);
          cs[j] += r[j]; cq[j] += r[j] * r[j];
        }
        *(u16x8*)&((u16*)outp)[(size_t)i * 128 + c0] = o;
      }
    } else if (q == 0) {
      float* op = (float*)outp + (size_t)i * 128 + c0;
      *(float4*)op = make_float4(r[0], r[1], r[2], r[3]);
      *(float4*)(op + 4) = make_float4(r[4], r[5], r[6], r[7]);
    }
  }
  if (norm_bf16) {
    if (q == 0) {
      #pragma unroll
      for (int j = 0; j < 8; ++j) {
        atomicAdd(&lsum[c0 + j], cs[j]);
        atomicAdd(&lssq[c0 + j], cq[j]);
      }
    }
    __syncthreads();
    if (t < 128) { atomicAdd(&sums[t], lsum[t]); atomicAdd(&sumsq[t], lssq[t]); }
  }
}

// ====== device: LDS-free small GEMM [1024x128]@[128x128] with invn epilogue =====
__device__ void dev_gemm_nolds(const float* in, const float* W,
                               const float* bp, const float* cv,
                               const float* invn, float* out, int bid) {
  int t = threadIdx.x;
  int c = t & 127, rh = t >> 7;
  int row0 = bid * 16 + rh * 8;
  float acc[8] = {};
  const float* ip = in + (size_t)row0 * 128;
  #pragma unroll 4
  for (int k = 0; k < 128; ++k) {
    float w = W[k * 128 + c];
    #pragma unroll
    for (int i = 0; i < 8; ++i)
      acc[i] = fmaf(ip[(size_t)i * 128 + k], w, acc[i]);
  }
  float cvc = cv[c], bpc = bp[c];
  #pragma unroll
  for (int i = 0; i < 8; ++i) {
    int row = row0 + i;
    out[(size_t)row * 128 + c] = invn[row] * (acc[i] - cvc) + bpc;
  }
}

// ===== device: split-K GEMM A_norm[1024x1024]@spC -> atomic preact (25088B) =====
__device__ void dev_gemm_ks(const float* A, const float* B, float* C,
                            int bid, char* smem) {
  float* As = (float*)smem;            // [32][68]
  float* Bs = As + 32 * 68;            // [32][128]
  int t = threadIdx.x;
  int c0 = (t & 31) * 4;
  int r0 = (t >> 5) * 8;
  int row0 = (bid >> 3) * 64;
  int kbeg = (bid & 7) * 128;
  int kend = kbeg + 128;
  int lr = t >> 2, lkb = (t & 3) * 8;
  float acc[8][4] = {};
  for (int k0 = kbeg; k0 < kend; k0 += 32) {
    __syncthreads();
    for (int idx = t * 4; idx < 32 * 128; idx += 1024)
      *(float4*)&Bs[(idx >> 7) * 128 + (idx & 127)] = *(const float4*)&B[(size_t)k0 * 128 + idx];
    {
      const float* ap = A + (size_t)(row0 + lr) * NSP + k0 + lkb;
      float4 v0 = *(const float4*)ap;
      float4 v1 = *(const float4*)(ap + 4);
      As[(lkb + 0) * 68 + lr] = v0.x; As[(lkb + 1) * 68 + lr] = v0.y;
      As[(lkb + 2) * 68 + lr] = v0.z; As[(lkb + 3) * 68 + lr] = v0.w;
      As[(lkb + 4) * 68 + lr] = v1.x; As[(lkb + 5) * 68 + lr] = v1.y;
      As[(lkb + 6) * 68 + lr] = v1.z; As[(lkb + 7) * 68 + lr] = v1.w;
    }
    __syncthreads();
    #pragma unroll 2
    for (int k = 0; k < 32; ++k) {
      float4 b4 = *(float4*)&Bs[k * 128 + c0];
      float4 a0 = *(float4*)&As[k * 68 + r0];
      float4 a1 = *(float4*)&As[k * 68 + r0 + 4];
      float av[8] = {a0.x, a0.y, a0.z, a0.w, a1.x, a1.y, a1.z, a1.w};
      float bv[4] = {b4.x, b4.y, b4.z, b4.w};
      #pragma unroll
      for (int r = 0; r < 8; ++r)
        #pragma unroll
        for (int c = 0; c < 4; ++c)
          acc[r][c] = fmaf(av[r], bv[c], acc[r][c]);
    }
  }
  #pragma unroll
  for (int r = 0; r < 8; ++r)
    #pragma unroll
    for (int c = 0; c < 4; ++c)
      atomicAdd(&C[(size_t)(row0 + r0 + r) * 128 + c0 + c], acc[r][c]);
}

// ============================ fused dispatches ===================================
__global__ __launch_bounds__(256) void k_za(P p) {        // scan_a | mgemm_pre
  __shared__ __align__(16) char smem[31744];
  int b = blockIdx.x;
  if (b < 256) dev_scan_a(p, b, smem);
  else dev_mgemm((const void*)p.xb, 1, 224, p.WTpre, 224, 224,
                 p.preB, nullptr, nullptr, (void*)p.bufA, 0,
                 S_A(p), S_A(p) + 128, b - 256, smem);
}
__global__ __launch_bounds__(256) void k_zb(P p) {        // scan_c2 | pool2
  __shared__ __align__(16) char smem[4096];
  int b = blockIdx.x;
  if (b < 256) dev_scan_c2(p, b, smem);
  else dev_pool2(p, b - 256, smem);
}
__global__ __launch_bounds__(256) void k_zc(P p) {        // scatter | rstatsHW
  __shared__ __align__(16) char smem[1024];
  int b = blockIdx.x;
  if (b < NE / 256) dev_scatter(p, b);
  else dev_rstats(p.bufA, nullptr, p.invM1, S_M1(p), S_M1(p) + 128, HW,
                  S_A(p), S_A(p) + 128, (float)HW, 0, b - NE / 256, 512, smem);
}
__global__ __launch_bounds__(256) void k_z8(P p) {        // rstatsG1 | prepwM1
  __shared__ __align__(16) char smem[8192];
  int b = blockIdx.x;
  if (b < 16) dev_rstats(p.spA, nullptr, p.invG1, S_G1(p), S_G1(p) + 128, NSP,
                         nullptr, nullptr, 1.f, 0, b, 16, smem);
  else dev_prepw(S_M1(p), S_M1(p) + 128, (float)HW, p.m1W, nullptr,
                 S_A(p), S_A(p) + 128, (float)HW,
                 nullptr, p.WTm1, p.cvM1, p.bpM1, smem);
}
__global__ __launch_bounds__(256) void k_z9(P p) {        // prepwG1 | mgemmM1
  __shared__ __align__(16) char smem[31744];
  int b = blockIdx.x;
  if (b < 1) dev_prepw(S_G1(p), S_G1(p) + 128, (float)NSP, p.g1W, p.g1b,
                       nullptr, nullptr, 1.f, p.WppG1, nullptr, p.cvG1, p.bpG1, smem);
  else dev_mgemm((const void*)p.bufA, 0, 128, p.WTm1, 128, 128,
                 p.bpM1, p.cvM1, p.invM1, (void*)p.xwB, 1,
                 nullptr, nullptr, b - 1, smem);
}
__global__ __launch_bounds__(256) void k_z10(P p) {       // gemmG1 | aggb1
  __shared__ __align__(16) char smem[1024];
  int b = blockIdx.x;
  if (b < 64) dev_gemm_nolds(p.spA, p.WppG1, p.bpG1, p.cvG1, p.invG1, p.spC, b);
  else dev_aggb(p, p.xwB, p.m1b, (void*)p.bufN, 1,
                S_M2(p), S_M2(p) + 128, b - 64, 2048, smem);
}
__global__ __launch_bounds__(256) void k_z11(P p) {       // anormG1 | prepwM2
  __shared__ __align__(16) char smem[25088];
  int b = blockIdx.x;
  if (b < 128) dev_gemm_ks(p.A_norm, p.spC, p.spDp, b, smem);
  else dev_prepw(S_M2(p), S_M2(p) + 128, (float)HW, p.m2W, nullptr,
                 nullptr, nullptr, 1.f, nullptr, p.WTm2, p.cvM2, p.bpM2, smem);
}
__global__ __launch_bounds__(256) void k_z12(P p) {       // rstatsG2 | mgemmM2
  __shared__ __align__(16) char smem[31744];
  int b = blockIdx.x;
  if (b < 16) dev_rstats(p.spDp, p.spDa, p.invG2, S_G2(p), S_G2(p) + 128, NSP,
                         nullptr, nullptr, 1.f, 1, b, 16, smem);
  else dev_mgemm((const void*)p.bufN, 1, 128, p.WTm2, 128, 128,
                 p.bpM2, p.cvM2, nullptr, (void*)p.xwB, 1,
                 nullptr, nullptr, b - 16, smem);
}
__global__ __launch_bounds__(256) void k_z13(P p) {       // prepwG2 | aggb2
  __shared__ __align__(16) char smem[8192];
  int b = blockIdx.x;
  if (b < 1) dev_prepw(S_G2(p), S_G2(p) + 128, (float)NSP, p.g2W, p.g2b,
                       nullptr, nullptr, 1.f, p.WppG2, nullptr, p.cvG2, p.bpG2, smem);
  else dev_aggb(p, p.xwB, p.m2b, (void*)p.bufB, 0,
                nullptr, nullptr, b - 1, 2048, smem);
}
__global__ __launch_bounds__(256) void k_g2(P p) {        // gemmG2 (nolds)
  dev_gemm_nolds(p.spDa, p.WppG2, p.bpG2, p.cvG2, p.invG2, p.spC, blockIdx.x);
}
__global__ __launch_bounds__(256) void k_an2(P p) {       // anormG2 (split-K)
  __shared__ __align__(16) char smem[25088];
  dev_gemm_ks(p.A_norm, p.spC, p.spHp, blockIdx.x, smem);
}

// ============ final: (m2 + leaky(H1p[seg])) @ out_W + out_b -> softmax ==========
__global__ __launch_bounds__(256) void k_final(P p) {
  __shared__ float rb[16][132];
  __shared__ float WL[128 * 16];
  int t = threadIdx.x;
  int row0 = blockIdx.x * 16;
  for (int idx = t; idx < 128 * NCLS; idx += 256) WL[idx] = p.oW[idx];
  for (int idx = t; idx < 16 * 128; idx += 256) {
    int r = idx >> 7, d = idx & 127;
    int row = row0 + r;
    float h = p.spHp[(size_t)p.seg[row] * 128 + d];
    h = (h >= 0.f) ? h : LSLOPE * h;
    rb[r][d] = p.bufB[(size_t)row * 128 + d] + h;
  }
  __syncthreads();
  int c = t & 15, r = t >> 4;
  float acc = p.ob[c];
  #pragma unroll 8
  for (int d = 0; d < 128; ++d) acc = fmaf(rb[r][d], WL[d * 16 + c], acc);
  float mx = acc;
  #pragma unroll
  for (int o = 1; o < 16; o <<= 1) mx = fmaxf(mx, __shfl_xor(mx, o));
  float e = expf(acc - mx);
  float s = e;
  #pragma unroll
  for (int o = 1; o < 16; o <<= 1) s += __shfl_xor(s, o);
  p.outp[(size_t)(row0 + r) * NCLS + c] = e / s;
}

// =================================================================================
extern "C" void kernel_launch(void* const* d_in, const int* in_sizes, int n_in,
                              void* d_out, int out_size, void* d_ws, size_t ws_size,
                              hipStream_t stream) {
  P p;
  p.x      = (const float*)d_in[0];
  p.Q      = (const float*)d_in[1];
  p.A_norm = (const float*)d_in[2];
  p.e_src  = (const int*)d_in[3];
  p.e_dst  = (const int*)d_in[3] + NE;
  p.preW = (const float*)d_in[4];  p.preB = (const float*)d_in[5];
  p.g1W  = (const float*)d_in[6];  p.g1b  = (const float*)d_in[7];
  p.g2W  = (const float*)d_in[8];  p.g2b  = (const float*)d_in[9];
  p.m1W  = (const float*)d_in[10]; p.m1b  = (const float*)d_in[11];
  p.m2W  = (const float*)d_in[12]; p.m2b  = (const float*)d_in[13];
  p.oW   = (const float*)d_in[14]; p.ob   = (const float*)d_in[15];
  p.outp = (float*)d_out;

  char* ws = (char*)d_ws;
  size_t o = 0;
  auto alloc = [&](size_t bytes) { size_t r = o; o = (o + bytes + 255) & ~255ULL; return r; };
  size_t bufA_o   = alloc((size_t)HW * 128 * 4);
  size_t bufB_o   = alloc((size_t)HW * 128 * 4);
  // ---- zero group ----
  size_t cntd_o   = alloc((size_t)HW * 4);
  size_t cntinv_o = alloc((size_t)NSP * 4);
  size_t stats_o  = alloc(5 * 256 * 4);
  size_t spDp_o   = alloc((size_t)NSP * 128 * 4);
  size_t spHp_o   = alloc((size_t)NSP * 128 * 4);
  size_t zero_end = o;
  // ---- end zero group ----
  size_t seg_o    = alloc((size_t)HW * 4);
  size_t seginv_o = alloc((size_t)HW * 4);
  size_t off_o    = alloc((size_t)(HW + 1) * 4);
  size_t cur_o    = alloc((size_t)HW * 4);
  size_t dinv_o   = alloc((size_t)HW * 4);
  size_t e2_o     = alloc((size_t)NE * 8);
  size_t bsum_o   = alloc(256 * 4);
  size_t spA_o    = alloc((size_t)NSP * 128 * 4);
  size_t spC_o    = alloc((size_t)NSP * 128 * 4);
  size_t spDa_o   = alloc((size_t)NSP * 128 * 4);
  size_t WppG1_o  = alloc(128 * 128 * 4);
  size_t WppG2_o  = alloc(128 * 128 * 4);
  size_t WTm1_o   = alloc(128 * 128 * 2);
  size_t WTm2_o   = alloc(128 * 128 * 2);
  size_t WTpre_o  = alloc(128 * 224 * 2);
  size_t cvG1_o = alloc(512), bpG1_o = alloc(512);
  size_t cvG2_o = alloc(512), bpG2_o = alloc(512);
  size_t cvM1_o = alloc(512), bpM1_o = alloc(512);
  size_t cvM2_o = alloc(512), bpM2_o = alloc(512);
  size_t invG1_o  = alloc((size_t)NSP * 4);
  size_t invG2_o  = alloc((size_t)NSP * 4);
  size_t invM1_o  = alloc((size_t)HW * 4);
  size_t xb_o     = alloc((size_t)HW * 224 * 2);
  size_t xwB_o    = alloc((size_t)HW * 128 * 2);
  size_t bufN_o   = alloc((size_t)HW * 128 * 2);
  if (o > ws_size) return;

  p.bufA  = (float*)(ws + bufA_o);
  p.bufB  = (float*)(ws + bufB_o);
  p.cntd  = (int*)(ws + cntd_o);
  p.cntinv= (int*)(ws + cntinv_o);
  p.stats = (float*)(ws + stats_o);
  p.spDp  = (float*)(ws + spDp_o);
  p.spHp  = (float*)(ws + spHp_o);
  p.seg   = (int*)(ws + seg_o);
  p.seginv= (int*)(ws + seginv_o);
  p.offp  = (int*)(ws + off_o);
  p.cur   = (int*)(ws + cur_o);
  p.dinv  = (float*)(ws + dinv_o);
  p.e2    = (int2*)(ws + e2_o);
  p.bsum  = (int*)(ws + bsum_o);
  p.spA   = (float*)(ws + spA_o);
  p.spC   = (float*)(ws + spC_o);
  p.spDa  = (float*)(ws + spDa_o);
  p.WppG1 = (float*)(ws + WppG1_o);
  p.WppG2 = (float*)(ws + WppG2_o);
  p.WTm1  = (u16*)(ws + WTm1_o);
  p.WTm2  = (u16*)(ws + WTm2_o);
  p.WTpre = (u16*)(ws + WTpre_o);
  p.cvG1 = (float*)(ws + cvG1_o); p.bpG1 = (float*)(ws + bpG1_o);
  p.cvG2 = (float*)(ws + cvG2_o); p.bpG2 = (float*)(ws + bpG2_o);
  p.cvM1 = (float*)(ws + cvM1_o); p.bpM1 = (float*)(ws + bpM1_o);
  p.cvM2 = (float*)(ws + cvM2_o); p.bpM2 = (float*)(ws + bpM2_o);
  p.invG1 = (float*)(ws + invG1_o);
  p.invG2 = (float*)(ws + invG2_o);
  p.invM1 = (float*)(ws + invM1_o);
  p.xb   = (u16*)(ws + xb_o);
  p.xwB  = (u16*)(ws + xwB_o);
  p.bufN = (u16*)(ws + bufN_o);

  hipMemsetAsync(ws + cntd_o, 0, zero_end - cntd_o, stream);

  hipLaunchKernelGGL(k_setup, dim3(NQB + NDB + CXB + CWB), dim3(256), 0, stream, p);
  hipLaunchKernelGGL(k_za,    dim3(256 + HW / 64), dim3(256), 0, stream, p);
  hipLaunchKernelGGL(k_zb,    dim3(256 + NSP), dim3(256), 0, stream, p);
  hipLaunchKernelGGL(k_zc,    dim3(NE / 256 + 512), dim3(256), 0, stream, p);
  hipLaunchKernelGGL(k_z8,    dim3(17), dim3(256), 0, stream, p);
  hipLaunchKernelGGL(k_z9,    dim3(1 + HW / 64), dim3(256), 0, stream, p);
  hipLaunchKernelGGL(k_z10,   dim3(64 + 2048), dim3(256), 0, stream, p);
  hipLaunchKernelGGL(k_z11,   dim3(129), dim3(256), 0, stream, p);
  hipLaunchKernelGGL(k_z12,   dim3(16 + HW / 64), dim3(256), 0, stream, p);
  hipLaunchKernelGGL(k_z13,   dim3(1 + 2048), dim3(256), 0, stream, p);
  hipLaunchKernelGGL(k_g2,    dim3(64), dim3(256), 0, stream, p);
  hipLaunchKernelGGL(k_an2,   dim3(128), dim3(256), 0, stream, p);
  hipLaunchKernelGGL(k_final, dim3(HW / 16), dim3(256), 0, stream, p);
}